// Round 2
// baseline (2270.616 us; speedup 1.0000x reference)
//
#include <hip/hip_runtime.h>
#include <math.h>

#define B_  4
#define D_  256
#define T_  256
#define F_  64
#define H_  8
// tokens M = B*T*F = 65536; stage chunking: 8192 tokens per qkv chunk

#define LN10000 9.210340371976184f
#define SM_SCALE 0.17677669529663687f   // 1/sqrt(32)
#define CHUNK_TOK 8192

// ---------------------------------------------------------------- RoPE helpers
__device__ __forceinline__ float2 rope_pair(float x0, float x1, int pairIdx, float pos) {
    float freq = __expf(-(float)(2 * pairIdx) * (LN10000 / 32.0f));
    float ang = pos * freq;
    float s, c;
    __sincosf(ang, &s, &c);
    return make_float2(x0 * c - x1 * s, x1 * c + x0 * s);
}

__device__ __forceinline__ void rope32(float* x, float pos) {
#pragma unroll
    for (int i = 0; i < 16; ++i) {
        float freq = __expf(-(float)(2 * i) * (LN10000 / 32.0f));
        float ang = pos * freq;
        float s, c;
        __sincosf(ang, &s, &c);
        float x0 = x[2 * i], x1 = x[2 * i + 1];
        x[2 * i]     = x0 * c - x1 * s;
        x[2 * i + 1] = x1 * c + x0 * s;
    }
}

// ---------------------------------------------------------------- transposes
// x (B, D, T, F) -> a0 rows ordered (b, f, t), cols d
__global__ __launch_bounds__(256) void transpose_in(const float* __restrict__ x,
                                                    float* __restrict__ a0) {
    __shared__ float tile[32][33];
    const int bt = blockIdx.z;          // b*T + t
    const int b = bt >> 8, t = bt & 255;
    const int d0 = blockIdx.x * 32, f0 = blockIdx.y * 32;
    const int tx = threadIdx.x, ty = threadIdx.y;   // (32, 8)
    const size_t xbase = (size_t)b * D_ * T_ * F_ + (size_t)t * F_;
#pragma unroll
    for (int j = 0; j < 4; ++j) {
        int d = d0 + ty + j * 8;
        tile[ty + j * 8][tx] = x[xbase + (size_t)d * T_ * F_ + f0 + tx];
    }
    __syncthreads();
    const size_t abase = (size_t)b * F_ * T_ * D_ + (size_t)t * D_;
#pragma unroll
    for (int j = 0; j < 4; ++j) {
        int f = f0 + ty + j * 8;
        a0[abase + (size_t)f * T_ * D_ + d0 + tx] = tile[tx][ty + j * 8];
    }
}

// y chunk rows ordered (bt_local, f), cols d -> out (B, D, T, F) for bt = bt0+z
__global__ __launch_bounds__(256) void transpose_out(const float* __restrict__ y,
                                                     float* __restrict__ out, int bt0) {
    __shared__ float tile[32][33];
    const int btl = blockIdx.z;
    const int bt = bt0 + btl;           // b*T + t
    const int b = bt >> 8, t = bt & 255;
    const int d0 = blockIdx.x * 32, f0 = blockIdx.y * 32;
    const int tx = threadIdx.x, ty = threadIdx.y;
    const size_t ybase = (size_t)btl * F_ * D_;
#pragma unroll
    for (int j = 0; j < 4; ++j) {
        int f = f0 + ty + j * 8;
        tile[ty + j * 8][tx] = y[ybase + (size_t)f * D_ + d0 + tx];
    }
    __syncthreads();
    const size_t obase = (size_t)b * D_ * T_ * F_ + (size_t)t * F_;
#pragma unroll
    for (int j = 0; j < 4; ++j) {
        int d = d0 + ty + j * 8;
        out[obase + (size_t)d * T_ * F_ + f0 + tx] = tile[tx][ty + j * 8];
    }
}

// ---------------------------------------------------------------- fp32 GEMM
// C (MxN) = A (MxK) @ W (KxN), K multiple of 16, M,N multiples of 64.
__global__ __launch_bounds__(256) void gemm_f32(const float* __restrict__ A,
                                                const float* __restrict__ Wt,
                                                float* __restrict__ C,
                                                int M, int N, int K) {
    __shared__ alignas(16) float As[16][64];   // [kk][m]
    __shared__ alignas(16) float Ws[16][64];   // [kk][n]
    const int tid = threadIdx.x;
    const int tx = tid & 15, ty = tid >> 4;
    const int row0 = blockIdx.x * 64, col0 = blockIdx.y * 64;
    float acc[4][4] = {};
    for (int k0 = 0; k0 < K; k0 += 16) {
        {
            const int l = tid * 4;
            const int m = l >> 4, kk = l & 15;
            const float4 v = *reinterpret_cast<const float4*>(
                &A[(size_t)(row0 + m) * K + k0 + kk]);
            As[kk + 0][m] = v.x; As[kk + 1][m] = v.y;
            As[kk + 2][m] = v.z; As[kk + 3][m] = v.w;
            const int kk2 = l >> 6, n = l & 63;
            *reinterpret_cast<float4*>(&Ws[kk2][n]) =
                *reinterpret_cast<const float4*>(&Wt[(size_t)(k0 + kk2) * N + col0 + n]);
        }
        __syncthreads();
#pragma unroll
        for (int kk = 0; kk < 16; ++kk) {
            const float4 av = *reinterpret_cast<const float4*>(&As[kk][ty * 4]);
            const float4 bv = *reinterpret_cast<const float4*>(&Ws[kk][tx * 4]);
            const float a[4] = {av.x, av.y, av.z, av.w};
            const float b[4] = {bv.x, bv.y, bv.z, bv.w};
#pragma unroll
            for (int i = 0; i < 4; ++i)
#pragma unroll
                for (int j = 0; j < 4; ++j)
                    acc[i][j] = fmaf(a[i], b[j], acc[i][j]);
        }
        __syncthreads();
    }
#pragma unroll
    for (int i = 0; i < 4; ++i) {
        float4 v = make_float4(acc[i][0], acc[i][1], acc[i][2], acc[i][3]);
        *reinterpret_cast<float4*>(&C[(size_t)(row0 + ty * 4 + i) * N + col0 + tx * 4]) = v;
    }
}

// ---------------------------------------------------------------- online softmax core
template <int SEQ>
__device__ __forceinline__ float online_attn(const float* __restrict__ Ks,
                                             const float* __restrict__ Vs,
                                             const float* __restrict__ q,
                                             float* __restrict__ o) {
    float m = -INFINITY, lsum = 0.f;
#pragma unroll
    for (int e = 0; e < 32; ++e) o[e] = 0.f;
    for (int j = 0; j < SEQ; ++j) {
        const float* kr = &Ks[j * 32];
        float s = 0.f;
#pragma unroll
        for (int e = 0; e < 32; ++e) s = fmaf(q[e], kr[e], s);
        s *= SM_SCALE;
        const float mn = fmaxf(m, s);
        const float corr = __expf(m - mn);
        const float p = __expf(s - mn);
        lsum = lsum * corr + p;
        const float* vr = &Vs[j * 32];
#pragma unroll
        for (int e = 0; e < 32; ++e) o[e] = fmaf(o[e], corr, p * vr[e]);
        m = mn;
    }
    return 1.0f / lsum;
}

// ---------------------------------------------------------------- stage 1 attention
// chunk of 32 sequences along t (len 256); qkv rows local (sl*256+t); out rows (b,t,f)
__global__ __launch_bounds__(256) void attn_s1(const float* __restrict__ qkv,
                                               float* __restrict__ out, int s0) {
    __shared__ alignas(16) float Ks[256 * 32];
    __shared__ alignas(16) float Vs[256 * 32];
    const int h = blockIdx.x;
    const int sl = blockIdx.y;
    const int s = s0 + sl;               // b*F + f
    const int b = s >> 6, f = s & 63;
    const int tid = threadIdx.x;
#pragma unroll
    for (int i = 0; i < 8; ++i) {
        const int l = i * 256 + tid;
        const int row = l >> 3, c = l & 7;
        const size_t g = ((size_t)(sl * 256 + row)) * 768 + h * 32 + c * 4;
        const float4 kv = *reinterpret_cast<const float4*>(&qkv[g + 256]);
        const float4 vv = *reinterpret_cast<const float4*>(&qkv[g + 512]);
        const float2 r0 = rope_pair(kv.x, kv.y, c * 2, (float)row);
        const float2 r1 = rope_pair(kv.z, kv.w, c * 2 + 1, (float)row);
        *reinterpret_cast<float4*>(&Ks[row * 32 + c * 4]) = make_float4(r0.x, r0.y, r1.x, r1.y);
        *reinterpret_cast<float4*>(&Vs[row * 32 + c * 4]) = vv;
    }
    alignas(16) float q[32];
    {
        const size_t gq = ((size_t)(sl * 256 + tid)) * 768 + h * 32;
#pragma unroll
        for (int c = 0; c < 8; ++c)
            *reinterpret_cast<float4*>(&q[c * 4]) =
                *reinterpret_cast<const float4*>(&qkv[gq + c * 4]);
        rope32(q, (float)tid);
    }
    __syncthreads();
    alignas(16) float o[32];
    const float inv = online_attn<256>(Ks, Vs, q, o);
    const int r2 = (b * 256 + tid) * 64 + f;   // (b,t,f)
    float* op = &out[(size_t)r2 * 256 + h * 32];
#pragma unroll
    for (int e = 0; e < 32; e += 4) {
        *reinterpret_cast<float4*>(&op[e]) =
            make_float4(o[e] * inv, o[e + 1] * inv, o[e + 2] * inv, o[e + 3] * inv);
    }
}

// ---------------------------------------------------------------- stage 2 attention
// chunk of 128 sequences along f (len 64); out rows (window w, pos p)
__global__ __launch_bounds__(64) void attn_s2(const float* __restrict__ qkv,
                                              float* __restrict__ out, int s20) {
    __shared__ alignas(16) float Ks[64 * 32];
    __shared__ alignas(16) float Vs[64 * 32];
    const int h = blockIdx.x;
    const int sl = blockIdx.y;
    const int s2 = s20 + sl;             // b*T + t
    const int b = s2 >> 8, t = s2 & 255;
    const int tid = threadIdx.x;         // 0..63 (= f for the query)
#pragma unroll
    for (int i = 0; i < 8; ++i) {
        const int l = i * 64 + tid;
        const int row = l >> 3, c = l & 7;
        const size_t g = ((size_t)(sl * 64 + row)) * 768 + h * 32 + c * 4;
        const float4 kv = *reinterpret_cast<const float4*>(&qkv[g + 256]);
        const float4 vv = *reinterpret_cast<const float4*>(&qkv[g + 512]);
        const float2 r0 = rope_pair(kv.x, kv.y, c * 2, (float)row);
        const float2 r1 = rope_pair(kv.z, kv.w, c * 2 + 1, (float)row);
        *reinterpret_cast<float4*>(&Ks[row * 32 + c * 4]) = make_float4(r0.x, r0.y, r1.x, r1.y);
        *reinterpret_cast<float4*>(&Vs[row * 32 + c * 4]) = vv;
    }
    alignas(16) float q[32];
    {
        const size_t gq = ((size_t)(sl * 64 + tid)) * 768 + h * 32;
#pragma unroll
        for (int c = 0; c < 8; ++c)
            *reinterpret_cast<float4*>(&q[c * 4]) =
                *reinterpret_cast<const float4*>(&qkv[gq + c * 4]);
        rope32(q, (float)tid);
    }
    __syncthreads();
    alignas(16) float o[32];
    const float inv = online_attn<64>(Ks, Vs, q, o);
    const int fq = tid;
    const int w = (b * 32 + (t >> 3)) * 8 + (fq >> 3);
    const int p = (t & 7) * 8 + (fq & 7);
    float* op = &out[((size_t)(w * 64 + p)) * 256 + h * 32];
#pragma unroll
    for (int e = 0; e < 32; e += 4) {
        *reinterpret_cast<float4*>(&op[e]) =
            make_float4(o[e] * inv, o[e + 1] * inv, o[e + 2] * inv, o[e + 3] * inv);
    }
}

// ---------------------------------------------------------------- stage 3 attention
// chunk of 128 windows (len 64); out rows (b,t,f)
__global__ __launch_bounds__(64) void attn_s3(const float* __restrict__ qkv,
                                              float* __restrict__ out, int w0) {
    __shared__ alignas(16) float Ks[64 * 32];
    __shared__ alignas(16) float Vs[64 * 32];
    const int h = blockIdx.x;
    const int wl = blockIdx.y;
    const int w = w0 + wl;               // 0..1023
    const int tid = threadIdx.x;         // 0..63 (= p for the query)
#pragma unroll
    for (int i = 0; i < 8; ++i) {
        const int l = i * 64 + tid;
        const int row = l >> 3, c = l & 7;
        const size_t g = ((size_t)(wl * 64 + row)) * 768 + h * 32 + c * 4;
        const float4 kv = *reinterpret_cast<const float4*>(&qkv[g + 256]);
        const float4 vv = *reinterpret_cast<const float4*>(&qkv[g + 512]);
        const float2 r0 = rope_pair(kv.x, kv.y, c * 2, (float)row);
        const float2 r1 = rope_pair(kv.z, kv.w, c * 2 + 1, (float)row);
        *reinterpret_cast<float4*>(&Ks[row * 32 + c * 4]) = make_float4(r0.x, r0.y, r1.x, r1.y);
        *reinterpret_cast<float4*>(&Vs[row * 32 + c * 4]) = vv;
    }
    alignas(16) float q[32];
    {
        const size_t gq = ((size_t)(wl * 64 + tid)) * 768 + h * 32;
#pragma unroll
        for (int c = 0; c < 8; ++c)
            *reinterpret_cast<float4*>(&q[c * 4]) =
                *reinterpret_cast<const float4*>(&qkv[gq + c * 4]);
        rope32(q, (float)tid);
    }
    __syncthreads();
    alignas(16) float o[32];
    const float inv = online_attn<64>(Ks, Vs, q, o);
    const int b = w >> 8, tb = (w >> 3) & 31, fb = w & 7;
    const int t = tb * 8 + (tid >> 3), f = fb * 8 + (tid & 7);
    float* op = &out[((size_t)((b * 256 + t) * 64 + f)) * 256 + h * 32];
#pragma unroll
    for (int e = 0; e < 32; e += 4) {
        *reinterpret_cast<float4*>(&op[e]) =
            make_float4(o[e] * inv, o[e + 1] * inv, o[e + 2] * inv, o[e + 3] * inv);
    }
}

// ---------------------------------------------------------------- launch
// Workspace budget (floats): wsAct 16.78M + qkv chunk 6.29M = 23.07M = 92.3 MB.
// d_out doubles as scratch: X1 (b,f,t) rows, then X3 (w,p) rows, then final output.
extern "C" void kernel_launch(void* const* d_in, const int* in_sizes, int n_in,
                              void* d_out, int out_size, void* d_ws, size_t ws_size,
                              hipStream_t stream) {
    const float* x  = (const float*)d_in[0];
    const float* W1 = (const float*)d_in[1];
    const float* W2 = (const float*)d_in[2];
    const float* W3 = (const float*)d_in[3];
    const float* Wp = (const float*)d_in[4];
    float* out = (float*)d_out;

    const size_t M = (size_t)B_ * T_ * F_;   // 65536 tokens
    float* wsAct = (float*)d_ws;             // M * 256 floats
    float* qkvC  = wsAct + M * 256;          // CHUNK_TOK * 768 floats

    float* X1 = out;     // (b,f,t) rows, stage-1 GEMM input
    float* X2 = wsAct;   // (b,t,f) rows, stage-1 attn output
    float* X3 = out;     // (w,p)  rows, stage-2 attn output
    float* X4 = wsAct;   // (b,t,f) rows, stage-3 attn output

    // stage 0: gather x -> (b,f,t) rows (into d_out scratch)
    transpose_in<<<dim3(D_ / 32, F_ / 32, B_ * T_), dim3(32, 8), 0, stream>>>(x, X1);

    // stage 1: time attention (8 chunks x 32 sequences x 256 tokens)
    for (int c = 0; c < 8; ++c) {
        const float* Ain = X1 + (size_t)c * CHUNK_TOK * 256;
        gemm_f32<<<dim3(CHUNK_TOK / 64, 768 / 64), 256, 0, stream>>>(
            Ain, W1, qkvC, CHUNK_TOK, 768, 256);
        attn_s1<<<dim3(H_, 32), 256, 0, stream>>>(qkvC, X2, c * 32);
    }

    // stage 2: freq attention (8 chunks x 128 sequences x 64 tokens)
    for (int c = 0; c < 8; ++c) {
        const float* Ain = X2 + (size_t)c * CHUNK_TOK * 256;
        gemm_f32<<<dim3(CHUNK_TOK / 64, 768 / 64), 256, 0, stream>>>(
            Ain, W2, qkvC, CHUNK_TOK, 768, 256);
        attn_s2<<<dim3(H_, 128), 64, 0, stream>>>(qkvC, X3, c * 128);
    }

    // stage 3: windowed attention (8 chunks x 128 windows x 64 tokens)
    for (int c = 0; c < 8; ++c) {
        const float* Ain = X3 + (size_t)c * CHUNK_TOK * 256;
        gemm_f32<<<dim3(CHUNK_TOK / 64, 768 / 64), 256, 0, stream>>>(
            Ain, W3, qkvC, CHUNK_TOK, 768, 256);
        attn_s3<<<dim3(H_, 128), 64, 0, stream>>>(qkvC, X4, c * 128);
    }

    // c_proj + output transpose (8 chunks x 128 (b,t) groups)
    for (int c = 0; c < 8; ++c) {
        const float* Ain = X4 + (size_t)c * CHUNK_TOK * 256;
        gemm_f32<<<dim3(CHUNK_TOK / 64, 256 / 64), 256, 0, stream>>>(
            Ain, Wp, qkvC, CHUNK_TOK, 256, 256);
        transpose_out<<<dim3(D_ / 32, F_ / 32, 128), dim3(32, 8), 0, stream>>>(
            qkvC, out, c * 128);
    }
}

// Round 3
// 1102.817 us; speedup vs baseline: 2.0589x; 2.0589x over previous
//
#include <hip/hip_runtime.h>
#include <math.h>

#define B_  4
#define D_  256
#define T_  256
#define F_  64
#define H_  8

#define LN10000 9.210340371976184f
#define SM_SCALE 0.17677669529663687f   // 1/sqrt(32)

typedef float f32x4 __attribute__((ext_vector_type(4)));
typedef short s16x8 __attribute__((ext_vector_type(8)));

// ---------------------------------------------------------------- bf16 split helpers
__device__ __forceinline__ unsigned short f2bf(float x) {
    unsigned u = __float_as_uint(x);
    return (unsigned short)((u + 0x7fffu + ((u >> 16) & 1u)) >> 16);
}
__device__ __forceinline__ float bf2f(unsigned short h) {
    return __uint_as_float(((unsigned)h) << 16);
}

// Activation "image" layout (A operand of all GEMMs), per 128-token block and
// 64-feature k-step: 32KB = [hi 16KB | lo 16KB]; within: row-major [128][64]
// bf16 with byte-offset XOR-swizzle ((row&7)<<4). Token t, head-dim feature d:
//   blk = (t>>7)*4 + (d>>6); row = t&127; byte = ((d&63)*2) ^ ((row&7)<<4)
__device__ __forceinline__ void write_img(char* __restrict__ X, int tok, int h,
                                          const float* __restrict__ o, float inv) {
    const int rloc = tok & 127;
    char* base = X + ((size_t)((tok >> 7) * 4 + (h >> 1))) * 32768;
    const int bb = (h & 1) * 64;
    const int sw = (rloc & 7) << 4;
#pragma unroll
    for (int s = 0; s < 4; ++s) {
        s16x8 hi, lo;
#pragma unroll
        for (int e = 0; e < 8; ++e) {
            float v = o[s * 8 + e] * inv;
            unsigned short hb = f2bf(v);
            hi[e] = (short)hb;
            lo[e] = (short)f2bf(v - bf2f(hb));
        }
        const int off = rloc * 128 + ((bb + s * 16) ^ sw);
        *(s16x8*)(base + off) = hi;
        *(s16x8*)(base + 16384 + off) = lo;
    }
}

// ---------------------------------------------------------------- RoPE helpers
__device__ __forceinline__ float2 rope_pair(float x0, float x1, int pairIdx, float pos) {
    float freq = __expf(-(float)(2 * pairIdx) * (LN10000 / 32.0f));
    float ang = pos * freq;
    float s, c;
    __sincosf(ang, &s, &c);
    return make_float2(x0 * c - x1 * s, x1 * c + x0 * s);
}

__device__ __forceinline__ void rope32(float* x, float pos) {
#pragma unroll
    for (int i = 0; i < 16; ++i) {
        float freq = __expf(-(float)(2 * i) * (LN10000 / 32.0f));
        float ang = pos * freq;
        float s, c;
        __sincosf(ang, &s, &c);
        float x0 = x[2 * i], x1 = x[2 * i + 1];
        x[2 * i]     = x0 * c - x1 * s;
        x[2 * i + 1] = x1 * c + x0 * s;
    }
}

// ---------------------------------------------------------------- weight split
// W (64k x 128n fp32 tile) -> image block (nb*4+ks)*32KB, [n][k] bf16 hi/lo, swizzled
__global__ __launch_bounds__(256) void split_w(const float* __restrict__ W,
                                               char* __restrict__ img, int N) {
    __shared__ float Wt[64][132];
    const int nb = blockIdx.x, ks = blockIdx.y;
    const int tid = threadIdx.x;
#pragma unroll
    for (int j = 0; j < 8; ++j) {
        int idx = j * 1024 + tid * 4;
        int r = idx >> 7, cidx = idx & 127;
        const float4 v = *reinterpret_cast<const float4*>(
            &W[(size_t)(ks * 64 + r) * N + nb * 128 + cidx]);
        Wt[r][cidx] = v.x; Wt[r][cidx + 1] = v.y;
        Wt[r][cidx + 2] = v.z; Wt[r][cidx + 3] = v.w;
    }
    __syncthreads();
    char* base = img + ((size_t)(nb * 4 + ks)) * 32768;
#pragma unroll
    for (int i = 0; i < 4; ++i) {
        int p = i * 256 + tid;
        int n = p >> 3, seg = p & 7;
        s16x8 hi, lo;
#pragma unroll
        for (int e = 0; e < 8; ++e) {
            float v = Wt[seg * 8 + e][n];
            unsigned short hb = f2bf(v);
            hi[e] = (short)hb;
            lo[e] = (short)f2bf(v - bf2f(hb));
        }
        int off = n * 128 + ((seg * 16) ^ ((n & 7) << 4));
        *(s16x8*)(base + off) = hi;
        *(s16x8*)(base + 16384 + off) = lo;
    }
}

// ---------------------------------------------------------------- input transpose
// x (B, D, T, F) -> X image with tokens ordered (b, f, t)
__global__ __launch_bounds__(256) void transpose_in(const float* __restrict__ x,
                                                    char* __restrict__ Ximg) {
    __shared__ float tile[32][33];
    const int bt = blockIdx.z, b = bt >> 8, t = bt & 255;
    const int d0 = blockIdx.x * 32, f0 = blockIdx.y * 32;
    const int tx = threadIdx.x, ty = threadIdx.y;   // (32, 8)
    const size_t xbase = (size_t)b * D_ * T_ * F_ + (size_t)t * F_;
#pragma unroll
    for (int j = 0; j < 4; ++j) {
        int d = d0 + ty + j * 8;
        tile[ty + j * 8][tx] = x[xbase + (size_t)d * T_ * F_ + f0 + tx];
    }
    __syncthreads();
    const int tok = (b * 64 + f0 + tx) * 256 + t;
    const int rloc = tok & 127;
    const int hl = ty >> 2, seg = ty & 3;
    char* base = Ximg + ((size_t)((tok >> 7) * 4 + (d0 >> 6))) * 32768 + hl * 16384;
    const int off = rloc * 128 + ((((d0 & 32) << 1) + seg * 16) ^ ((rloc & 7) << 4));
    s16x8 v;
#pragma unroll
    for (int e = 0; e < 8; ++e) {
        float xv = tile[seg * 8 + e][tx];
        unsigned short hb = f2bf(xv);
        v[e] = hl ? (short)f2bf(xv - bf2f(hb)) : (short)hb;
    }
    *(s16x8*)(base + off) = v;
}

// y chunk rows ordered (bt_local, f), cols d -> out (B, D, T, F) for bt = bt0+z
__global__ __launch_bounds__(256) void transpose_out(const float* __restrict__ y,
                                                     float* __restrict__ out, int bt0) {
    __shared__ float tile[32][33];
    const int btl = blockIdx.z;
    const int bt = bt0 + btl, b = bt >> 8, t = bt & 255;
    const int d0 = blockIdx.x * 32, f0 = blockIdx.y * 32;
    const int tx = threadIdx.x, ty = threadIdx.y;
    const size_t ybase = (size_t)btl * F_ * D_;
#pragma unroll
    for (int j = 0; j < 4; ++j) {
        int f = f0 + ty + j * 8;
        tile[ty + j * 8][tx] = y[ybase + (size_t)f * D_ + d0 + tx];
    }
    __syncthreads();
    const size_t obase = (size_t)b * D_ * T_ * F_ + (size_t)t * F_;
#pragma unroll
    for (int j = 0; j < 4; ++j) {
        int d = d0 + ty + j * 8;
        out[obase + (size_t)d * T_ * F_ + f0 + tx] = tile[tx][ty + j * 8];
    }
}

// ---------------------------------------------------------------- bf16x3 MFMA GEMM
// C (Mx N fp32) = A(img) @ B(img), K = 256 (4 ksteps of 64). Tile 128x128, 4 waves.
__global__ __launch_bounds__(256) void gemm_bf16x3(const char* __restrict__ Aimg,
                                                   const char* __restrict__ Bimg,
                                                   float* __restrict__ C, int N) {
    __shared__ alignas(16) char lds[65536];   // Ah|Al (32KB) + Bh|Bl (32KB)
    const int tid = threadIdx.x, lane = tid & 63, wave = tid >> 6;
    const int wm = wave >> 1, wn = wave & 1;
    const int rlo = lane & 15, rg = lane >> 4;
    f32x4 acc[4][4] = {};
    for (int ks = 0; ks < 4; ++ks) {
        const char* ga = Aimg + ((size_t)(blockIdx.x * 4 + ks)) * 32768 + wave * 8192 + lane * 16;
        const char* gb = Bimg + ((size_t)(blockIdx.y * 4 + ks)) * 32768 + wave * 8192 + lane * 16;
        char* la = lds + wave * 8192;
        char* lb = lds + 32768 + wave * 8192;
#pragma unroll
        for (int i = 0; i < 8; ++i) {
            __builtin_amdgcn_global_load_lds(
                (const __attribute__((address_space(1))) void*)(ga + i * 1024),
                (__attribute__((address_space(3))) void*)(la + i * 1024), 16, 0, 0);
            __builtin_amdgcn_global_load_lds(
                (const __attribute__((address_space(1))) void*)(gb + i * 1024),
                (__attribute__((address_space(3))) void*)(lb + i * 1024), 16, 0, 0);
        }
        __syncthreads();
#pragma unroll
        for (int kk = 0; kk < 2; ++kk) {
            s16x8 ah[4], al[4], bh[4], bl[4];
#pragma unroll
            for (int i = 0; i < 4; ++i) {
                const int ra = wm * 64 + i * 16 + rlo;
                const int ka = (kk * 64 + rg * 16) ^ ((ra & 7) << 4);
                ah[i] = *(const s16x8*)(lds + ra * 128 + ka);
                al[i] = *(const s16x8*)(lds + 16384 + ra * 128 + ka);
                const int rb = wn * 64 + i * 16 + rlo;
                const int kb = (kk * 64 + rg * 16) ^ ((rb & 7) << 4);
                bh[i] = *(const s16x8*)(lds + 32768 + rb * 128 + kb);
                bl[i] = *(const s16x8*)(lds + 49152 + rb * 128 + kb);
            }
#pragma unroll
            for (int mt = 0; mt < 4; ++mt)
#pragma unroll
                for (int nt = 0; nt < 4; ++nt) {
                    acc[mt][nt] = __builtin_amdgcn_mfma_f32_16x16x32_bf16(ah[mt], bh[nt], acc[mt][nt], 0, 0, 0);
                    acc[mt][nt] = __builtin_amdgcn_mfma_f32_16x16x32_bf16(ah[mt], bl[nt], acc[mt][nt], 0, 0, 0);
                    acc[mt][nt] = __builtin_amdgcn_mfma_f32_16x16x32_bf16(al[mt], bh[nt], acc[mt][nt], 0, 0, 0);
                }
        }
        __syncthreads();
    }
    const int row0 = blockIdx.x * 128 + wm * 64, col0 = blockIdx.y * 128 + wn * 64;
#pragma unroll
    for (int mt = 0; mt < 4; ++mt)
#pragma unroll
        for (int nt = 0; nt < 4; ++nt)
#pragma unroll
            for (int r = 0; r < 4; ++r)
                C[(size_t)(row0 + mt * 16 + rg * 4 + r) * N + col0 + nt * 16 + rlo] =
                    acc[mt][nt][r];
}

// ---------------------------------------------------------------- online softmax core
template <int SEQ>
__device__ __forceinline__ float online_attn(const float* __restrict__ Ks,
                                             const float* __restrict__ Vs,
                                             const float* __restrict__ q,
                                             float* __restrict__ o) {
    float m = -INFINITY, lsum = 0.f;
#pragma unroll
    for (int e = 0; e < 32; ++e) o[e] = 0.f;
    for (int j = 0; j < SEQ; ++j) {
        const float* kr = &Ks[j * 32];
        float s = 0.f;
#pragma unroll
        for (int e = 0; e < 32; ++e) s = fmaf(q[e], kr[e], s);
        s *= SM_SCALE;
        const float mn = fmaxf(m, s);
        const float corr = __expf(m - mn);
        const float p = __expf(s - mn);
        lsum = lsum * corr + p;
        const float* vr = &Vs[j * 32];
#pragma unroll
        for (int e = 0; e < 32; ++e) o[e] = fmaf(o[e], corr, p * vr[e]);
        m = mn;
    }
    return 1.0f / lsum;
}

// ---------------------------------------------------------------- stage 1 attention
__global__ __launch_bounds__(256) void attn_s1(const float* __restrict__ qkv,
                                               char* __restrict__ Ximg, int s0) {
    __shared__ alignas(16) float Ks[256 * 32];
    __shared__ alignas(16) float Vs[256 * 32];
    const int h = blockIdx.x;
    const int sl = blockIdx.y;
    const int s = s0 + sl;               // b*F + f
    const int b = s >> 6, f = s & 63;
    const int tid = threadIdx.x;
#pragma unroll
    for (int i = 0; i < 8; ++i) {
        const int l = i * 256 + tid;
        const int row = l >> 3, c = l & 7;
        const size_t g = ((size_t)(sl * 256 + row)) * 768 + h * 32 + c * 4;
        const float4 kv = *reinterpret_cast<const float4*>(&qkv[g + 256]);
        const float4 vv = *reinterpret_cast<const float4*>(&qkv[g + 512]);
        const float2 r0 = rope_pair(kv.x, kv.y, c * 2, (float)row);
        const float2 r1 = rope_pair(kv.z, kv.w, c * 2 + 1, (float)row);
        *reinterpret_cast<float4*>(&Ks[row * 32 + c * 4]) = make_float4(r0.x, r0.y, r1.x, r1.y);
        *reinterpret_cast<float4*>(&Vs[row * 32 + c * 4]) = vv;
    }
    alignas(16) float q[32];
    {
        const size_t gq = ((size_t)(sl * 256 + tid)) * 768 + h * 32;
#pragma unroll
        for (int c = 0; c < 8; ++c)
            *reinterpret_cast<float4*>(&q[c * 4]) =
                *reinterpret_cast<const float4*>(&qkv[gq + c * 4]);
        rope32(q, (float)tid);
    }
    __syncthreads();
    alignas(16) float o[32];
    const float inv = online_attn<256>(Ks, Vs, q, o);
    const int tok = (b * 256 + tid) * 64 + f;    // (b,t,f)
    write_img(Ximg, tok, h, o, inv);
}

// ---------------------------------------------------------------- stage 2 attention
__global__ __launch_bounds__(64) void attn_s2(const float* __restrict__ qkv,
                                              char* __restrict__ Ximg, int s20) {
    __shared__ alignas(16) float Ks[64 * 32];
    __shared__ alignas(16) float Vs[64 * 32];
    const int h = blockIdx.x;
    const int sl = blockIdx.y;
    const int s2 = s20 + sl;             // b*T + t
    const int b = s2 >> 8, t = s2 & 255;
    const int tid = threadIdx.x;         // = f for the query
#pragma unroll
    for (int i = 0; i < 8; ++i) {
        const int l = i * 64 + tid;
        const int row = l >> 3, c = l & 7;
        const size_t g = ((size_t)(sl * 64 + row)) * 768 + h * 32 + c * 4;
        const float4 kv = *reinterpret_cast<const float4*>(&qkv[g + 256]);
        const float4 vv = *reinterpret_cast<const float4*>(&qkv[g + 512]);
        const float2 r0 = rope_pair(kv.x, kv.y, c * 2, (float)row);
        const float2 r1 = rope_pair(kv.z, kv.w, c * 2 + 1, (float)row);
        *reinterpret_cast<float4*>(&Ks[row * 32 + c * 4]) = make_float4(r0.x, r0.y, r1.x, r1.y);
        *reinterpret_cast<float4*>(&Vs[row * 32 + c * 4]) = vv;
    }
    alignas(16) float q[32];
    {
        const size_t gq = ((size_t)(sl * 64 + tid)) * 768 + h * 32;
#pragma unroll
        for (int c = 0; c < 8; ++c)
            *reinterpret_cast<float4*>(&q[c * 4]) =
                *reinterpret_cast<const float4*>(&qkv[gq + c * 4]);
        rope32(q, (float)tid);
    }
    __syncthreads();
    alignas(16) float o[32];
    const float inv = online_attn<64>(Ks, Vs, q, o);
    const int fq = tid;
    const int w = (b * 32 + (t >> 3)) * 8 + (fq >> 3);
    const int p = (t & 7) * 8 + (fq & 7);
    write_img(Ximg, w * 64 + p, h, o, inv);      // (w,p)
}

// ---------------------------------------------------------------- stage 3 attention
__global__ __launch_bounds__(64) void attn_s3(const float* __restrict__ qkv,
                                              char* __restrict__ Ximg, int w0) {
    __shared__ alignas(16) float Ks[64 * 32];
    __shared__ alignas(16) float Vs[64 * 32];
    const int h = blockIdx.x;
    const int wl = blockIdx.y;
    const int w = w0 + wl;               // 0..1023
    const int tid = threadIdx.x;         // = p for the query
#pragma unroll
    for (int i = 0; i < 8; ++i) {
        const int l = i * 64 + tid;
        const int row = l >> 3, c = l & 7;
        const size_t g = ((size_t)(wl * 64 + row)) * 768 + h * 32 + c * 4;
        const float4 kv = *reinterpret_cast<const float4*>(&qkv[g + 256]);
        const float4 vv = *reinterpret_cast<const float4*>(&qkv[g + 512]);
        const float2 r0 = rope_pair(kv.x, kv.y, c * 2, (float)row);
        const float2 r1 = rope_pair(kv.z, kv.w, c * 2 + 1, (float)row);
        *reinterpret_cast<float4*>(&Ks[row * 32 + c * 4]) = make_float4(r0.x, r0.y, r1.x, r1.y);
        *reinterpret_cast<float4*>(&Vs[row * 32 + c * 4]) = vv;
    }
    alignas(16) float q[32];
    {
        const size_t gq = ((size_t)(wl * 64 + tid)) * 768 + h * 32;
#pragma unroll
        for (int c = 0; c < 8; ++c)
            *reinterpret_cast<float4*>(&q[c * 4]) =
                *reinterpret_cast<const float4*>(&qkv[gq + c * 4]);
        rope32(q, (float)tid);
    }
    __syncthreads();
    alignas(16) float o[32];
    const float inv = online_attn<64>(Ks, Vs, q, o);
    const int b = w >> 8, tb = (w >> 3) & 31, fb = w & 7;
    const int t = tb * 8 + (tid >> 3), f = fb * 8 + (tid & 7);
    write_img(Ximg, (b * 256 + t) * 64 + f, h, o, inv);   // (b,t,f)
}

// ---------------------------------------------------------------- launch
extern "C" void kernel_launch(void* const* d_in, const int* in_sizes, int n_in,
                              void* d_out, int out_size, void* d_ws, size_t ws_size,
                              hipStream_t stream) {
    const float* x  = (const float*)d_in[0];
    const float* W1 = (const float*)d_in[1];
    const float* W2 = (const float*)d_in[2];
    const float* W3 = (const float*)d_in[3];
    const float* Wp = (const float*)d_in[4];
    float* out = (float*)d_out;

    const size_t M = (size_t)B_ * T_ * F_;        // 65536 tokens
    char* Xa = (char*)d_out;                      // image buffer A (X1, X3) — 67.1MB
    char* Xb = (char*)d_ws;                       // image buffer B (X2, X4) — 67.1MB
    char* W1i = (char*)d_ws + M * 1024;           // weight images: 3x768KB + 256KB
    char* W2i = W1i + 786432;
    char* W3i = W2i + 786432;
    char* Wpi = W3i + 786432;
    float* qkvC = (float*)(Wpi + 262144);

    // adaptive chunk size (tokens) by available workspace
    const size_t fixedBytes = M * 1024 + 3 * 786432 + 262144;
    int CH = 2048;
    const int cands[5] = {65536, 32768, 16384, 8192, 4096};
    for (int i = 0; i < 5; ++i) {
        if (fixedBytes + (size_t)cands[i] * 768 * 4 <= ws_size) { CH = cands[i]; break; }
    }
    const int NC = (int)(M / CH);

    // weight preprocessing (once per launch)
    split_w<<<dim3(6, 4), 256, 0, stream>>>(W1, W1i, 768);
    split_w<<<dim3(6, 4), 256, 0, stream>>>(W2, W2i, 768);
    split_w<<<dim3(6, 4), 256, 0, stream>>>(W3, W3i, 768);
    split_w<<<dim3(2, 4), 256, 0, stream>>>(Wp, Wpi, 256);

    // stage 0: x -> X1 image, tokens (b,f,t)
    transpose_in<<<dim3(8, 2, 1024), dim3(32, 8), 0, stream>>>(x, Xa);

    // stage 1: time attention
    for (int c = 0; c < NC; ++c) {
        gemm_bf16x3<<<dim3(CH / 128, 6), 256, 0, stream>>>(
            Xa + (size_t)c * CH * 1024, W1i, qkvC, 768);
        attn_s1<<<dim3(H_, CH / 256), 256, 0, stream>>>(qkvC, Xb, c * (CH / 256));
    }
    // stage 2: freq attention
    for (int c = 0; c < NC; ++c) {
        gemm_bf16x3<<<dim3(CH / 128, 6), 256, 0, stream>>>(
            Xb + (size_t)c * CH * 1024, W2i, qkvC, 768);
        attn_s2<<<dim3(H_, CH / 64), 64, 0, stream>>>(qkvC, Xa, c * (CH / 64));
    }
    // stage 3: windowed attention
    for (int c = 0; c < NC; ++c) {
        gemm_bf16x3<<<dim3(CH / 128, 6), 256, 0, stream>>>(
            Xa + (size_t)c * CH * 1024, W3i, qkvC, 768);
        attn_s3<<<dim3(H_, CH / 64), 64, 0, stream>>>(qkvC, Xb, c * (CH / 64));
    }
    // c_proj + output transpose
    for (int c = 0; c < NC; ++c) {
        gemm_bf16x3<<<dim3(CH / 128, 2), 256, 0, stream>>>(
            Xb + (size_t)c * CH * 1024, Wpi, qkvC, 256);
        transpose_out<<<dim3(8, 2, CH / 64), dim3(32, 8), 0, stream>>>(
            qkvC, out, c * (CH / 64));
    }
}

// Round 4
// 612.470 us; speedup vs baseline: 3.7073x; 1.8006x over previous
//
#include <hip/hip_runtime.h>
#include <math.h>

#define B_  4
#define D_  256
#define T_  256
#define F_  64
#define H_  8

#define LN10000 9.210340371976184f
#define SM_SCALE 0.17677669529663687f   // 1/sqrt(32)

typedef float f32x4 __attribute__((ext_vector_type(4)));
typedef short s16x8 __attribute__((ext_vector_type(8)));

// ---------------------------------------------------------------- bf16 helpers
__device__ __forceinline__ unsigned short f2bf(float x) {
    unsigned u = __float_as_uint(x);
    return (unsigned short)((u + 0x7fffu + ((u >> 16) & 1u)) >> 16);
}
__device__ __forceinline__ float bf2f(unsigned short h) {
    return __uint_as_float(((unsigned)h) << 16);
}
__device__ __forceinline__ unsigned cvt_pk_bf16(float a, float b) {
    unsigned r;
    asm("v_cvt_pk_bf16_f32 %0, %1, %2" : "=v"(r) : "v"(a), "v"(b));
    return r;   // lo16 = bf16(a), hi16 = bf16(b)
}

// ---------------------------------------------------------------- RoPE helper
__device__ __forceinline__ float2 rope_pair(float x0, float x1, int pairIdx, float pos) {
    float freq = __expf(-(float)(2 * pairIdx) * (LN10000 / 32.0f));
    float ang = pos * freq;
    float s, c;
    __sincosf(ang, &s, &c);
    return make_float2(x0 * c - x1 * s, x1 * c + x0 * s);
}

// ---------------------------------------------------------------- weight split
// W (64k x 128n fp32 tile) -> image block (nb*4+ks)*32KB, [n][k] bf16 hi/lo, swizzled
__global__ __launch_bounds__(256) void split_w(const float* __restrict__ W,
                                               char* __restrict__ img, int N) {
    __shared__ float Wt[64][132];
    const int nb = blockIdx.x, ks = blockIdx.y;
    const int tid = threadIdx.x;
#pragma unroll
    for (int j = 0; j < 8; ++j) {
        int idx = j * 1024 + tid * 4;
        int r = idx >> 7, cidx = idx & 127;
        const float4 v = *reinterpret_cast<const float4*>(
            &W[(size_t)(ks * 64 + r) * N + nb * 128 + cidx]);
        Wt[r][cidx] = v.x; Wt[r][cidx + 1] = v.y;
        Wt[r][cidx + 2] = v.z; Wt[r][cidx + 3] = v.w;
    }
    __syncthreads();
    char* base = img + ((size_t)(nb * 4 + ks)) * 32768;
#pragma unroll
    for (int i = 0; i < 4; ++i) {
        int p = i * 256 + tid;
        int n = p >> 3, seg = p & 7;
        s16x8 hi, lo;
#pragma unroll
        for (int e = 0; e < 8; ++e) {
            float v = Wt[seg * 8 + e][n];
            unsigned short hb = f2bf(v);
            hi[e] = (short)hb;
            lo[e] = (short)f2bf(v - bf2f(hb));
        }
        int off = n * 128 + ((seg * 16) ^ ((n & 7) << 4));
        *(s16x8*)(base + off) = hi;
        *(s16x8*)(base + 16384 + off) = lo;
    }
}

// ---------------------------------------------------------------- input transpose
// x (B, D, T, F) -> X image with tokens ordered (b, f, t)
__global__ __launch_bounds__(256) void transpose_in(const float* __restrict__ x,
                                                    char* __restrict__ Ximg) {
    __shared__ float tile[32][33];
    const int bt = blockIdx.z, b = bt >> 8, t = bt & 255;
    const int d0 = blockIdx.x * 32, f0 = blockIdx.y * 32;
    const int tx = threadIdx.x, ty = threadIdx.y;   // (32, 8)
    const size_t xbase = (size_t)b * D_ * T_ * F_ + (size_t)t * F_;
#pragma unroll
    for (int j = 0; j < 4; ++j) {
        int d = d0 + ty + j * 8;
        tile[ty + j * 8][tx] = x[xbase + (size_t)d * T_ * F_ + f0 + tx];
    }
    __syncthreads();
    const int tok = (b * 64 + f0 + tx) * 256 + t;
    const int rloc = tok & 127;
    const int hl = ty >> 2, seg = ty & 3;
    char* base = Ximg + ((size_t)((tok >> 7) * 4 + (d0 >> 6))) * 32768 + hl * 16384;
    const int off = rloc * 128 + ((((d0 & 32) << 1) + seg * 16) ^ ((rloc & 7) << 4));
    s16x8 v;
#pragma unroll
    for (int e = 0; e < 8; ++e) {
        float xv = tile[seg * 8 + e][tx];
        unsigned short hb = f2bf(xv);
        v[e] = hl ? (short)f2bf(xv - bf2f(hb)) : (short)hb;
    }
    *(s16x8*)(base + off) = v;
}

// y chunk rows ordered (bt_local, f), cols d -> out (B, D, T, F) for bt = bt0+z
__global__ __launch_bounds__(256) void transpose_out(const float* __restrict__ y,
                                                     float* __restrict__ out, int bt0) {
    __shared__ float tile[32][33];
    const int btl = blockIdx.z;
    const int bt = bt0 + btl, b = bt >> 8, t = bt & 255;
    const int d0 = blockIdx.x * 32, f0 = blockIdx.y * 32;
    const int tx = threadIdx.x, ty = threadIdx.y;
    const size_t ybase = (size_t)btl * F_ * D_;
#pragma unroll
    for (int j = 0; j < 4; ++j) {
        int f = f0 + ty + j * 8;
        tile[ty + j * 8][tx] = y[ybase + (size_t)f * D_ + d0 + tx];
    }
    __syncthreads();
    const size_t obase = (size_t)b * D_ * T_ * F_ + (size_t)t * F_;
#pragma unroll
    for (int j = 0; j < 4; ++j) {
        int d = d0 + ty + j * 8;
        out[obase + (size_t)d * T_ * F_ + f0 + tx] = tile[tx][ty + j * 8];
    }
}

// ---------------------------------------------------------------- bf16x3 MFMA GEMM
__global__ __launch_bounds__(256) void gemm_bf16x3(const char* __restrict__ Aimg,
                                                   const char* __restrict__ Bimg,
                                                   float* __restrict__ C, int N) {
    __shared__ alignas(16) char lds[65536];   // Ah|Al (32KB) + Bh|Bl (32KB)
    const int tid = threadIdx.x, lane = tid & 63, wave = tid >> 6;
    const int wm = wave >> 1, wn = wave & 1;
    const int rlo = lane & 15, rg = lane >> 4;
    f32x4 acc[4][4] = {};
    for (int ks = 0; ks < 4; ++ks) {
        const char* ga = Aimg + ((size_t)(blockIdx.x * 4 + ks)) * 32768 + wave * 8192 + lane * 16;
        const char* gb = Bimg + ((size_t)(blockIdx.y * 4 + ks)) * 32768 + wave * 8192 + lane * 16;
        char* la = lds + wave * 8192;
        char* lb = lds + 32768 + wave * 8192;
#pragma unroll
        for (int i = 0; i < 8; ++i) {
            __builtin_amdgcn_global_load_lds(
                (const __attribute__((address_space(1))) void*)(ga + i * 1024),
                (__attribute__((address_space(3))) void*)(la + i * 1024), 16, 0, 0);
            __builtin_amdgcn_global_load_lds(
                (const __attribute__((address_space(1))) void*)(gb + i * 1024),
                (__attribute__((address_space(3))) void*)(lb + i * 1024), 16, 0, 0);
        }
        __syncthreads();
#pragma unroll
        for (int kk = 0; kk < 2; ++kk) {
            s16x8 ah[4], al[4], bh[4], bl[4];
#pragma unroll
            for (int i = 0; i < 4; ++i) {
                const int ra = wm * 64 + i * 16 + rlo;
                const int ka = (kk * 64 + rg * 16) ^ ((ra & 7) << 4);
                ah[i] = *(const s16x8*)(lds + ra * 128 + ka);
                al[i] = *(const s16x8*)(lds + 16384 + ra * 128 + ka);
                const int rb = wn * 64 + i * 16 + rlo;
                const int kb = (kk * 64 + rg * 16) ^ ((rb & 7) << 4);
                bh[i] = *(const s16x8*)(lds + 32768 + rb * 128 + kb);
                bl[i] = *(const s16x8*)(lds + 49152 + rb * 128 + kb);
            }
#pragma unroll
            for (int mt = 0; mt < 4; ++mt)
#pragma unroll
                for (int nt = 0; nt < 4; ++nt) {
                    acc[mt][nt] = __builtin_amdgcn_mfma_f32_16x16x32_bf16(ah[mt], bh[nt], acc[mt][nt], 0, 0, 0);
                    acc[mt][nt] = __builtin_amdgcn_mfma_f32_16x16x32_bf16(ah[mt], bl[nt], acc[mt][nt], 0, 0, 0);
                    acc[mt][nt] = __builtin_amdgcn_mfma_f32_16x16x32_bf16(al[mt], bh[nt], acc[mt][nt], 0, 0, 0);
                }
        }
        __syncthreads();
    }
    const int row0 = blockIdx.x * 128 + wm * 64, col0 = blockIdx.y * 128 + wn * 64;
#pragma unroll
    for (int mt = 0; mt < 4; ++mt)
#pragma unroll
        for (int nt = 0; nt < 4; ++nt)
#pragma unroll
            for (int r = 0; r < 4; ++r)
                C[(size_t)(row0 + mt * 16 + rg * 4 + r) * N + col0 + nt * 16 + rlo] =
                    acc[mt][nt][r];
}

// ---------------------------------------------------------------- MFMA attention
// STAGE=1: L=256, 1 head/block. STAGE=2/3: L=64, 2 heads/block.
// Per wave-pass (16 q): swapped QK^T (S = K·Q^T), online softmax in fragment
// space, bpermute P->PV A-frag, PV accumulates O[16q x 32d]. Output written
// as hi/lo bf16 swizzled image (GEMM A-operand format).
template <int STAGE>
__global__ __launch_bounds__(256) void attn_mfma(const float* __restrict__ qkv,
                                                 char* __restrict__ Ximg, int s0) {
    constexpr int L   = (STAGE == 1) ? 256 : 64;
    constexpr int HPB = (STAGE == 1) ? 1 : 2;
    constexpr int NCH = L / 32;
    constexpr int KFB = L * 64;            // Kf bytes per head (= Vf bytes)
    __shared__ alignas(16) char kvLds[HPB * 2 * KFB];
    __shared__ alignas(16) float Osc[4][16][36];
    const int tid = threadIdx.x, lane = tid & 63, wave = tid >> 6;
    const int sl = blockIdx.y;

    // ---- stage K (rope'd) and V into fragment-ordered LDS ----
    {
        const int nIter = (STAGE == 1) ? 2 : 1;
#pragma unroll
        for (int it = 0; it < nIter; ++it) {
            int idx, headl;
            if (STAGE == 1) { idx = it * 256 + tid; headl = 0; }
            else            { idx = tid & 127;      headl = tid >> 7; }
            const int k = idx >> 1, dh = idx & 1;
            const int h = blockIdx.x * HPB + headl;
            const size_t grow = ((size_t)(sl * L + k)) * 768 + h * 32 + dh * 16;
            float kvv[16], vvv[16];
            *(float4*)&kvv[0]  = *(const float4*)&qkv[grow + 256];
            *(float4*)&kvv[4]  = *(const float4*)&qkv[grow + 260];
            *(float4*)&kvv[8]  = *(const float4*)&qkv[grow + 264];
            *(float4*)&kvv[12] = *(const float4*)&qkv[grow + 268];
            *(float4*)&vvv[0]  = *(const float4*)&qkv[grow + 512];
            *(float4*)&vvv[4]  = *(const float4*)&qkv[grow + 516];
            *(float4*)&vvv[8]  = *(const float4*)&qkv[grow + 520];
            *(float4*)&vvv[12] = *(const float4*)&qkv[grow + 524];
#pragma unroll
            for (int j = 0; j < 8; ++j) {
                float2 r = rope_pair(kvv[2 * j], kvv[2 * j + 1], dh * 8 + j, (float)k);
                kvv[2 * j] = r.x; kvv[2 * j + 1] = r.y;
            }
            char* kf = kvLds + headl * 2 * KFB;
#pragma unroll
            for (int jg = 0; jg < 2; ++jg) {
                s16x8 w;
#pragma unroll
                for (int e = 0; e < 8; ++e) w[e] = (short)f2bf(kvv[jg * 8 + e]);
                *(s16x8*)(kf + ((k >> 4) * 64 + (k & 15) + 16 * (dh * 2 + jg)) * 16) = w;
            }
            // V fragment: value V[k][d] -> subblock (k>>5)*2+dh, lane (d&15)+16*((k>>3)&3), elem k&7
            char* vf = kvLds + headl * 2 * KFB + KFB;
            const int sb = (k >> 5) * 2 + dh;
            const int lgo = 16 * ((k >> 3) & 3);
            const int eo = (k & 7) * 2;
#pragma unroll
            for (int dp = 0; dp < 16; ++dp)
                *(unsigned short*)(vf + sb * 1024 + (dp + lgo) * 16 + eo) = f2bf(vvv[dp]);
        }
    }
    __syncthreads();

    // ---- compute ----
    const int headl = (STAGE == 1) ? 0 : (wave >> 1);
    const int h = blockIdx.x * HPB + headl;
    const char* Kf = kvLds + headl * 2 * KFB;
    const char* Vf = Kf + KFB;
    const int nPass = (STAGE == 1) ? 4 : 2;
    const int addr_lo = ((lane & 15) + ((lane >> 4) & 1) * 32) * 4;
    const int addr_hi = addr_lo + 64;
    const bool hiSel = lane >= 32;

    for (int pass = 0; pass < nPass; ++pass) {
        const int qbase = (STAGE == 1) ? ((wave & 3) * 16 + pass * 64)
                                       : ((wave & 1) * 16 + pass * 32);
        const int q = qbase + (lane & 15);
        // Q fragment (rope + scale folded)
        s16x8 qf;
        {
            float qv[8];
            const size_t qrow = ((size_t)(sl * L + q)) * 768 + h * 32 + (lane >> 4) * 8;
            *(float4*)&qv[0] = *(const float4*)&qkv[qrow];
            *(float4*)&qv[4] = *(const float4*)&qkv[qrow + 4];
#pragma unroll
            for (int j = 0; j < 4; ++j) {
                float2 r = rope_pair(qv[2 * j], qv[2 * j + 1], (lane >> 4) * 4 + j, (float)q);
                qf[2 * j]     = (short)f2bf(r.x * SM_SCALE);
                qf[2 * j + 1] = (short)f2bf(r.y * SM_SCALE);
            }
        }
        f32x4 olo = {0.f, 0.f, 0.f, 0.f}, ohi = {0.f, 0.f, 0.f, 0.f};
        const f32x4 zero = {0.f, 0.f, 0.f, 0.f};
        float m = -INFINITY, lsum = 0.f;
#pragma unroll
        for (int c = 0; c < NCH; ++c) {
            const s16x8 ka = *(const s16x8*)(Kf + (c * 2) * 1024 + lane * 16);
            const s16x8 kb = *(const s16x8*)(Kf + (c * 2 + 1) * 1024 + lane * 16);
            f32x4 sA = __builtin_amdgcn_mfma_f32_16x16x32_bf16(ka, qf, zero, 0, 0, 0);
            f32x4 sB = __builtin_amdgcn_mfma_f32_16x16x32_bf16(kb, qf, zero, 0, 0, 0);
            float cmax = fmaxf(fmaxf(fmaxf(sA[0], sA[1]), fmaxf(sA[2], sA[3])),
                               fmaxf(fmaxf(sB[0], sB[1]), fmaxf(sB[2], sB[3])));
            cmax = fmaxf(cmax, __shfl_xor(cmax, 16, 64));
            cmax = fmaxf(cmax, __shfl_xor(cmax, 32, 64));
            const float mnew = fmaxf(m, cmax);
            const float corr = __expf(m - mnew);
            m = mnew;
            float p[8];
#pragma unroll
            for (int e = 0; e < 4; ++e) p[e] = __expf(sA[e] - mnew);
#pragma unroll
            for (int e = 0; e < 4; ++e) p[4 + e] = __expf(sB[e] - mnew);
            float ps = ((p[0] + p[1]) + (p[2] + p[3])) + ((p[4] + p[5]) + (p[6] + p[7]));
            lsum = lsum * corr + ps;
            // pack P (bf16 pairs) per t-tile
            const int t0w0 = (int)cvt_pk_bf16(p[0], p[1]);
            const int t0w1 = (int)cvt_pk_bf16(p[2], p[3]);
            const int t1w0 = (int)cvt_pk_bf16(p[4], p[5]);
            const int t1w1 = (int)cvt_pk_bf16(p[6], p[7]);
            // redistribute into PV A-fragment
            union { int u[4]; s16x8 v; } Af;
            const int a0 = __builtin_amdgcn_ds_bpermute(addr_lo, t0w0);
            const int a1 = __builtin_amdgcn_ds_bpermute(addr_lo, t0w1);
            const int a2 = __builtin_amdgcn_ds_bpermute(addr_hi, t0w0);
            const int a3 = __builtin_amdgcn_ds_bpermute(addr_hi, t0w1);
            const int b0 = __builtin_amdgcn_ds_bpermute(addr_lo, t1w0);
            const int b1 = __builtin_amdgcn_ds_bpermute(addr_lo, t1w1);
            const int b2 = __builtin_amdgcn_ds_bpermute(addr_hi, t1w0);
            const int b3 = __builtin_amdgcn_ds_bpermute(addr_hi, t1w1);
            Af.u[0] = hiSel ? b0 : a0;
            Af.u[1] = hiSel ? b1 : a1;
            Af.u[2] = hiSel ? b2 : a2;
            Af.u[3] = hiSel ? b3 : a3;
            // rescale O by corr (per output row q = (lane>>4)*4+r)
#pragma unroll
            for (int r = 0; r < 4; ++r) {
                const float fr = __shfl(corr, (lane >> 4) * 4 + r, 64);
                olo[r] *= fr; ohi[r] *= fr;
            }
            const s16x8 va = *(const s16x8*)(Vf + (c * 2) * 1024 + lane * 16);
            const s16x8 vb = *(const s16x8*)(Vf + (c * 2 + 1) * 1024 + lane * 16);
            olo = __builtin_amdgcn_mfma_f32_16x16x32_bf16(Af.v, va, olo, 0, 0, 0);
            ohi = __builtin_amdgcn_mfma_f32_16x16x32_bf16(Af.v, vb, ohi, 0, 0, 0);
        }
        // ---- normalize + transpose via wave-private LDS ----
        lsum += __shfl_xor(lsum, 16, 64);
        lsum += __shfl_xor(lsum, 32, 64);
        const float inv = 1.0f / lsum;
#pragma unroll
        for (int r = 0; r < 4; ++r) {
            const float ir = __shfl(inv, (lane >> 4) * 4 + r, 64);
            Osc[wave][(lane >> 4) * 4 + r][lane & 15]        = olo[r] * ir;
            Osc[wave][(lane >> 4) * 4 + r][16 + (lane & 15)] = ohi[r] * ir;
        }
        const int seg = lane >> 4;
        float v8[8];
        *(float4*)&v8[0] = *(const float4*)&Osc[wave][lane & 15][seg * 8];
        *(float4*)&v8[4] = *(const float4*)&Osc[wave][lane & 15][seg * 8 + 4];
        // token mapping
        int tok;
        if constexpr (STAGE == 1) {
            const int s = s0 + sl, b = s >> 6, f = s & 63;
            tok = (b * 256 + q) * 64 + f;
        } else if constexpr (STAGE == 2) {
            const int s2 = s0 + sl, b = s2 >> 8, t = s2 & 255;
            tok = ((b * 32 + (t >> 3)) * 8 + (q >> 3)) * 64 + (t & 7) * 8 + (q & 7);
        } else {
            const int w = s0 + sl, b = w >> 8, tb = (w >> 3) & 31, fb = w & 7;
            tok = (b * 256 + tb * 8 + (q >> 3)) * 64 + fb * 8 + (q & 7);
        }
        const int rloc = tok & 127;
        char* base = Ximg + ((size_t)((tok >> 7) * 4 + (h >> 1))) * 32768;
        const int off = rloc * 128 + ((((h & 1) * 64) + seg * 16) ^ ((rloc & 7) << 4));
        s16x8 hi, lo;
#pragma unroll
        for (int e = 0; e < 8; ++e) {
            unsigned short hb = f2bf(v8[e]);
            hi[e] = (short)hb;
            lo[e] = (short)f2bf(v8[e] - bf2f(hb));
        }
        *(s16x8*)(base + off) = hi;
        *(s16x8*)(base + 16384 + off) = lo;
    }
}

// ---------------------------------------------------------------- launch
extern "C" void kernel_launch(void* const* d_in, const int* in_sizes, int n_in,
                              void* d_out, int out_size, void* d_ws, size_t ws_size,
                              hipStream_t stream) {
    const float* x  = (const float*)d_in[0];
    const float* W1 = (const float*)d_in[1];
    const float* W2 = (const float*)d_in[2];
    const float* W3 = (const float*)d_in[3];
    const float* Wp = (const float*)d_in[4];
    float* out = (float*)d_out;

    const size_t M = (size_t)B_ * T_ * F_;        // 65536 tokens
    char* Xa = (char*)d_out;                      // image buffer A (X1, X3)
    char* Xb = (char*)d_ws;                       // image buffer B (X2, X4)
    char* W1i = (char*)d_ws + M * 1024;           // weight images
    char* W2i = W1i + 786432;
    char* W3i = W2i + 786432;
    char* Wpi = W3i + 786432;
    float* qkvC = (float*)(Wpi + 262144);

    const size_t fixedBytes = M * 1024 + 3 * 786432 + 262144;
    int CH = 2048;
    const int cands[5] = {65536, 32768, 16384, 8192, 4096};
    for (int i = 0; i < 5; ++i) {
        if (fixedBytes + (size_t)cands[i] * 768 * 4 <= ws_size) { CH = cands[i]; break; }
    }
    const int NC = (int)(M / CH);

    split_w<<<dim3(6, 4), 256, 0, stream>>>(W1, W1i, 768);
    split_w<<<dim3(6, 4), 256, 0, stream>>>(W2, W2i, 768);
    split_w<<<dim3(6, 4), 256, 0, stream>>>(W3, W3i, 768);
    split_w<<<dim3(2, 4), 256, 0, stream>>>(Wp, Wpi, 256);

    transpose_in<<<dim3(8, 2, 1024), dim3(32, 8), 0, stream>>>(x, Xa);

    // stage 1: time attention (L=256)
    for (int c = 0; c < NC; ++c) {
        gemm_bf16x3<<<dim3(CH / 128, 6), 256, 0, stream>>>(
            Xa + (size_t)c * CH * 1024, W1i, qkvC, 768);
        attn_mfma<1><<<dim3(H_, CH / 256), 256, 0, stream>>>(qkvC, Xb, c * (CH / 256));
    }
    // stage 2: freq attention (L=64)
    for (int c = 0; c < NC; ++c) {
        gemm_bf16x3<<<dim3(CH / 128, 6), 256, 0, stream>>>(
            Xb + (size_t)c * CH * 1024, W2i, qkvC, 768);
        attn_mfma<2><<<dim3(H_ / 2, CH / 64), 256, 0, stream>>>(qkvC, Xa, c * (CH / 64));
    }
    // stage 3: windowed attention (L=64)
    for (int c = 0; c < NC; ++c) {
        gemm_bf16x3<<<dim3(CH / 128, 6), 256, 0, stream>>>(
            Xa + (size_t)c * CH * 1024, W3i, qkvC, 768);
        attn_mfma<3><<<dim3(H_ / 2, CH / 64), 256, 0, stream>>>(qkvC, Xb, c * (CH / 64));
    }
    // c_proj + output transpose
    for (int c = 0; c < NC; ++c) {
        gemm_bf16x3<<<dim3(CH / 128, 2), 256, 0, stream>>>(
            Xb + (size_t)c * CH * 1024, Wpi, qkvC, 256);
        transpose_out<<<dim3(8, 2, CH / 64), dim3(32, 8), 0, stream>>>(
            qkvC, out, c * (CH / 64));
    }
}

// Round 5
// 548.262 us; speedup vs baseline: 4.1415x; 1.1171x over previous
//
#include <hip/hip_runtime.h>
#include <math.h>

#define B_  4
#define D_  256
#define T_  256
#define F_  64
#define H_  8

#define LN10000 9.210340371976184f
#define SM_SCALE 0.17677669529663687f   // 1/sqrt(32)

typedef float f32x4 __attribute__((ext_vector_type(4)));
typedef short s16x8 __attribute__((ext_vector_type(8)));

// ---------------------------------------------------------------- bf16 helpers
__device__ __forceinline__ unsigned short f2bf(float x) {
    unsigned u = __float_as_uint(x);
    return (unsigned short)((u + 0x7fffu + ((u >> 16) & 1u)) >> 16);
}
__device__ __forceinline__ float bf2f(unsigned short h) {
    return __uint_as_float(((unsigned)h) << 16);
}
__device__ __forceinline__ unsigned cvt_pk_bf16(float a, float b) {
    unsigned r;
    asm("v_cvt_pk_bf16_f32 %0, %1, %2" : "=v"(r) : "v"(a), "v"(b));
    return r;   // lo16 = bf16(a), hi16 = bf16(b)
}

// ---------------------------------------------------------------- RoPE helper
__device__ __forceinline__ float2 rope_pair(float x0, float x1, int pairIdx, float pos) {
    float freq = __expf(-(float)(2 * pairIdx) * (LN10000 / 32.0f));
    float ang = pos * freq;
    float s, c;
    __sincosf(ang, &s, &c);
    return make_float2(x0 * c - x1 * s, x1 * c + x0 * s);
}

// ---------------------------------------------------------------- weight split
// W (64k x 128n fp32 tile) -> image block (nb*4+ks)*32KB, [n][k] bf16 hi/lo, swizzled
__global__ __launch_bounds__(256) void split_w(const float* __restrict__ W,
                                               char* __restrict__ img, int N) {
    __shared__ float Wt[64][132];
    const int nb = blockIdx.x, ks = blockIdx.y;
    const int tid = threadIdx.x;
#pragma unroll
    for (int j = 0; j < 8; ++j) {
        int idx = j * 1024 + tid * 4;
        int r = idx >> 7, cidx = idx & 127;
        const float4 v = *reinterpret_cast<const float4*>(
            &W[(size_t)(ks * 64 + r) * N + nb * 128 + cidx]);
        Wt[r][cidx] = v.x; Wt[r][cidx + 1] = v.y;
        Wt[r][cidx + 2] = v.z; Wt[r][cidx + 3] = v.w;
    }
    __syncthreads();
    char* base = img + ((size_t)(nb * 4 + ks)) * 32768;
#pragma unroll
    for (int i = 0; i < 4; ++i) {
        int p = i * 256 + tid;
        int n = p >> 3, seg = p & 7;
        s16x8 hi, lo;
#pragma unroll
        for (int e = 0; e < 8; ++e) {
            float v = Wt[seg * 8 + e][n];
            unsigned short hb = f2bf(v);
            hi[e] = (short)hb;
            lo[e] = (short)f2bf(v - bf2f(hb));
        }
        int off = n * 128 + ((seg * 16) ^ ((n & 7) << 4));
        *(s16x8*)(base + off) = hi;
        *(s16x8*)(base + 16384 + off) = lo;
    }
}

// ---------------------------------------------------------------- input transpose
// x (B, D, T, F) -> X image with tokens ordered (b, f, t)
__global__ __launch_bounds__(256) void transpose_in(const float* __restrict__ x,
                                                    char* __restrict__ Ximg) {
    __shared__ float tile[32][33];
    const int bt = blockIdx.z, b = bt >> 8, t = bt & 255;
    const int d0 = blockIdx.x * 32, f0 = blockIdx.y * 32;
    const int tx = threadIdx.x, ty = threadIdx.y;   // (32, 8)
    const size_t xbase = (size_t)b * D_ * T_ * F_ + (size_t)t * F_;
#pragma unroll
    for (int j = 0; j < 4; ++j) {
        int d = d0 + ty + j * 8;
        tile[ty + j * 8][tx] = x[xbase + (size_t)d * T_ * F_ + f0 + tx];
    }
    __syncthreads();
    const int tok = (b * 64 + f0 + tx) * 256 + t;
    const int rloc = tok & 127;
    const int hl = ty >> 2, seg = ty & 3;
    char* base = Ximg + ((size_t)((tok >> 7) * 4 + (d0 >> 6))) * 32768 + hl * 16384;
    const int off = rloc * 128 + ((((d0 & 32) << 1) + seg * 16) ^ ((rloc & 7) << 4));
    s16x8 v;
#pragma unroll
    for (int e = 0; e < 8; ++e) {
        float xv = tile[seg * 8 + e][tx];
        unsigned short hb = f2bf(xv);
        v[e] = hl ? (short)f2bf(xv - bf2f(hb)) : (short)hb;
    }
    *(s16x8*)(base + off) = v;
}

// y chunk rows ordered (bt_local, f), cols d -> out (B, D, T, F) for bt = bt0+z
__global__ __launch_bounds__(256) void transpose_out(const float* __restrict__ y,
                                                     float* __restrict__ out, int bt0) {
    __shared__ float tile[32][33];
    const int btl = blockIdx.z;
    const int bt = bt0 + btl, b = bt >> 8, t = bt & 255;
    const int d0 = blockIdx.x * 32, f0 = blockIdx.y * 32;
    const int tx = threadIdx.x, ty = threadIdx.y;
    const size_t ybase = (size_t)btl * F_ * D_;
#pragma unroll
    for (int j = 0; j < 4; ++j) {
        int f = f0 + ty + j * 8;
        tile[ty + j * 8][tx] = y[ybase + (size_t)f * D_ + d0 + tx];
    }
    __syncthreads();
    const size_t obase = (size_t)b * D_ * T_ * F_ + (size_t)t * F_;
#pragma unroll
    for (int j = 0; j < 4; ++j) {
        int d = d0 + ty + j * 8;
        out[obase + (size_t)d * T_ * F_ + f0 + tx] = tile[tx][ty + j * 8];
    }
}

// ---------------------------------------------------------------- bf16x3 MFMA GEMM
// BF16OUT: C stored as bf16 row-major (qkv); else fp32 row-major (c_proj).
template <bool BF16OUT>
__global__ __launch_bounds__(256) void gemm_bf16x3(const char* __restrict__ Aimg,
                                                   const char* __restrict__ Bimg,
                                                   void* __restrict__ Cv, int N) {
    __shared__ alignas(16) char lds[65536];   // Ah|Al (32KB) + Bh|Bl (32KB)
    const int tid = threadIdx.x, lane = tid & 63, wave = tid >> 6;
    const int wm = wave >> 1, wn = wave & 1;
    const int rlo = lane & 15, rg = lane >> 4;
    f32x4 acc[4][4] = {};
    for (int ks = 0; ks < 4; ++ks) {
        const char* ga = Aimg + ((size_t)(blockIdx.x * 4 + ks)) * 32768 + wave * 8192 + lane * 16;
        const char* gb = Bimg + ((size_t)(blockIdx.y * 4 + ks)) * 32768 + wave * 8192 + lane * 16;
        char* la = lds + wave * 8192;
        char* lb = lds + 32768 + wave * 8192;
#pragma unroll
        for (int i = 0; i < 8; ++i) {
            __builtin_amdgcn_global_load_lds(
                (const __attribute__((address_space(1))) void*)(ga + i * 1024),
                (__attribute__((address_space(3))) void*)(la + i * 1024), 16, 0, 0);
            __builtin_amdgcn_global_load_lds(
                (const __attribute__((address_space(1))) void*)(gb + i * 1024),
                (__attribute__((address_space(3))) void*)(lb + i * 1024), 16, 0, 0);
        }
        __syncthreads();
#pragma unroll
        for (int kk = 0; kk < 2; ++kk) {
            s16x8 ah[4], al[4], bh[4], bl[4];
#pragma unroll
            for (int i = 0; i < 4; ++i) {
                const int ra = wm * 64 + i * 16 + rlo;
                const int ka = (kk * 64 + rg * 16) ^ ((ra & 7) << 4);
                ah[i] = *(const s16x8*)(lds + ra * 128 + ka);
                al[i] = *(const s16x8*)(lds + 16384 + ra * 128 + ka);
                const int rb = wn * 64 + i * 16 + rlo;
                const int kb = (kk * 64 + rg * 16) ^ ((rb & 7) << 4);
                bh[i] = *(const s16x8*)(lds + 32768 + rb * 128 + kb);
                bl[i] = *(const s16x8*)(lds + 49152 + rb * 128 + kb);
            }
#pragma unroll
            for (int mt = 0; mt < 4; ++mt)
#pragma unroll
                for (int nt = 0; nt < 4; ++nt) {
                    acc[mt][nt] = __builtin_amdgcn_mfma_f32_16x16x32_bf16(ah[mt], bh[nt], acc[mt][nt], 0, 0, 0);
                    acc[mt][nt] = __builtin_amdgcn_mfma_f32_16x16x32_bf16(ah[mt], bl[nt], acc[mt][nt], 0, 0, 0);
                    acc[mt][nt] = __builtin_amdgcn_mfma_f32_16x16x32_bf16(al[mt], bh[nt], acc[mt][nt], 0, 0, 0);
                }
        }
        __syncthreads();
    }
    const int row0 = blockIdx.x * 128 + wm * 64, col0 = blockIdx.y * 128 + wn * 64;
    if constexpr (BF16OUT) {
        unsigned short* C = (unsigned short*)Cv;
#pragma unroll
        for (int mt = 0; mt < 4; ++mt)
#pragma unroll
            for (int nt = 0; nt < 4; ++nt)
#pragma unroll
                for (int r = 0; r < 4; ++r)
                    C[(size_t)(row0 + mt * 16 + rg * 4 + r) * N + col0 + nt * 16 + rlo] =
                        f2bf(acc[mt][nt][r]);
    } else {
        float* C = (float*)Cv;
#pragma unroll
        for (int mt = 0; mt < 4; ++mt)
#pragma unroll
            for (int nt = 0; nt < 4; ++nt)
#pragma unroll
                for (int r = 0; r < 4; ++r)
                    C[(size_t)(row0 + mt * 16 + rg * 4 + r) * N + col0 + nt * 16 + rlo] =
                        acc[mt][nt][r];
    }
}

// ---------------------------------------------------------------- MFMA attention
// qkv is bf16 row-major [tok][768]. STAGE=1: L=256, 1 head/block; 2/3: L=64, 2 heads.
template <int STAGE>
__global__ __launch_bounds__(256) void attn_mfma(const unsigned short* __restrict__ qkv,
                                                 char* __restrict__ Ximg, int s0) {
    constexpr int L   = (STAGE == 1) ? 256 : 64;
    constexpr int HPB = (STAGE == 1) ? 1 : 2;
    constexpr int NCH = L / 32;
    constexpr int KFB = L * 64;            // Kf bytes per head (= Vf bytes)
    __shared__ alignas(16) char kvLds[HPB * 2 * KFB];
    __shared__ alignas(16) float Osc[4][16][36];
    const int tid = threadIdx.x, lane = tid & 63, wave = tid >> 6;
    const int sl = blockIdx.y;

    // ---- stage K (rope'd) and V into fragment-ordered LDS ----
    {
        const int nIter = (STAGE == 1) ? 2 : 1;
#pragma unroll
        for (int it = 0; it < nIter; ++it) {
            int idx, headl;
            if (STAGE == 1) { idx = it * 256 + tid; headl = 0; }
            else            { idx = tid & 127;      headl = tid >> 7; }
            const int k = idx >> 1, dh = idx & 1;
            const int h = blockIdx.x * HPB + headl;
            const size_t grow = ((size_t)(sl * L + k)) * 768 + h * 32 + dh * 16;
            const s16x8 kr0 = *(const s16x8*)&qkv[grow + 256];
            const s16x8 kr1 = *(const s16x8*)&qkv[grow + 264];
            const s16x8 vr0 = *(const s16x8*)&qkv[grow + 512];
            const s16x8 vr1 = *(const s16x8*)&qkv[grow + 520];
            float kvv[16];
#pragma unroll
            for (int e = 0; e < 8; ++e) {
                kvv[e]     = bf2f((unsigned short)kr0[e]);
                kvv[8 + e] = bf2f((unsigned short)kr1[e]);
            }
#pragma unroll
            for (int j = 0; j < 8; ++j) {
                float2 r = rope_pair(kvv[2 * j], kvv[2 * j + 1], dh * 8 + j, (float)k);
                kvv[2 * j] = r.x; kvv[2 * j + 1] = r.y;
            }
            char* kf = kvLds + headl * 2 * KFB;
#pragma unroll
            for (int jg = 0; jg < 2; ++jg) {
                s16x8 w;
#pragma unroll
                for (int e = 0; e < 8; ++e) w[e] = (short)f2bf(kvv[jg * 8 + e]);
                *(s16x8*)(kf + ((k >> 4) * 64 + (k & 15) + 16 * (dh * 2 + jg)) * 16) = w;
            }
            // V fragment: V[k][d] -> subblock (k>>5)*2+dh, lane (d&15)+16*((k>>3)&3), elem k&7
            char* vf = kvLds + headl * 2 * KFB + KFB;
            const int sb = (k >> 5) * 2 + dh;
            const int lgo = 16 * ((k >> 3) & 3);
            const int eo = (k & 7) * 2;
#pragma unroll
            for (int dp = 0; dp < 16; ++dp) {
                const unsigned short vv = (unsigned short)((dp < 8) ? vr0[dp] : vr1[dp - 8]);
                *(unsigned short*)(vf + sb * 1024 + (dp + lgo) * 16 + eo) = vv;
            }
        }
    }
    __syncthreads();

    // ---- compute ----
    const int headl = (STAGE == 1) ? 0 : (wave >> 1);
    const int h = blockIdx.x * HPB + headl;
    const char* Kf = kvLds + headl * 2 * KFB;
    const char* Vf = Kf + KFB;
    const int nPass = (STAGE == 1) ? 4 : 2;
    const int addr_lo = ((lane & 15) + ((lane >> 4) & 1) * 32) * 4;
    const int addr_hi = addr_lo + 64;
    const bool hiSel = lane >= 32;

    for (int pass = 0; pass < nPass; ++pass) {
        const int qbase = (STAGE == 1) ? ((wave & 3) * 16 + pass * 64)
                                       : ((wave & 1) * 16 + pass * 32);
        const int q = qbase + (lane & 15);
        // Q fragment (rope + scale folded)
        s16x8 qf;
        {
            const size_t qrow = ((size_t)(sl * L + q)) * 768 + h * 32 + (lane >> 4) * 8;
            const s16x8 qr = *(const s16x8*)&qkv[qrow];
            float qv[8];
#pragma unroll
            for (int e = 0; e < 8; ++e) qv[e] = bf2f((unsigned short)qr[e]);
#pragma unroll
            for (int j = 0; j < 4; ++j) {
                float2 r = rope_pair(qv[2 * j], qv[2 * j + 1], (lane >> 4) * 4 + j, (float)q);
                qf[2 * j]     = (short)f2bf(r.x * SM_SCALE);
                qf[2 * j + 1] = (short)f2bf(r.y * SM_SCALE);
            }
        }
        f32x4 olo = {0.f, 0.f, 0.f, 0.f}, ohi = {0.f, 0.f, 0.f, 0.f};
        const f32x4 zero = {0.f, 0.f, 0.f, 0.f};
        float m = -INFINITY, lsum = 0.f;
#pragma unroll
        for (int c = 0; c < NCH; ++c) {
            const s16x8 ka = *(const s16x8*)(Kf + (c * 2) * 1024 + lane * 16);
            const s16x8 kb = *(const s16x8*)(Kf + (c * 2 + 1) * 1024 + lane * 16);
            f32x4 sA = __builtin_amdgcn_mfma_f32_16x16x32_bf16(ka, qf, zero, 0, 0, 0);
            f32x4 sB = __builtin_amdgcn_mfma_f32_16x16x32_bf16(kb, qf, zero, 0, 0, 0);
            float cmax = fmaxf(fmaxf(fmaxf(sA[0], sA[1]), fmaxf(sA[2], sA[3])),
                               fmaxf(fmaxf(sB[0], sB[1]), fmaxf(sB[2], sB[3])));
            cmax = fmaxf(cmax, __shfl_xor(cmax, 16, 64));
            cmax = fmaxf(cmax, __shfl_xor(cmax, 32, 64));
            const float mnew = fmaxf(m, cmax);
            const float corr = __expf(m - mnew);
            m = mnew;
            float p[8];
#pragma unroll
            for (int e = 0; e < 4; ++e) p[e] = __expf(sA[e] - mnew);
#pragma unroll
            for (int e = 0; e < 4; ++e) p[4 + e] = __expf(sB[e] - mnew);
            float ps = ((p[0] + p[1]) + (p[2] + p[3])) + ((p[4] + p[5]) + (p[6] + p[7]));
            lsum = lsum * corr + ps;
            const int t0w0 = (int)cvt_pk_bf16(p[0], p[1]);
            const int t0w1 = (int)cvt_pk_bf16(p[2], p[3]);
            const int t1w0 = (int)cvt_pk_bf16(p[4], p[5]);
            const int t1w1 = (int)cvt_pk_bf16(p[6], p[7]);
            union { int u[4]; s16x8 v; } Af;
            const int a0 = __builtin_amdgcn_ds_bpermute(addr_lo, t0w0);
            const int a1 = __builtin_amdgcn_ds_bpermute(addr_lo, t0w1);
            const int a2 = __builtin_amdgcn_ds_bpermute(addr_hi, t0w0);
            const int a3 = __builtin_amdgcn_ds_bpermute(addr_hi, t0w1);
            const int b0 = __builtin_amdgcn_ds_bpermute(addr_lo, t1w0);
            const int b1 = __builtin_amdgcn_ds_bpermute(addr_lo, t1w1);
            const int b2 = __builtin_amdgcn_ds_bpermute(addr_hi, t1w0);
            const int b3 = __builtin_amdgcn_ds_bpermute(addr_hi, t1w1);
            Af.u[0] = hiSel ? b0 : a0;
            Af.u[1] = hiSel ? b1 : a1;
            Af.u[2] = hiSel ? b2 : a2;
            Af.u[3] = hiSel ? b3 : a3;
#pragma unroll
            for (int r = 0; r < 4; ++r) {
                const float fr = __shfl(corr, (lane >> 4) * 4 + r, 64);
                olo[r] *= fr; ohi[r] *= fr;
            }
            const s16x8 va = *(const s16x8*)(Vf + (c * 2) * 1024 + lane * 16);
            const s16x8 vb = *(const s16x8*)(Vf + (c * 2 + 1) * 1024 + lane * 16);
            olo = __builtin_amdgcn_mfma_f32_16x16x32_bf16(Af.v, va, olo, 0, 0, 0);
            ohi = __builtin_amdgcn_mfma_f32_16x16x32_bf16(Af.v, vb, ohi, 0, 0, 0);
        }
        // ---- normalize + transpose via wave-private LDS ----
        lsum += __shfl_xor(lsum, 16, 64);
        lsum += __shfl_xor(lsum, 32, 64);
        const float inv = 1.0f / lsum;
#pragma unroll
        for (int r = 0; r < 4; ++r) {
            const float ir = __shfl(inv, (lane >> 4) * 4 + r, 64);
            Osc[wave][(lane >> 4) * 4 + r][lane & 15]        = olo[r] * ir;
            Osc[wave][(lane >> 4) * 4 + r][16 + (lane & 15)] = ohi[r] * ir;
        }
        const int seg = lane >> 4;
        float v8[8];
        *(float4*)&v8[0] = *(const float4*)&Osc[wave][lane & 15][seg * 8];
        *(float4*)&v8[4] = *(const float4*)&Osc[wave][lane & 15][seg * 8 + 4];
        // token mapping
        int tok;
        if constexpr (STAGE == 1) {
            const int s = s0 + sl, b = s >> 6, f = s & 63;
            tok = (b * 256 + q) * 64 + f;
        } else if constexpr (STAGE == 2) {
            const int s2 = s0 + sl, b = s2 >> 8, t = s2 & 255;
            tok = ((b * 32 + (t >> 3)) * 8 + (q >> 3)) * 64 + (t & 7) * 8 + (q & 7);
        } else {
            const int w = s0 + sl, b = w >> 8, tb = (w >> 3) & 31, fb = w & 7;
            tok = (b * 256 + tb * 8 + (q >> 3)) * 64 + fb * 8 + (q & 7);
        }
        const int rloc = tok & 127;
        char* base = Ximg + ((size_t)((tok >> 7) * 4 + (h >> 1))) * 32768;
        const int off = rloc * 128 + ((((h & 1) * 64) + seg * 16) ^ ((rloc & 7) << 4));
        s16x8 hi, lo;
#pragma unroll
        for (int e = 0; e < 8; ++e) {
            unsigned short hb = f2bf(v8[e]);
            hi[e] = (short)hb;
            lo[e] = (short)f2bf(v8[e] - bf2f(hb));
        }
        *(s16x8*)(base + off) = hi;
        *(s16x8*)(base + 16384 + off) = lo;
    }
}

// ---------------------------------------------------------------- launch
extern "C" void kernel_launch(void* const* d_in, const int* in_sizes, int n_in,
                              void* d_out, int out_size, void* d_ws, size_t ws_size,
                              hipStream_t stream) {
    const float* x  = (const float*)d_in[0];
    const float* W1 = (const float*)d_in[1];
    const float* W2 = (const float*)d_in[2];
    const float* W3 = (const float*)d_in[3];
    const float* Wp = (const float*)d_in[4];
    float* out = (float*)d_out;

    const size_t M = (size_t)B_ * T_ * F_;        // 65536 tokens
    char* Xa = (char*)d_out;                      // image buffer A (X1, X3)
    char* Xb = (char*)d_ws;                       // image buffer B (X2, X4)
    char* W1i = (char*)d_ws + M * 1024;           // weight images
    char* W2i = W1i + 786432;
    char* W3i = W2i + 786432;
    char* Wpi = W3i + 786432;
    unsigned short* qkvB = (unsigned short*)(Wpi + 262144);  // bf16 qkv
    float* qkvF = (float*)(Wpi + 262144);                    // fp32 alias (c_proj out)

    // adaptive chunk (tokens): qkv chunk is CH*768 bf16 = CH*1536 bytes
    const size_t fixedBytes = M * 1024 + 3 * 786432 + 262144;
    int CH = 2048;
    const int cands[5] = {65536, 32768, 16384, 8192, 4096};
    for (int i = 0; i < 5; ++i) {
        if (fixedBytes + (size_t)cands[i] * 1536 <= ws_size) { CH = cands[i]; break; }
    }
    const int NC = (int)(M / CH);

    split_w<<<dim3(6, 4), 256, 0, stream>>>(W1, W1i, 768);
    split_w<<<dim3(6, 4), 256, 0, stream>>>(W2, W2i, 768);
    split_w<<<dim3(6, 4), 256, 0, stream>>>(W3, W3i, 768);
    split_w<<<dim3(2, 4), 256, 0, stream>>>(Wp, Wpi, 256);

    transpose_in<<<dim3(8, 2, 1024), dim3(32, 8), 0, stream>>>(x, Xa);

    // stage 1: time attention (L=256)
    for (int c = 0; c < NC; ++c) {
        gemm_bf16x3<true><<<dim3(CH / 128, 6), 256, 0, stream>>>(
            Xa + (size_t)c * CH * 1024, W1i, qkvB, 768);
        attn_mfma<1><<<dim3(H_, CH / 256), 256, 0, stream>>>(qkvB, Xb, c * (CH / 256));
    }
    // stage 2: freq attention (L=64)
    for (int c = 0; c < NC; ++c) {
        gemm_bf16x3<true><<<dim3(CH / 128, 6), 256, 0, stream>>>(
            Xb + (size_t)c * CH * 1024, W2i, qkvB, 768);
        attn_mfma<2><<<dim3(H_ / 2, CH / 64), 256, 0, stream>>>(qkvB, Xa, c * (CH / 64));
    }
    // stage 3: windowed attention (L=64)
    for (int c = 0; c < NC; ++c) {
        gemm_bf16x3<true><<<dim3(CH / 128, 6), 256, 0, stream>>>(
            Xa + (size_t)c * CH * 1024, W3i, qkvB, 768);
        attn_mfma<3><<<dim3(H_ / 2, CH / 64), 256, 0, stream>>>(qkvB, Xb, c * (CH / 64));
    }
    // c_proj (fp32 out, aliases dead qkv region) + output transpose
    for (int c = 0; c < NC; ++c) {
        gemm_bf16x3<false><<<dim3(CH / 128, 2), 256, 0, stream>>>(
            Xb + (size_t)c * CH * 1024, Wpi, qkvF, 256);
        transpose_out<<<dim3(8, 2, CH / 64), dim3(32, 8), 0, stream>>>(
            qkvF, out, c * (CH / 64));
    }
}

// Round 6
// 525.402 us; speedup vs baseline: 4.3217x; 1.0435x over previous
//
#include <hip/hip_runtime.h>
#include <math.h>

#define B_  4
#define D_  256
#define T_  256
#define F_  64
#define H_  8

#define LN10000 9.210340371976184f
#define SM_SCALE 0.17677669529663687f   // 1/sqrt(32)

typedef float f32x4 __attribute__((ext_vector_type(4)));
typedef short s16x8 __attribute__((ext_vector_type(8)));

// ---------------------------------------------------------------- bf16 helpers
__device__ __forceinline__ unsigned short f2bf(float x) {
    unsigned u = __float_as_uint(x);
    return (unsigned short)((u + 0x7fffu + ((u >> 16) & 1u)) >> 16);
}
__device__ __forceinline__ float bf2f(unsigned short h) {
    return __uint_as_float(((unsigned)h) << 16);
}
__device__ __forceinline__ unsigned cvt_pk_bf16(float a, float b) {
    unsigned r;
    asm("v_cvt_pk_bf16_f32 %0, %1, %2" : "=v"(r) : "v"(a), "v"(b));
    return r;   // lo16 = bf16(a), hi16 = bf16(b)
}

// ---------------------------------------------------------------- RoPE helper
__device__ __forceinline__ float2 rope_pair(float x0, float x1, int pairIdx, float pos) {
    float freq = __expf(-(float)(2 * pairIdx) * (LN10000 / 32.0f));
    float ang = pos * freq;
    float s, c;
    __sincosf(ang, &s, &c);
    return make_float2(x0 * c - x1 * s, x1 * c + x0 * s);
}

// ---------------------------------------------------------------- weight split
// W (64k x 128n fp32 tile) -> image block (nb*4+ks)*32KB, [n][k] bf16 hi/lo, swizzled
__global__ __launch_bounds__(256) void split_w(const float* __restrict__ W,
                                               char* __restrict__ img, int N) {
    __shared__ float Wt[64][132];
    const int nb = blockIdx.x, ks = blockIdx.y;
    const int tid = threadIdx.x;
#pragma unroll
    for (int j = 0; j < 8; ++j) {
        int idx = j * 1024 + tid * 4;
        int r = idx >> 7, cidx = idx & 127;
        const float4 v = *reinterpret_cast<const float4*>(
            &W[(size_t)(ks * 64 + r) * N + nb * 128 + cidx]);
        Wt[r][cidx] = v.x; Wt[r][cidx + 1] = v.y;
        Wt[r][cidx + 2] = v.z; Wt[r][cidx + 3] = v.w;
    }
    __syncthreads();
    char* base = img + ((size_t)(nb * 4 + ks)) * 32768;
#pragma unroll
    for (int i = 0; i < 4; ++i) {
        int p = i * 256 + tid;
        int n = p >> 3, seg = p & 7;
        s16x8 hi, lo;
#pragma unroll
        for (int e = 0; e < 8; ++e) {
            float v = Wt[seg * 8 + e][n];
            unsigned short hb = f2bf(v);
            hi[e] = (short)hb;
            lo[e] = (short)f2bf(v - bf2f(hb));
        }
        int off = n * 128 + ((seg * 16) ^ ((n & 7) << 4));
        *(s16x8*)(base + off) = hi;
        *(s16x8*)(base + 16384 + off) = lo;
    }
}

// ---------------------------------------------------------------- input transpose
// x (B, D, T, F) -> X image with tokens ordered (b, f, t)
__global__ __launch_bounds__(256) void transpose_in(const float* __restrict__ x,
                                                    char* __restrict__ Ximg) {
    __shared__ float tile[32][33];
    const int bt = blockIdx.z, b = bt >> 8, t = bt & 255;
    const int d0 = blockIdx.x * 32, f0 = blockIdx.y * 32;
    const int tx = threadIdx.x, ty = threadIdx.y;   // (32, 8)
    const size_t xbase = (size_t)b * D_ * T_ * F_ + (size_t)t * F_;
#pragma unroll
    for (int j = 0; j < 4; ++j) {
        int d = d0 + ty + j * 8;
        tile[ty + j * 8][tx] = x[xbase + (size_t)d * T_ * F_ + f0 + tx];
    }
    __syncthreads();
    const int tok = (b * 64 + f0 + tx) * 256 + t;
    const int rloc = tok & 127;
    const int hl = ty >> 2, seg = ty & 3;
    char* base = Ximg + ((size_t)((tok >> 7) * 4 + (d0 >> 6))) * 32768 + hl * 16384;
    const int off = rloc * 128 + ((((d0 & 32) << 1) + seg * 16) ^ ((rloc & 7) << 4));
    s16x8 v;
#pragma unroll
    for (int e = 0; e < 8; ++e) {
        float xv = tile[seg * 8 + e][tx];
        unsigned short hb = f2bf(xv);
        v[e] = hl ? (short)f2bf(xv - bf2f(hb)) : (short)hb;
    }
    *(s16x8*)(base + off) = v;
}

// y chunk rows ordered (bt_local, f), cols d -> out (B, D, T, F) for bt = bt0+z
__global__ __launch_bounds__(256) void transpose_out(const float* __restrict__ y,
                                                     float* __restrict__ out, int bt0) {
    __shared__ float tile[32][33];
    const int btl = blockIdx.z;
    const int bt = bt0 + btl, b = bt >> 8, t = bt & 255;
    const int d0 = blockIdx.x * 32, f0 = blockIdx.y * 32;
    const int tx = threadIdx.x, ty = threadIdx.y;
    const size_t ybase = (size_t)btl * F_ * D_;
#pragma unroll
    for (int j = 0; j < 4; ++j) {
        int f = f0 + ty + j * 8;
        tile[ty + j * 8][tx] = y[ybase + (size_t)f * D_ + d0 + tx];
    }
    __syncthreads();
    const size_t obase = (size_t)b * D_ * T_ * F_ + (size_t)t * F_;
#pragma unroll
    for (int j = 0; j < 4; ++j) {
        int d = d0 + ty + j * 8;
        out[obase + (size_t)d * T_ * F_ + f0 + tx] = tile[tx][ty + j * 8];
    }
}

// ---------------------------------------------------------------- bf16x3 GEMM (A: 2-block/CU, col-fast grid)
// grid = (N/128, M/128): blockIdx.x = column tile (fast), blockIdx.y = row tile.
template <bool BF16OUT>
__global__ __launch_bounds__(256) void gemm_bf16x3(const char* __restrict__ Aimg,
                                                   const char* __restrict__ Bimg,
                                                   void* __restrict__ Cv, int N) {
    __shared__ alignas(16) char lds[65536];   // Ah|Al (32KB) + Bh|Bl (32KB)
    const int tid = threadIdx.x, lane = tid & 63, wave = tid >> 6;
    const int wm = wave >> 1, wn = wave & 1;
    const int rlo = lane & 15, rg = lane >> 4;
    f32x4 acc[4][4] = {};
    for (int ks = 0; ks < 4; ++ks) {
        const char* ga = Aimg + ((size_t)(blockIdx.y * 4 + ks)) * 32768 + wave * 8192 + lane * 16;
        const char* gb = Bimg + ((size_t)(blockIdx.x * 4 + ks)) * 32768 + wave * 8192 + lane * 16;
        char* la = lds + wave * 8192;
        char* lb = lds + 32768 + wave * 8192;
#pragma unroll
        for (int i = 0; i < 8; ++i) {
            __builtin_amdgcn_global_load_lds(
                (const __attribute__((address_space(1))) void*)(ga + i * 1024),
                (__attribute__((address_space(3))) void*)(la + i * 1024), 16, 0, 0);
            __builtin_amdgcn_global_load_lds(
                (const __attribute__((address_space(1))) void*)(gb + i * 1024),
                (__attribute__((address_space(3))) void*)(lb + i * 1024), 16, 0, 0);
        }
        __syncthreads();
#pragma unroll
        for (int kk = 0; kk < 2; ++kk) {
            s16x8 ah[4], al[4], bh[4], bl[4];
#pragma unroll
            for (int i = 0; i < 4; ++i) {
                const int ra = wm * 64 + i * 16 + rlo;
                const int ka = (kk * 64 + rg * 16) ^ ((ra & 7) << 4);
                ah[i] = *(const s16x8*)(lds + ra * 128 + ka);
                al[i] = *(const s16x8*)(lds + 16384 + ra * 128 + ka);
                const int rb = wn * 64 + i * 16 + rlo;
                const int kb = (kk * 64 + rg * 16) ^ ((rb & 7) << 4);
                bh[i] = *(const s16x8*)(lds + 32768 + rb * 128 + kb);
                bl[i] = *(const s16x8*)(lds + 49152 + rb * 128 + kb);
            }
#pragma unroll
            for (int mt = 0; mt < 4; ++mt)
#pragma unroll
                for (int nt = 0; nt < 4; ++nt) {
                    acc[mt][nt] = __builtin_amdgcn_mfma_f32_16x16x32_bf16(ah[mt], bh[nt], acc[mt][nt], 0, 0, 0);
                    acc[mt][nt] = __builtin_amdgcn_mfma_f32_16x16x32_bf16(ah[mt], bl[nt], acc[mt][nt], 0, 0, 0);
                    acc[mt][nt] = __builtin_amdgcn_mfma_f32_16x16x32_bf16(al[mt], bh[nt], acc[mt][nt], 0, 0, 0);
                }
        }
        __syncthreads();
    }
    const int row0 = blockIdx.y * 128 + wm * 64, col0 = blockIdx.x * 128 + wn * 64;
    if constexpr (BF16OUT) {
        unsigned short* C = (unsigned short*)Cv;
#pragma unroll
        for (int mt = 0; mt < 4; ++mt)
#pragma unroll
            for (int nt = 0; nt < 4; ++nt)
#pragma unroll
                for (int r = 0; r < 4; ++r)
                    C[(size_t)(row0 + mt * 16 + rg * 4 + r) * N + col0 + nt * 16 + rlo] =
                        f2bf(acc[mt][nt][r]);
    } else {
        float* C = (float*)Cv;
#pragma unroll
        for (int mt = 0; mt < 4; ++mt)
#pragma unroll
            for (int nt = 0; nt < 4; ++nt)
#pragma unroll
                for (int r = 0; r < 4; ++r)
                    C[(size_t)(row0 + mt * 16 + rg * 4 + r) * N + col0 + nt * 16 + rlo] =
                        acc[mt][nt][r];
    }
}

// ---------------------------------------------------------------- bf16x3 GEMM (B: double-buffered, 512 thr)
// grid = (N/128, M/128). LDS 128KB (2 phases x (A 32KB + B 32KB)), 8 waves (2m x 4n),
// wave tile 64x32. T3 minimum 2-phase: STAGE(next) -> compute(cur) -> syncthreads.
__global__ __launch_bounds__(512) void gemm_dbuf(const char* __restrict__ Aimg,
                                                 const char* __restrict__ Bimg,
                                                 unsigned short* __restrict__ C, int N) {
    __shared__ alignas(16) char lds[131072];
    const int tid = threadIdx.x, lane = tid & 63, wave = tid >> 6;
    const int wm = wave >> 2, wn = wave & 3;       // 2 x 4
    const int rlo = lane & 15, rg = lane >> 4;
    f32x4 acc[4][2] = {};
    const char* gA = Aimg + (size_t)blockIdx.y * 131072;
    const char* gB = Bimg + (size_t)blockIdx.x * 131072;

#define STAGE_KS(p, ks)                                                                     \
    {                                                                                       \
        char* la_ = lds + (p) * 65536;                                                      \
        const char* a_ = gA + (ks) * 32768 + tid * 16;                                      \
        const char* b_ = gB + (ks) * 32768 + tid * 16;                                      \
        _Pragma("unroll")                                                                   \
        for (int i_ = 0; i_ < 4; ++i_) {                                                    \
            __builtin_amdgcn_global_load_lds(                                               \
                (const __attribute__((address_space(1))) void*)(a_ + i_ * 8192),            \
                (__attribute__((address_space(3))) void*)(la_ + tid * 16 + i_ * 8192), 16, 0, 0); \
            __builtin_amdgcn_global_load_lds(                                               \
                (const __attribute__((address_space(1))) void*)(b_ + i_ * 8192),            \
                (__attribute__((address_space(3))) void*)(la_ + 32768 + tid * 16 + i_ * 8192), 16, 0, 0); \
        }                                                                                   \
    }

    STAGE_KS(0, 0);
    __syncthreads();
#pragma unroll
    for (int ks = 0; ks < 4; ++ks) {
        if (ks + 1 < 4) STAGE_KS((ks + 1) & 1, ks + 1);
        const char* la = lds + (ks & 1) * 65536;
        const char* lb = la + 32768;
#pragma unroll
        for (int kk = 0; kk < 2; ++kk) {
            s16x8 ah[4], al[4], bh[2], bl[2];
#pragma unroll
            for (int i = 0; i < 4; ++i) {
                const int ra = wm * 64 + i * 16 + rlo;
                const int ka = (kk * 64 + rg * 16) ^ ((ra & 7) << 4);
                ah[i] = *(const s16x8*)(la + ra * 128 + ka);
                al[i] = *(const s16x8*)(la + 16384 + ra * 128 + ka);
            }
#pragma unroll
            for (int j = 0; j < 2; ++j) {
                const int rb = wn * 32 + j * 16 + rlo;
                const int kb = (kk * 64 + rg * 16) ^ ((rb & 7) << 4);
                bh[j] = *(const s16x8*)(lb + rb * 128 + kb);
                bl[j] = *(const s16x8*)(lb + 16384 + rb * 128 + kb);
            }
#pragma unroll
            for (int mt = 0; mt < 4; ++mt)
#pragma unroll
                for (int j = 0; j < 2; ++j) {
                    acc[mt][j] = __builtin_amdgcn_mfma_f32_16x16x32_bf16(ah[mt], bh[j], acc[mt][j], 0, 0, 0);
                    acc[mt][j] = __builtin_amdgcn_mfma_f32_16x16x32_bf16(ah[mt], bl[j], acc[mt][j], 0, 0, 0);
                    acc[mt][j] = __builtin_amdgcn_mfma_f32_16x16x32_bf16(al[mt], bh[j], acc[mt][j], 0, 0, 0);
                }
        }
        __syncthreads();
    }
#undef STAGE_KS
    const int row0 = blockIdx.y * 128 + wm * 64, col0 = blockIdx.x * 128 + wn * 32;
#pragma unroll
    for (int mt = 0; mt < 4; ++mt)
#pragma unroll
        for (int j = 0; j < 2; ++j)
#pragma unroll
            for (int r = 0; r < 4; ++r)
                C[(size_t)(row0 + mt * 16 + rg * 4 + r) * N + col0 + j * 16 + rlo] =
                    f2bf(acc[mt][j][r]);
}

// ---------------------------------------------------------------- MFMA attention
// qkv is bf16 row-major [tok][768]. STAGE=1: L=256, 1 head/block; 2/3: L=64, 2 heads.
template <int STAGE>
__global__ __launch_bounds__(256) void attn_mfma(const unsigned short* __restrict__ qkv,
                                                 char* __restrict__ Ximg, int s0) {
    constexpr int L   = (STAGE == 1) ? 256 : 64;
    constexpr int HPB = (STAGE == 1) ? 1 : 2;
    constexpr int NCH = L / 32;
    constexpr int KFB = L * 64;            // Kf bytes per head (= Vf bytes)
    __shared__ alignas(16) char kvLds[HPB * 2 * KFB];
    __shared__ alignas(16) float Osc[4][16][36];
    const int tid = threadIdx.x, lane = tid & 63, wave = tid >> 6;
    const int sl = blockIdx.y;

    // ---- stage K (rope'd) and V into fragment-ordered LDS ----
    {
        const int nIter = (STAGE == 1) ? 2 : 1;
#pragma unroll
        for (int it = 0; it < nIter; ++it) {
            int idx, headl;
            if (STAGE == 1) { idx = it * 256 + tid; headl = 0; }
            else            { idx = tid & 127;      headl = tid >> 7; }
            const int k = idx >> 1, dh = idx & 1;
            const int h = blockIdx.x * HPB + headl;
            const size_t grow = ((size_t)(sl * L + k)) * 768 + h * 32 + dh * 16;
            const s16x8 kr0 = *(const s16x8*)&qkv[grow + 256];
            const s16x8 kr1 = *(const s16x8*)&qkv[grow + 264];
            const s16x8 vr0 = *(const s16x8*)&qkv[grow + 512];
            const s16x8 vr1 = *(const s16x8*)&qkv[grow + 520];
            float kvv[16];
#pragma unroll
            for (int e = 0; e < 8; ++e) {
                kvv[e]     = bf2f((unsigned short)kr0[e]);
                kvv[8 + e] = bf2f((unsigned short)kr1[e]);
            }
#pragma unroll
            for (int j = 0; j < 8; ++j) {
                float2 r = rope_pair(kvv[2 * j], kvv[2 * j + 1], dh * 8 + j, (float)k);
                kvv[2 * j] = r.x; kvv[2 * j + 1] = r.y;
            }
            char* kf = kvLds + headl * 2 * KFB;
#pragma unroll
            for (int jg = 0; jg < 2; ++jg) {
                s16x8 w;
#pragma unroll
                for (int e = 0; e < 8; ++e) w[e] = (short)f2bf(kvv[jg * 8 + e]);
                *(s16x8*)(kf + ((k >> 4) * 64 + (k & 15) + 16 * (dh * 2 + jg)) * 16) = w;
            }
            // V fragment: V[k][d] -> subblock (k>>5)*2+dh, lane (d&15)+16*((k>>3)&3), elem k&7
            char* vf = kvLds + headl * 2 * KFB + KFB;
            const int sb = (k >> 5) * 2 + dh;
            const int lgo = 16 * ((k >> 3) & 3);
            const int eo = (k & 7) * 2;
#pragma unroll
            for (int dp = 0; dp < 16; ++dp) {
                const unsigned short vv = (unsigned short)((dp < 8) ? vr0[dp] : vr1[dp - 8]);
                *(unsigned short*)(vf + sb * 1024 + (dp + lgo) * 16 + eo) = vv;
            }
        }
    }
    __syncthreads();

    // ---- compute ----
    const int headl = (STAGE == 1) ? 0 : (wave >> 1);
    const int h = blockIdx.x * HPB + headl;
    const char* Kf = kvLds + headl * 2 * KFB;
    const char* Vf = Kf + KFB;
    const int nPass = (STAGE == 1) ? 4 : 2;
    const int addr_lo = ((lane & 15) + ((lane >> 4) & 1) * 32) * 4;
    const int addr_hi = addr_lo + 64;
    const bool hiSel = lane >= 32;

    for (int pass = 0; pass < nPass; ++pass) {
        const int qbase = (STAGE == 1) ? ((wave & 3) * 16 + pass * 64)
                                       : ((wave & 1) * 16 + pass * 32);
        const int q = qbase + (lane & 15);
        // Q fragment (rope + scale folded)
        s16x8 qf;
        {
            const size_t qrow = ((size_t)(sl * L + q)) * 768 + h * 32 + (lane >> 4) * 8;
            const s16x8 qr = *(const s16x8*)&qkv[qrow];
            float qv[8];
#pragma unroll
            for (int e = 0; e < 8; ++e) qv[e] = bf2f((unsigned short)qr[e]);
#pragma unroll
            for (int j = 0; j < 4; ++j) {
                float2 r = rope_pair(qv[2 * j], qv[2 * j + 1], (lane >> 4) * 4 + j, (float)q);
                qf[2 * j]     = (short)f2bf(r.x * SM_SCALE);
                qf[2 * j + 1] = (short)f2bf(r.y * SM_SCALE);
            }
        }
        f32x4 olo = {0.f, 0.f, 0.f, 0.f}, ohi = {0.f, 0.f, 0.f, 0.f};
        const f32x4 zero = {0.f, 0.f, 0.f, 0.f};
        float m = -INFINITY, lsum = 0.f;
#pragma unroll
        for (int c = 0; c < NCH; ++c) {
            const s16x8 ka = *(const s16x8*)(Kf + (c * 2) * 1024 + lane * 16);
            const s16x8 kb = *(const s16x8*)(Kf + (c * 2 + 1) * 1024 + lane * 16);
            f32x4 sA = __builtin_amdgcn_mfma_f32_16x16x32_bf16(ka, qf, zero, 0, 0, 0);
            f32x4 sB = __builtin_amdgcn_mfma_f32_16x16x32_bf16(kb, qf, zero, 0, 0, 0);
            float cmax = fmaxf(fmaxf(fmaxf(sA[0], sA[1]), fmaxf(sA[2], sA[3])),
                               fmaxf(fmaxf(sB[0], sB[1]), fmaxf(sB[2], sB[3])));
            cmax = fmaxf(cmax, __shfl_xor(cmax, 16, 64));
            cmax = fmaxf(cmax, __shfl_xor(cmax, 32, 64));
            const float mnew = fmaxf(m, cmax);
            const float corr = __expf(m - mnew);
            m = mnew;
            float p[8];
#pragma unroll
            for (int e = 0; e < 4; ++e) p[e] = __expf(sA[e] - mnew);
#pragma unroll
            for (int e = 0; e < 4; ++e) p[4 + e] = __expf(sB[e] - mnew);
            float ps = ((p[0] + p[1]) + (p[2] + p[3])) + ((p[4] + p[5]) + (p[6] + p[7]));
            lsum = lsum * corr + ps;
            const int t0w0 = (int)cvt_pk_bf16(p[0], p[1]);
            const int t0w1 = (int)cvt_pk_bf16(p[2], p[3]);
            const int t1w0 = (int)cvt_pk_bf16(p[4], p[5]);
            const int t1w1 = (int)cvt_pk_bf16(p[6], p[7]);
            union { int u[4]; s16x8 v; } Af;
            const int a0 = __builtin_amdgcn_ds_bpermute(addr_lo, t0w0);
            const int a1 = __builtin_amdgcn_ds_bpermute(addr_lo, t0w1);
            const int a2 = __builtin_amdgcn_ds_bpermute(addr_hi, t0w0);
            const int a3 = __builtin_amdgcn_ds_bpermute(addr_hi, t0w1);
            const int b0 = __builtin_amdgcn_ds_bpermute(addr_lo, t1w0);
            const int b1 = __builtin_amdgcn_ds_bpermute(addr_lo, t1w1);
            const int b2 = __builtin_amdgcn_ds_bpermute(addr_hi, t1w0);
            const int b3 = __builtin_amdgcn_ds_bpermute(addr_hi, t1w1);
            Af.u[0] = hiSel ? b0 : a0;
            Af.u[1] = hiSel ? b1 : a1;
            Af.u[2] = hiSel ? b2 : a2;
            Af.u[3] = hiSel ? b3 : a3;
#pragma unroll
            for (int r = 0; r < 4; ++r) {
                const float fr = __shfl(corr, (lane >> 4) * 4 + r, 64);
                olo[r] *= fr; ohi[r] *= fr;
            }
            const s16x8 va = *(const s16x8*)(Vf + (c * 2) * 1024 + lane * 16);
            const s16x8 vb = *(const s16x8*)(Vf + (c * 2 + 1) * 1024 + lane * 16);
            olo = __builtin_amdgcn_mfma_f32_16x16x32_bf16(Af.v, va, olo, 0, 0, 0);
            ohi = __builtin_amdgcn_mfma_f32_16x16x32_bf16(Af.v, vb, ohi, 0, 0, 0);
        }
        // ---- normalize + transpose via wave-private LDS ----
        lsum += __shfl_xor(lsum, 16, 64);
        lsum += __shfl_xor(lsum, 32, 64);
        const float inv = 1.0f / lsum;
#pragma unroll
        for (int r = 0; r < 4; ++r) {
            const float ir = __shfl(inv, (lane >> 4) * 4 + r, 64);
            Osc[wave][(lane >> 4) * 4 + r][lane & 15]        = olo[r] * ir;
            Osc[wave][(lane >> 4) * 4 + r][16 + (lane & 15)] = ohi[r] * ir;
        }
        const int seg = lane >> 4;
        float v8[8];
        *(float4*)&v8[0] = *(const float4*)&Osc[wave][lane & 15][seg * 8];
        *(float4*)&v8[4] = *(const float4*)&Osc[wave][lane & 15][seg * 8 + 4];
        // token mapping
        int tok;
        if constexpr (STAGE == 1) {
            const int s = s0 + sl, b = s >> 6, f = s & 63;
            tok = (b * 256 + q) * 64 + f;
        } else if constexpr (STAGE == 2) {
            const int s2 = s0 + sl, b = s2 >> 8, t = s2 & 255;
            tok = ((b * 32 + (t >> 3)) * 8 + (q >> 3)) * 64 + (t & 7) * 8 + (q & 7);
        } else {
            const int w = s0 + sl, b = w >> 8, tb = (w >> 3) & 31, fb = w & 7;
            tok = (b * 256 + tb * 8 + (q >> 3)) * 64 + fb * 8 + (q & 7);
        }
        const int rloc = tok & 127;
        char* base = Ximg + ((size_t)((tok >> 7) * 4 + (h >> 1))) * 32768;
        const int off = rloc * 128 + ((((h & 1) * 64) + seg * 16) ^ ((rloc & 7) << 4));
        s16x8 hi, lo;
#pragma unroll
        for (int e = 0; e < 8; ++e) {
            unsigned short hb = f2bf(v8[e]);
            hi[e] = (short)hb;
            lo[e] = (short)f2bf(v8[e] - bf2f(hb));
        }
        *(s16x8*)(base + off) = hi;
        *(s16x8*)(base + 16384 + off) = lo;
    }
}

// ---------------------------------------------------------------- launch
extern "C" void kernel_launch(void* const* d_in, const int* in_sizes, int n_in,
                              void* d_out, int out_size, void* d_ws, size_t ws_size,
                              hipStream_t stream) {
    const float* x  = (const float*)d_in[0];
    const float* W1 = (const float*)d_in[1];
    const float* W2 = (const float*)d_in[2];
    const float* W3 = (const float*)d_in[3];
    const float* Wp = (const float*)d_in[4];
    float* out = (float*)d_out;

    const size_t M = (size_t)B_ * T_ * F_;        // 65536 tokens
    char* Xa = (char*)d_out;                      // image buffer A (X1, X3)
    char* Xb = (char*)d_ws;                       // image buffer B (X2, X4)
    char* W1i = (char*)d_ws + M * 1024;           // weight images
    char* W2i = W1i + 786432;
    char* W3i = W2i + 786432;
    char* Wpi = W3i + 786432;
    unsigned short* qkvB = (unsigned short*)(Wpi + 262144);  // bf16 qkv
    float* qkvF = (float*)(Wpi + 262144);                    // fp32 alias (c_proj out)

    // adaptive chunk (tokens): qkv chunk is CH*768 bf16 = CH*1536 bytes
    const size_t fixedBytes = M * 1024 + 3 * 786432 + 262144;
    int CH = 2048;
    const int cands[5] = {65536, 32768, 16384, 8192, 4096};
    for (int i = 0; i < 5; ++i) {
        if (fixedBytes + (size_t)cands[i] * 1536 <= ws_size) { CH = cands[i]; break; }
    }
    const int NC = (int)(M / CH);

    split_w<<<dim3(6, 4), 256, 0, stream>>>(W1, W1i, 768);
    split_w<<<dim3(6, 4), 256, 0, stream>>>(W2, W2i, 768);
    split_w<<<dim3(6, 4), 256, 0, stream>>>(W3, W3i, 768);
    split_w<<<dim3(2, 4), 256, 0, stream>>>(Wp, Wpi, 256);

    transpose_in<<<dim3(8, 2, 1024), dim3(32, 8), 0, stream>>>(x, Xa);

    // stage 1: time attention (L=256) — GEMM variant B (dbuf, 512 thr)
    for (int c = 0; c < NC; ++c) {
        gemm_dbuf<<<dim3(6, CH / 128), 512, 0, stream>>>(
            Xa + (size_t)c * CH * 1024, W1i, qkvB, 768);
        attn_mfma<1><<<dim3(H_, CH / 256), 256, 0, stream>>>(qkvB, Xb, c * (CH / 256));
    }
    // stage 2: freq attention (L=64) — GEMM variant A (2-block/CU, col-fast grid)
    for (int c = 0; c < NC; ++c) {
        gemm_bf16x3<true><<<dim3(6, CH / 128), 256, 0, stream>>>(
            Xb + (size_t)c * CH * 1024, W2i, qkvB, 768);
        attn_mfma<2><<<dim3(H_ / 2, CH / 64), 256, 0, stream>>>(qkvB, Xa, c * (CH / 64));
    }
    // stage 3: windowed attention (L=64) — GEMM variant A (replicate)
    for (int c = 0; c < NC; ++c) {
        gemm_bf16x3<true><<<dim3(6, CH / 128), 256, 0, stream>>>(
            Xa + (size_t)c * CH * 1024, W3i, qkvB, 768);
        attn_mfma<3><<<dim3(H_ / 2, CH / 64), 256, 0, stream>>>(qkvB, Xb, c * (CH / 64));
    }
    // c_proj (fp32 out, aliases dead qkv region) + output transpose
    for (int c = 0; c < NC; ++c) {
        gemm_bf16x3<false><<<dim3(2, CH / 128), 256, 0, stream>>>(
            Xb + (size_t)c * CH * 1024, Wpi, qkvF, 256);
        transpose_out<<<dim3(8, 2, CH / 64), dim3(32, 8), 0, stream>>>(
            qkvF, out, c * (CH / 64));
    }
}

// Round 7
// 456.086 us; speedup vs baseline: 4.9785x; 1.1520x over previous
//
#include <hip/hip_runtime.h>
#include <math.h>

#define B_  4
#define D_  256
#define T_  256
#define F_  64
#define H_  8

#define LN10000 9.210340371976184f
#define SM_SCALE 0.17677669529663687f   // 1/sqrt(32)

typedef float f32x4 __attribute__((ext_vector_type(4)));
typedef short s16x8 __attribute__((ext_vector_type(8)));

// ---------------------------------------------------------------- bf16 helpers
__device__ __forceinline__ unsigned short f2bf(float x) {
    unsigned u = __float_as_uint(x);
    return (unsigned short)((u + 0x7fffu + ((u >> 16) & 1u)) >> 16);
}
__device__ __forceinline__ float bf2f(unsigned short h) {
    return __uint_as_float(((unsigned)h) << 16);
}
__device__ __forceinline__ unsigned cvt_pk_bf16(float a, float b) {
    unsigned r;
    asm("v_cvt_pk_bf16_f32 %0, %1, %2" : "=v"(r) : "v"(a), "v"(b));
    return r;   // lo16 = bf16(a), hi16 = bf16(b)
}

// XCD-aware bijective remap of a 1D hardware block id (nwg % 8 == 0):
// XCD k (= lin % 8) owns the contiguous logical range [k*nwg/8, (k+1)*nwg/8).
__device__ __forceinline__ int xcd_swz(int lin, int nwg) {
    return (lin & 7) * (nwg >> 3) + (lin >> 3);
}

// ---------------------------------------------------------------- RoPE helper
__device__ __forceinline__ float2 rope_pair(float x0, float x1, int pairIdx, float pos) {
    float freq = __expf(-(float)(2 * pairIdx) * (LN10000 / 32.0f));
    float ang = pos * freq;
    float s, c;
    __sincosf(ang, &s, &c);
    return make_float2(x0 * c - x1 * s, x1 * c + x0 * s);
}

// ---------------------------------------------------------------- weight split
// W (64k x 128n fp32 tile) -> image block (nb*4+ks)*32KB, [n][k] bf16 hi/lo, swizzled
__global__ __launch_bounds__(256) void split_w(const float* __restrict__ W,
                                               char* __restrict__ img, int N) {
    __shared__ float Wt[64][132];
    const int nb = blockIdx.x, ks = blockIdx.y;
    const int tid = threadIdx.x;
#pragma unroll
    for (int j = 0; j < 8; ++j) {
        int idx = j * 1024 + tid * 4;
        int r = idx >> 7, cidx = idx & 127;
        const float4 v = *reinterpret_cast<const float4*>(
            &W[(size_t)(ks * 64 + r) * N + nb * 128 + cidx]);
        Wt[r][cidx] = v.x; Wt[r][cidx + 1] = v.y;
        Wt[r][cidx + 2] = v.z; Wt[r][cidx + 3] = v.w;
    }
    __syncthreads();
    char* base = img + ((size_t)(nb * 4 + ks)) * 32768;
#pragma unroll
    for (int i = 0; i < 4; ++i) {
        int p = i * 256 + tid;
        int n = p >> 3, seg = p & 7;
        s16x8 hi, lo;
#pragma unroll
        for (int e = 0; e < 8; ++e) {
            float v = Wt[seg * 8 + e][n];
            unsigned short hb = f2bf(v);
            hi[e] = (short)hb;
            lo[e] = (short)f2bf(v - bf2f(hb));
        }
        int off = n * 128 + ((seg * 16) ^ ((n & 7) << 4));
        *(s16x8*)(base + off) = hi;
        *(s16x8*)(base + 16384 + off) = lo;
    }
}

// ---------------------------------------------------------------- input transpose
// x (B, D, T, F) -> X image with tokens ordered (b, f, t)
__global__ __launch_bounds__(256) void transpose_in(const float* __restrict__ x,
                                                    char* __restrict__ Ximg) {
    __shared__ float tile[32][33];
    const int bt = blockIdx.z, b = bt >> 8, t = bt & 255;
    const int d0 = blockIdx.x * 32, f0 = blockIdx.y * 32;
    const int tx = threadIdx.x, ty = threadIdx.y;   // (32, 8)
    const size_t xbase = (size_t)b * D_ * T_ * F_ + (size_t)t * F_;
#pragma unroll
    for (int j = 0; j < 4; ++j) {
        int d = d0 + ty + j * 8;
        tile[ty + j * 8][tx] = x[xbase + (size_t)d * T_ * F_ + f0 + tx];
    }
    __syncthreads();
    const int tok = (b * 64 + f0 + tx) * 256 + t;
    const int rloc = tok & 127;
    const int hl = ty >> 2, seg = ty & 3;
    char* base = Ximg + ((size_t)((tok >> 7) * 4 + (d0 >> 6))) * 32768 + hl * 16384;
    const int off = rloc * 128 + ((((d0 & 32) << 1) + seg * 16) ^ ((rloc & 7) << 4));
    s16x8 v;
#pragma unroll
    for (int e = 0; e < 8; ++e) {
        float xv = tile[seg * 8 + e][tx];
        unsigned short hb = f2bf(xv);
        v[e] = hl ? (short)f2bf(xv - bf2f(hb)) : (short)hb;
    }
    *(s16x8*)(base + off) = v;
}

// ---------------------------------------------------------------- bf16x3 GEMM (XCD-swizzled 1D grid)
__global__ __launch_bounds__(256) void gemm_bf16x3(const char* __restrict__ Aimg,
                                                   const char* __restrict__ Bimg,
                                                   unsigned short* __restrict__ C, int N) {
    __shared__ alignas(16) char lds[65536];   // Ah|Al (32KB) + Bh|Bl (32KB)
    const int tid = threadIdx.x, lane = tid & 63, wave = tid >> 6;
    const int wm = wave >> 1, wn = wave & 1;
    const int rlo = lane & 15, rg = lane >> 4;
    const int wg = xcd_swz(blockIdx.x, gridDim.x);
    const int ncol = N >> 7;
    const int brow = wg / ncol, bcol = wg % ncol;
    f32x4 acc[4][4] = {};
    for (int ks = 0; ks < 4; ++ks) {
        const char* ga = Aimg + ((size_t)(brow * 4 + ks)) * 32768 + wave * 8192 + lane * 16;
        const char* gb = Bimg + ((size_t)(bcol * 4 + ks)) * 32768 + wave * 8192 + lane * 16;
        char* la = lds + wave * 8192;
        char* lb = lds + 32768 + wave * 8192;
#pragma unroll
        for (int i = 0; i < 8; ++i) {
            __builtin_amdgcn_global_load_lds(
                (const __attribute__((address_space(1))) void*)(ga + i * 1024),
                (__attribute__((address_space(3))) void*)(la + i * 1024), 16, 0, 0);
            __builtin_amdgcn_global_load_lds(
                (const __attribute__((address_space(1))) void*)(gb + i * 1024),
                (__attribute__((address_space(3))) void*)(lb + i * 1024), 16, 0, 0);
        }
        __syncthreads();
#pragma unroll
        for (int kk = 0; kk < 2; ++kk) {
            s16x8 ah[4], al[4], bh[4], bl[4];
#pragma unroll
            for (int i = 0; i < 4; ++i) {
                const int ra = wm * 64 + i * 16 + rlo;
                const int ka = (kk * 64 + rg * 16) ^ ((ra & 7) << 4);
                ah[i] = *(const s16x8*)(lds + ra * 128 + ka);
                al[i] = *(const s16x8*)(lds + 16384 + ra * 128 + ka);
                const int rb = wn * 64 + i * 16 + rlo;
                const int kb = (kk * 64 + rg * 16) ^ ((rb & 7) << 4);
                bh[i] = *(const s16x8*)(lds + 32768 + rb * 128 + kb);
                bl[i] = *(const s16x8*)(lds + 49152 + rb * 128 + kb);
            }
#pragma unroll
            for (int mt = 0; mt < 4; ++mt)
#pragma unroll
                for (int nt = 0; nt < 4; ++nt) {
                    acc[mt][nt] = __builtin_amdgcn_mfma_f32_16x16x32_bf16(ah[mt], bh[nt], acc[mt][nt], 0, 0, 0);
                    acc[mt][nt] = __builtin_amdgcn_mfma_f32_16x16x32_bf16(ah[mt], bl[nt], acc[mt][nt], 0, 0, 0);
                    acc[mt][nt] = __builtin_amdgcn_mfma_f32_16x16x32_bf16(al[mt], bh[nt], acc[mt][nt], 0, 0, 0);
                }
        }
        __syncthreads();
    }
    const int row0 = brow * 128 + wm * 64, col0 = bcol * 128 + wn * 64;
#pragma unroll
    for (int mt = 0; mt < 4; ++mt)
#pragma unroll
        for (int nt = 0; nt < 4; ++nt)
#pragma unroll
            for (int r = 0; r < 4; ++r)
                C[(size_t)(row0 + mt * 16 + rg * 4 + r) * N + col0 + nt * 16 + rlo] =
                    f2bf(acc[mt][nt][r]);
}

// ---------------------------------------------------------------- fused c_proj GEMM + (b,d,t,f) scatter
// N = 256. Epilogue transposes C tile through reused LDS and writes out directly.
__global__ __launch_bounds__(256) void gemm_cproj(const char* __restrict__ Aimg,
                                                  const char* __restrict__ Bimg,
                                                  float* __restrict__ out, int tok0) {
    __shared__ alignas(16) char lds[65536];
    const int tid = threadIdx.x, lane = tid & 63, wave = tid >> 6;
    const int wm = wave >> 1, wn = wave & 1;
    const int rlo = lane & 15, rg = lane >> 4;
    const int wg = xcd_swz(blockIdx.x, gridDim.x);
    const int brow = wg >> 1, bcol = wg & 1;
    f32x4 acc[4][4] = {};
    for (int ks = 0; ks < 4; ++ks) {
        const char* ga = Aimg + ((size_t)(brow * 4 + ks)) * 32768 + wave * 8192 + lane * 16;
        const char* gb = Bimg + ((size_t)(bcol * 4 + ks)) * 32768 + wave * 8192 + lane * 16;
        char* la = lds + wave * 8192;
        char* lb = lds + 32768 + wave * 8192;
#pragma unroll
        for (int i = 0; i < 8; ++i) {
            __builtin_amdgcn_global_load_lds(
                (const __attribute__((address_space(1))) void*)(ga + i * 1024),
                (__attribute__((address_space(3))) void*)(la + i * 1024), 16, 0, 0);
            __builtin_amdgcn_global_load_lds(
                (const __attribute__((address_space(1))) void*)(gb + i * 1024),
                (__attribute__((address_space(3))) void*)(lb + i * 1024), 16, 0, 0);
        }
        __syncthreads();
#pragma unroll
        for (int kk = 0; kk < 2; ++kk) {
            s16x8 ah[4], al[4], bh[4], bl[4];
#pragma unroll
            for (int i = 0; i < 4; ++i) {
                const int ra = wm * 64 + i * 16 + rlo;
                const int ka = (kk * 64 + rg * 16) ^ ((ra & 7) << 4);
                ah[i] = *(const s16x8*)(lds + ra * 128 + ka);
                al[i] = *(const s16x8*)(lds + 16384 + ra * 128 + ka);
                const int rb = wn * 64 + i * 16 + rlo;
                const int kb = (kk * 64 + rg * 16) ^ ((rb & 7) << 4);
                bh[i] = *(const s16x8*)(lds + 32768 + rb * 128 + kb);
                bl[i] = *(const s16x8*)(lds + 49152 + rb * 128 + kb);
            }
#pragma unroll
            for (int mt = 0; mt < 4; ++mt)
#pragma unroll
                for (int nt = 0; nt < 4; ++nt) {
                    acc[mt][nt] = __builtin_amdgcn_mfma_f32_16x16x32_bf16(ah[mt], bh[nt], acc[mt][nt], 0, 0, 0);
                    acc[mt][nt] = __builtin_amdgcn_mfma_f32_16x16x32_bf16(ah[mt], bl[nt], acc[mt][nt], 0, 0, 0);
                    acc[mt][nt] = __builtin_amdgcn_mfma_f32_16x16x32_bf16(al[mt], bh[nt], acc[mt][nt], 0, 0, 0);
                }
        }
        __syncthreads();
    }
    // ---- in-LDS transpose: ct[d][tok ^ ((d&7)<<2)], 128x128 f32 = 64 KB (aliases staging) ----
    float* ct = (float*)lds;
#pragma unroll
    for (int mt = 0; mt < 4; ++mt)
#pragma unroll
        for (int nt = 0; nt < 4; ++nt)
#pragma unroll
            for (int r = 0; r < 4; ++r) {
                const int tok = wm * 64 + mt * 16 + rg * 4 + r;
                const int d   = wn * 64 + nt * 16 + rlo;
                ct[d * 128 + (tok ^ ((d & 7) << 2))] = acc[mt][nt][r];
            }
    __syncthreads();
    const int tokb = tok0 + brow * 128;       // 128 consecutive (b,t,f) tokens
    const int bidx = tokb >> 14;
    const int t0 = (tokb >> 6) & 255;         // spans t0, t0+1 x f=0..63
    const int dcol0 = bcol * 128;
#pragma unroll
    for (int it = 0; it < 16; ++it) {
        const int seg = it * 16 + (tid >> 4);  // 256 segs: d(128) x tt(2)
        const int dd = seg >> 1, tt = seg & 1;
        const int f0 = (tid & 15) * 4;
        const float4 v = *(const float4*)&ct[dd * 128 + ((tt * 64 + f0) ^ ((dd & 7) << 2))];
        *(float4*)&out[((size_t)((bidx * 256 + dcol0 + dd) * 256 + t0 + tt)) * 64 + f0] = v;
    }
}

// ---------------------------------------------------------------- MFMA attention
// qkv is bf16 row-major [tok][768]. STAGE=1: L=256, 1 head/block; 2/3: L=64, 2 heads.
// 1D grid, XCD-swizzled: all heads of a sequence land on the same XCD.
template <int STAGE>
__global__ __launch_bounds__(256) void attn_mfma(const unsigned short* __restrict__ qkv,
                                                 char* __restrict__ Ximg, int s0) {
    constexpr int L   = (STAGE == 1) ? 256 : 64;
    constexpr int HPB = (STAGE == 1) ? 1 : 2;
    constexpr int GX  = (STAGE == 1) ? 8 : 4;     // head-blocks per sequence
    constexpr int NCH = L / 32;
    constexpr int KFB = L * 64;            // Kf bytes per head (= Vf bytes)
    __shared__ alignas(16) char kvLds[HPB * 2 * KFB];
    __shared__ alignas(16) float Osc[4][16][36];
    const int tid = threadIdx.x, lane = tid & 63, wave = tid >> 6;
    const int wg = xcd_swz(blockIdx.x, gridDim.x);
    const int hx = wg & (GX - 1);
    const int sl = wg / GX;

    // ---- stage K (rope'd) and V into fragment-ordered LDS ----
    {
        const int nIter = (STAGE == 1) ? 2 : 1;
#pragma unroll
        for (int it = 0; it < nIter; ++it) {
            int idx, headl;
            if (STAGE == 1) { idx = it * 256 + tid; headl = 0; }
            else            { idx = tid & 127;      headl = tid >> 7; }
            const int k = idx >> 1, dh = idx & 1;
            const int h = hx * HPB + headl;
            const size_t grow = ((size_t)(sl * L + k)) * 768 + h * 32 + dh * 16;
            const s16x8 kr0 = *(const s16x8*)&qkv[grow + 256];
            const s16x8 kr1 = *(const s16x8*)&qkv[grow + 264];
            const s16x8 vr0 = *(const s16x8*)&qkv[grow + 512];
            const s16x8 vr1 = *(const s16x8*)&qkv[grow + 520];
            float kvv[16];
#pragma unroll
            for (int e = 0; e < 8; ++e) {
                kvv[e]     = bf2f((unsigned short)kr0[e]);
                kvv[8 + e] = bf2f((unsigned short)kr1[e]);
            }
#pragma unroll
            for (int j = 0; j < 8; ++j) {
                float2 r = rope_pair(kvv[2 * j], kvv[2 * j + 1], dh * 8 + j, (float)k);
                kvv[2 * j] = r.x; kvv[2 * j + 1] = r.y;
            }
            char* kf = kvLds + headl * 2 * KFB;
#pragma unroll
            for (int jg = 0; jg < 2; ++jg) {
                s16x8 w;
#pragma unroll
                for (int e = 0; e < 8; ++e) w[e] = (short)f2bf(kvv[jg * 8 + e]);
                *(s16x8*)(kf + ((k >> 4) * 64 + (k & 15) + 16 * (dh * 2 + jg)) * 16) = w;
            }
            char* vf = kvLds + headl * 2 * KFB + KFB;
            const int sb = (k >> 5) * 2 + dh;
            const int lgo = 16 * ((k >> 3) & 3);
            const int eo = (k & 7) * 2;
#pragma unroll
            for (int dp = 0; dp < 16; ++dp) {
                const unsigned short vv = (unsigned short)((dp < 8) ? vr0[dp] : vr1[dp - 8]);
                *(unsigned short*)(vf + sb * 1024 + (dp + lgo) * 16 + eo) = vv;
            }
        }
    }
    __syncthreads();

    // ---- compute ----
    const int headl = (STAGE == 1) ? 0 : (wave >> 1);
    const int h = hx * HPB + headl;
    const char* Kf = kvLds + headl * 2 * KFB;
    const char* Vf = Kf + KFB;
    const int nPass = (STAGE == 1) ? 4 : 2;
    const int addr_lo = ((lane & 15) + ((lane >> 4) & 1) * 32) * 4;
    const int addr_hi = addr_lo + 64;
    const bool hiSel = lane >= 32;

    for (int pass = 0; pass < nPass; ++pass) {
        const int qbase = (STAGE == 1) ? ((wave & 3) * 16 + pass * 64)
                                       : ((wave & 1) * 16 + pass * 32);
        const int q = qbase + (lane & 15);
        s16x8 qf;
        {
            const size_t qrow = ((size_t)(sl * L + q)) * 768 + h * 32 + (lane >> 4) * 8;
            const s16x8 qr = *(const s16x8*)&qkv[qrow];
            float qv[8];
#pragma unroll
            for (int e = 0; e < 8; ++e) qv[e] = bf2f((unsigned short)qr[e]);
#pragma unroll
            for (int j = 0; j < 4; ++j) {
                float2 r = rope_pair(qv[2 * j], qv[2 * j + 1], (lane >> 4) * 4 + j, (float)q);
                qf[2 * j]     = (short)f2bf(r.x * SM_SCALE);
                qf[2 * j + 1] = (short)f2bf(r.y * SM_SCALE);
            }
        }
        f32x4 olo = {0.f, 0.f, 0.f, 0.f}, ohi = {0.f, 0.f, 0.f, 0.f};
        const f32x4 zero = {0.f, 0.f, 0.f, 0.f};
        float m = -INFINITY, lsum = 0.f;
#pragma unroll
        for (int c = 0; c < NCH; ++c) {
            const s16x8 ka = *(const s16x8*)(Kf + (c * 2) * 1024 + lane * 16);
            const s16x8 kb = *(const s16x8*)(Kf + (c * 2 + 1) * 1024 + lane * 16);
            f32x4 sA = __builtin_amdgcn_mfma_f32_16x16x32_bf16(ka, qf, zero, 0, 0, 0);
            f32x4 sB = __builtin_amdgcn_mfma_f32_16x16x32_bf16(kb, qf, zero, 0, 0, 0);
            float cmax = fmaxf(fmaxf(fmaxf(sA[0], sA[1]), fmaxf(sA[2], sA[3])),
                               fmaxf(fmaxf(sB[0], sB[1]), fmaxf(sB[2], sB[3])));
            cmax = fmaxf(cmax, __shfl_xor(cmax, 16, 64));
            cmax = fmaxf(cmax, __shfl_xor(cmax, 32, 64));
            const float mnew = fmaxf(m, cmax);
            const float corr = __expf(m - mnew);
            m = mnew;
            float p[8];
#pragma unroll
            for (int e = 0; e < 4; ++e) p[e] = __expf(sA[e] - mnew);
#pragma unroll
            for (int e = 0; e < 4; ++e) p[4 + e] = __expf(sB[e] - mnew);
            float ps = ((p[0] + p[1]) + (p[2] + p[3])) + ((p[4] + p[5]) + (p[6] + p[7]));
            lsum = lsum * corr + ps;
            const int t0w0 = (int)cvt_pk_bf16(p[0], p[1]);
            const int t0w1 = (int)cvt_pk_bf16(p[2], p[3]);
            const int t1w0 = (int)cvt_pk_bf16(p[4], p[5]);
            const int t1w1 = (int)cvt_pk_bf16(p[6], p[7]);
            union { int u[4]; s16x8 v; } Af;
            const int a0 = __builtin_amdgcn_ds_bpermute(addr_lo, t0w0);
            const int a1 = __builtin_amdgcn_ds_bpermute(addr_lo, t0w1);
            const int a2 = __builtin_amdgcn_ds_bpermute(addr_hi, t0w0);
            const int a3 = __builtin_amdgcn_ds_bpermute(addr_hi, t0w1);
            const int b0 = __builtin_amdgcn_ds_bpermute(addr_lo, t1w0);
            const int b1 = __builtin_amdgcn_ds_bpermute(addr_lo, t1w1);
            const int b2 = __builtin_amdgcn_ds_bpermute(addr_hi, t1w0);
            const int b3 = __builtin_amdgcn_ds_bpermute(addr_hi, t1w1);
            Af.u[0] = hiSel ? b0 : a0;
            Af.u[1] = hiSel ? b1 : a1;
            Af.u[2] = hiSel ? b2 : a2;
            Af.u[3] = hiSel ? b3 : a3;
#pragma unroll
            for (int r = 0; r < 4; ++r) {
                const float fr = __shfl(corr, (lane >> 4) * 4 + r, 64);
                olo[r] *= fr; ohi[r] *= fr;
            }
            const s16x8 va = *(const s16x8*)(Vf + (c * 2) * 1024 + lane * 16);
            const s16x8 vb = *(const s16x8*)(Vf + (c * 2 + 1) * 1024 + lane * 16);
            olo = __builtin_amdgcn_mfma_f32_16x16x32_bf16(Af.v, va, olo, 0, 0, 0);
            ohi = __builtin_amdgcn_mfma_f32_16x16x32_bf16(Af.v, vb, ohi, 0, 0, 0);
        }
        // ---- normalize + transpose via wave-private LDS ----
        lsum += __shfl_xor(lsum, 16, 64);
        lsum += __shfl_xor(lsum, 32, 64);
        const float inv = 1.0f / lsum;
#pragma unroll
        for (int r = 0; r < 4; ++r) {
            const float ir = __shfl(inv, (lane >> 4) * 4 + r, 64);
            Osc[wave][(lane >> 4) * 4 + r][lane & 15]        = olo[r] * ir;
            Osc[wave][(lane >> 4) * 4 + r][16 + (lane & 15)] = ohi[r] * ir;
        }
        const int seg = lane >> 4;
        float v8[8];
        *(float4*)&v8[0] = *(const float4*)&Osc[wave][lane & 15][seg * 8];
        *(float4*)&v8[4] = *(const float4*)&Osc[wave][lane & 15][seg * 8 + 4];
        int tok;
        if constexpr (STAGE == 1) {
            const int s = s0 + sl, b = s >> 6, f = s & 63;
            tok = (b * 256 + q) * 64 + f;
        } else if constexpr (STAGE == 2) {
            const int s2 = s0 + sl, b = s2 >> 8, t = s2 & 255;
            tok = ((b * 32 + (t >> 3)) * 8 + (q >> 3)) * 64 + (t & 7) * 8 + (q & 7);
        } else {
            const int w = s0 + sl, b = w >> 8, tb = (w >> 3) & 31, fb = w & 7;
            tok = (b * 256 + tb * 8 + (q >> 3)) * 64 + fb * 8 + (q & 7);
        }
        const int rloc = tok & 127;
        char* base = Ximg + ((size_t)((tok >> 7) * 4 + (h >> 1))) * 32768;
        const int off = rloc * 128 + ((((h & 1) * 64) + seg * 16) ^ ((rloc & 7) << 4));
        s16x8 hi, lo;
#pragma unroll
        for (int e = 0; e < 8; ++e) {
            unsigned short hb = f2bf(v8[e]);
            hi[e] = (short)hb;
            lo[e] = (short)f2bf(v8[e] - bf2f(hb));
        }
        *(s16x8*)(base + off) = hi;
        *(s16x8*)(base + 16384 + off) = lo;
    }
}

// ---------------------------------------------------------------- launch
extern "C" void kernel_launch(void* const* d_in, const int* in_sizes, int n_in,
                              void* d_out, int out_size, void* d_ws, size_t ws_size,
                              hipStream_t stream) {
    const float* x  = (const float*)d_in[0];
    const float* W1 = (const float*)d_in[1];
    const float* W2 = (const float*)d_in[2];
    const float* W3 = (const float*)d_in[3];
    const float* Wp = (const float*)d_in[4];
    float* out = (float*)d_out;

    const size_t M = (size_t)B_ * T_ * F_;        // 65536 tokens
    char* Xa = (char*)d_out;                      // image buffer A (X1, X3)
    char* Xb = (char*)d_ws;                       // image buffer B (X2, X4)
    char* W1i = (char*)d_ws + M * 1024;           // weight images
    char* W2i = W1i + 786432;
    char* W3i = W2i + 786432;
    char* Wpi = W3i + 786432;
    unsigned short* qkvB = (unsigned short*)(Wpi + 262144);  // bf16 qkv

    // adaptive chunk (tokens): qkv chunk is CH*768 bf16 = CH*1536 bytes
    const size_t fixedBytes = M * 1024 + 3 * 786432 + 262144;
    int CH = 2048;
    const int cands[5] = {65536, 32768, 16384, 8192, 4096};
    for (int i = 0; i < 5; ++i) {
        if (fixedBytes + (size_t)cands[i] * 1536 <= ws_size) { CH = cands[i]; break; }
    }
    const int NC = (int)(M / CH);

    split_w<<<dim3(6, 4), 256, 0, stream>>>(W1, W1i, 768);
    split_w<<<dim3(6, 4), 256, 0, stream>>>(W2, W2i, 768);
    split_w<<<dim3(6, 4), 256, 0, stream>>>(W3, W3i, 768);
    split_w<<<dim3(2, 4), 256, 0, stream>>>(Wp, Wpi, 256);

    transpose_in<<<dim3(8, 2, 1024), dim3(32, 8), 0, stream>>>(x, Xa);

    // stage 1: time attention (L=256)
    for (int c = 0; c < NC; ++c) {
        gemm_bf16x3<<<(CH / 128) * 6, 256, 0, stream>>>(
            Xa + (size_t)c * CH * 1024, W1i, qkvB, 768);
        attn_mfma<1><<<8 * (CH / 256), 256, 0, stream>>>(qkvB, Xb, c * (CH / 256));
    }
    // stage 2: freq attention (L=64)
    for (int c = 0; c < NC; ++c) {
        gemm_bf16x3<<<(CH / 128) * 6, 256, 0, stream>>>(
            Xb + (size_t)c * CH * 1024, W2i, qkvB, 768);
        attn_mfma<2><<<4 * (CH / 64), 256, 0, stream>>>(qkvB, Xa, c * (CH / 64));
    }
    // stage 3: windowed attention (L=64)
    for (int c = 0; c < NC; ++c) {
        gemm_bf16x3<<<(CH / 128) * 6, 256, 0, stream>>>(
            Xa + (size_t)c * CH * 1024, W3i, qkvB, 768);
        attn_mfma<3><<<4 * (CH / 64), 256, 0, stream>>>(qkvB, Xb, c * (CH / 64));
    }
    // fused c_proj + output scatter (reads Xb, writes final out)
    for (int c = 0; c < NC; ++c) {
        gemm_cproj<<<(CH / 128) * 2, 256, 0, stream>>>(
            Xb + (size_t)c * CH * 1024, Wpi, out, c * CH);
    }
}

// Round 9
// 440.275 us; speedup vs baseline: 5.1573x; 1.0359x over previous
//
#include <hip/hip_runtime.h>
#include <math.h>

#define B_  4
#define D_  256
#define T_  256
#define F_  64
#define H_  8

#define LN10000 9.210340371976184f
#define SM_SCALE 0.17677669529663687f   // 1/sqrt(32)

typedef float f32x4  __attribute__((ext_vector_type(4)));
typedef float f32x16 __attribute__((ext_vector_type(16)));
typedef short s16x8  __attribute__((ext_vector_type(8)));

// ---------------------------------------------------------------- bf16 helpers
__device__ __forceinline__ unsigned short f2bf(float x) {
    unsigned u = __float_as_uint(x);
    return (unsigned short)((u + 0x7fffu + ((u >> 16) & 1u)) >> 16);
}
__device__ __forceinline__ float bf2f(unsigned short h) {
    return __uint_as_float(((unsigned)h) << 16);
}
__device__ __forceinline__ int cvt_pk_bf16(float a, float b) {
    int r;
    asm("v_cvt_pk_bf16_f32 %0, %1, %2" : "=v"(r) : "v"(a), "v"(b));
    return r;   // lo16 = bf16(a), hi16 = bf16(b)
}

// XCD-aware bijective remap of a 1D block id (nwg % 8 == 0)
__device__ __forceinline__ int xcd_swz(int lin, int nwg) {
    return (lin & 7) * (nwg >> 3) + (lin >> 3);
}

// ---------------------------------------------------------------- RoPE helper
__device__ __forceinline__ float2 rope_pair(float x0, float x1, int pairIdx, float pos) {
    float freq = __expf(-(float)(2 * pairIdx) * (LN10000 / 32.0f));
    float ang = pos * freq;
    float s, c;
    __sincosf(ang, &s, &c);
    return make_float2(x0 * c - x1 * s, x1 * c + x0 * s);
}

// ---------------------------------------------------------------- weight split
__global__ __launch_bounds__(256) void split_w(const float* __restrict__ W,
                                               char* __restrict__ img, int N) {
    __shared__ float Wt[64][132];
    const int nb = blockIdx.x, ks = blockIdx.y;
    const int tid = threadIdx.x;
#pragma unroll
    for (int j = 0; j < 8; ++j) {
        int idx = j * 1024 + tid * 4;
        int r = idx >> 7, cidx = idx & 127;
        const float4 v = *reinterpret_cast<const float4*>(
            &W[(size_t)(ks * 64 + r) * N + nb * 128 + cidx]);
        Wt[r][cidx] = v.x; Wt[r][cidx + 1] = v.y;
        Wt[r][cidx + 2] = v.z; Wt[r][cidx + 3] = v.w;
    }
    __syncthreads();
    char* base = img + ((size_t)(nb * 4 + ks)) * 32768;
#pragma unroll
    for (int i = 0; i < 4; ++i) {
        int p = i * 256 + tid;
        int n = p >> 3, seg = p & 7;
        s16x8 hi, lo;
#pragma unroll
        for (int e = 0; e < 8; ++e) {
            float v = Wt[seg * 8 + e][n];
            unsigned short hb = f2bf(v);
            hi[e] = (short)hb;
            lo[e] = (short)f2bf(v - bf2f(hb));
        }
        int off = n * 128 + ((seg * 16) ^ ((n & 7) << 4));
        *(s16x8*)(base + off) = hi;
        *(s16x8*)(base + 16384 + off) = lo;
    }
}

// ---------------------------------------------------------------- input transpose
__global__ __launch_bounds__(256) void transpose_in(const float* __restrict__ x,
                                                    char* __restrict__ Ximg) {
    __shared__ float tile[32][33];
    const int bt = blockIdx.z, b = bt >> 8, t = bt & 255;
    const int d0 = blockIdx.x * 32, f0 = blockIdx.y * 32;
    const int tx = threadIdx.x, ty = threadIdx.y;   // (32, 8)
    const size_t xbase = (size_t)b * D_ * T_ * F_ + (size_t)t * F_;
#pragma unroll
    for (int j = 0; j < 4; ++j) {
        int d = d0 + ty + j * 8;
        tile[ty + j * 8][tx] = x[xbase + (size_t)d * T_ * F_ + f0 + tx];
    }
    __syncthreads();
    const int tok = (b * 64 + f0 + tx) * 256 + t;
    const int rloc = tok & 127;
    const int hl = ty >> 2, seg = ty & 3;
    char* base = Ximg + ((size_t)((tok >> 7) * 4 + (d0 >> 6))) * 32768 + hl * 16384;
    const int off = rloc * 128 + ((((d0 & 32) << 1) + seg * 16) ^ ((rloc & 7) << 4));
    s16x8 v;
#pragma unroll
    for (int e = 0; e < 8; ++e) {
        float xv = tile[seg * 8 + e][tx];
        unsigned short hb = f2bf(xv);
        v[e] = hl ? (short)f2bf(xv - bf2f(hb)) : (short)hb;
    }
    *(s16x8*)(base + off) = v;
}

// ---------------------------------------------------------------- bf16x3 GEMM (XCD-swizzled 1D grid)
__global__ __launch_bounds__(256) void gemm_bf16x3(const char* __restrict__ Aimg,
                                                   const char* __restrict__ Bimg,
                                                   unsigned short* __restrict__ C, int N) {
    __shared__ alignas(16) char lds[65536];
    const int tid = threadIdx.x, lane = tid & 63, wave = tid >> 6;
    const int wm = wave >> 1, wn = wave & 1;
    const int rlo = lane & 15, rg = lane >> 4;
    const int wg = xcd_swz(blockIdx.x, gridDim.x);
    const int ncol = N >> 7;
    const int brow = wg / ncol, bcol = wg % ncol;
    f32x4 acc[4][4] = {};
    for (int ks = 0; ks < 4; ++ks) {
        const char* ga = Aimg + ((size_t)(brow * 4 + ks)) * 32768 + wave * 8192 + lane * 16;
        const char* gb = Bimg + ((size_t)(bcol * 4 + ks)) * 32768 + wave * 8192 + lane * 16;
        char* la = lds + wave * 8192;
        char* lb = lds + 32768 + wave * 8192;
#pragma unroll
        for (int i = 0; i < 8; ++i) {
            __builtin_amdgcn_global_load_lds(
                (const __attribute__((address_space(1))) void*)(ga + i * 1024),
                (__attribute__((address_space(3))) void*)(la + i * 1024), 16, 0, 0);
            __builtin_amdgcn_global_load_lds(
                (const __attribute__((address_space(1))) void*)(gb + i * 1024),
                (__attribute__((address_space(3))) void*)(lb + i * 1024), 16, 0, 0);
        }
        __syncthreads();
#pragma unroll
        for (int kk = 0; kk < 2; ++kk) {
            s16x8 ah[4], al[4], bh[4], bl[4];
#pragma unroll
            for (int i = 0; i < 4; ++i) {
                const int ra = wm * 64 + i * 16 + rlo;
                const int ka = (kk * 64 + rg * 16) ^ ((ra & 7) << 4);
                ah[i] = *(const s16x8*)(lds + ra * 128 + ka);
                al[i] = *(const s16x8*)(lds + 16384 + ra * 128 + ka);
                const int rb = wn * 64 + i * 16 + rlo;
                const int kb = (kk * 64 + rg * 16) ^ ((rb & 7) << 4);
                bh[i] = *(const s16x8*)(lds + 32768 + rb * 128 + kb);
                bl[i] = *(const s16x8*)(lds + 49152 + rb * 128 + kb);
            }
#pragma unroll
            for (int mt = 0; mt < 4; ++mt)
#pragma unroll
                for (int nt = 0; nt < 4; ++nt) {
                    acc[mt][nt] = __builtin_amdgcn_mfma_f32_16x16x32_bf16(ah[mt], bh[nt], acc[mt][nt], 0, 0, 0);
                    acc[mt][nt] = __builtin_amdgcn_mfma_f32_16x16x32_bf16(ah[mt], bl[nt], acc[mt][nt], 0, 0, 0);
                    acc[mt][nt] = __builtin_amdgcn_mfma_f32_16x16x32_bf16(al[mt], bh[nt], acc[mt][nt], 0, 0, 0);
                }
        }
        __syncthreads();
    }
    const int row0 = brow * 128 + wm * 64, col0 = bcol * 128 + wn * 64;
#pragma unroll
    for (int mt = 0; mt < 4; ++mt)
#pragma unroll
        for (int nt = 0; nt < 4; ++nt)
#pragma unroll
            for (int r = 0; r < 4; ++r)
                C[(size_t)(row0 + mt * 16 + rg * 4 + r) * N + col0 + nt * 16 + rlo] =
                    f2bf(acc[mt][nt][r]);
}

// ---------------------------------------------------------------- fused c_proj GEMM + (b,d,t,f) scatter
__global__ __launch_bounds__(256) void gemm_cproj(const char* __restrict__ Aimg,
                                                  const char* __restrict__ Bimg,
                                                  float* __restrict__ out, int tok0) {
    __shared__ alignas(16) char lds[65536];
    const int tid = threadIdx.x, lane = tid & 63, wave = tid >> 6;
    const int wm = wave >> 1, wn = wave & 1;
    const int rlo = lane & 15, rg = lane >> 4;
    const int wg = xcd_swz(blockIdx.x, gridDim.x);
    const int brow = wg >> 1, bcol = wg & 1;
    f32x4 acc[4][4] = {};
    for (int ks = 0; ks < 4; ++ks) {
        const char* ga = Aimg + ((size_t)(brow * 4 + ks)) * 32768 + wave * 8192 + lane * 16;
        const char* gb = Bimg + ((size_t)(bcol * 4 + ks)) * 32768 + wave * 8192 + lane * 16;
        char* la = lds + wave * 8192;
        char* lb = lds + 32768 + wave * 8192;
#pragma unroll
        for (int i = 0; i < 8; ++i) {
            __builtin_amdgcn_global_load_lds(
                (const __attribute__((address_space(1))) void*)(ga + i * 1024),
                (__attribute__((address_space(3))) void*)(la + i * 1024), 16, 0, 0);
            __builtin_amdgcn_global_load_lds(
                (const __attribute__((address_space(1))) void*)(gb + i * 1024),
                (__attribute__((address_space(3))) void*)(lb + i * 1024), 16, 0, 0);
        }
        __syncthreads();
#pragma unroll
        for (int kk = 0; kk < 2; ++kk) {
            s16x8 ah[4], al[4], bh[4], bl[4];
#pragma unroll
            for (int i = 0; i < 4; ++i) {
                const int ra = wm * 64 + i * 16 + rlo;
                const int ka = (kk * 64 + rg * 16) ^ ((ra & 7) << 4);
                ah[i] = *(const s16x8*)(lds + ra * 128 + ka);
                al[i] = *(const s16x8*)(lds + 16384 + ra * 128 + ka);
                const int rb = wn * 64 + i * 16 + rlo;
                const int kb = (kk * 64 + rg * 16) ^ ((rb & 7) << 4);
                bh[i] = *(const s16x8*)(lds + 32768 + rb * 128 + kb);
                bl[i] = *(const s16x8*)(lds + 49152 + rb * 128 + kb);
            }
#pragma unroll
            for (int mt = 0; mt < 4; ++mt)
#pragma unroll
                for (int nt = 0; nt < 4; ++nt) {
                    acc[mt][nt] = __builtin_amdgcn_mfma_f32_16x16x32_bf16(ah[mt], bh[nt], acc[mt][nt], 0, 0, 0);
                    acc[mt][nt] = __builtin_amdgcn_mfma_f32_16x16x32_bf16(ah[mt], bl[nt], acc[mt][nt], 0, 0, 0);
                    acc[mt][nt] = __builtin_amdgcn_mfma_f32_16x16x32_bf16(al[mt], bh[nt], acc[mt][nt], 0, 0, 0);
                }
        }
        __syncthreads();
    }
    float* ct = (float*)lds;
#pragma unroll
    for (int mt = 0; mt < 4; ++mt)
#pragma unroll
        for (int nt = 0; nt < 4; ++nt)
#pragma unroll
            for (int r = 0; r < 4; ++r) {
                const int tok = wm * 64 + mt * 16 + rg * 4 + r;
                const int d   = wn * 64 + nt * 16 + rlo;
                ct[d * 128 + (tok ^ ((d & 7) << 2))] = acc[mt][nt][r];
            }
    __syncthreads();
    const int tokb = tok0 + brow * 128;
    const int bidx = tokb >> 14;
    const int t0 = (tokb >> 6) & 255;
    const int dcol0 = bcol * 128;
#pragma unroll
    for (int it = 0; it < 16; ++it) {
        const int seg = it * 16 + (tid >> 4);
        const int dd = seg >> 1, tt = seg & 1;
        const int f0 = (tid & 15) * 4;
        const float4 v = *(const float4*)&ct[dd * 128 + ((tt * 64 + f0) ^ ((dd & 7) << 2))];
        *(float4*)&out[((size_t)((bidx * 256 + dcol0 + dd) * 256 + t0 + tt)) * 64 + f0] = v;
    }
}

// ---------------------------------------------------------------- MFMA attention (32x32, swapped ops, LDS-bounced P/epilogue)
// Lane owns q = qt*32 + (lane&31); lanes l and l^32 share q (C/D col = lane&31).
// S = mfma32(K, Q): rows = attn k, col = own q. Row-reduce in-register +
// __shfl_xor(32) partner merge. P routed through PLds with explicit pairrow
// addressing (pairrow = kr(2j)/2 = (j&1)+4*(j>>1)+2*hiSel from the verified
// C/D row map). O^T = mfma32(V^T, P): col = own q -> lane-local rescale.
// Epilogue through Osc (round-7-proven pattern, pad 36 keeps float4 aligned).
template <int STAGE>
__global__ __launch_bounds__(256) void attn_mfma(const unsigned short* __restrict__ qkv,
                                                 char* __restrict__ Ximg, int s0) {
    constexpr int L   = (STAGE == 1) ? 256 : 64;
    constexpr int HPB = (STAGE == 1) ? 1 : 2;
    constexpr int GX  = (STAGE == 1) ? 8 : 4;
    constexpr int NCH = L / 32;
    constexpr int KVB = L * 64;            // bytes per head for K frags (= V frags)
    __shared__ alignas(16) char kvLds[HPB * 2 * KVB];
    __shared__ int   PLds[4][16][32];
    __shared__ alignas(16) float Osc[4][32][36];
    const int tid = threadIdx.x, lane = tid & 63, wave = tid >> 6;
    const int hiSel = lane >> 5;
    const int qloc = lane & 31;
    const int wg = xcd_swz(blockIdx.x, gridDim.x);
    const int hx = wg & (GX - 1);
    const int sl = wg / GX;

    // ---- stage K (roped, A-frag order) and V (V^T A-frag order) ----
    {
        const int nIter = (STAGE == 1) ? 2 : 1;
#pragma unroll
        for (int it = 0; it < nIter; ++it) {
            int idx, headl;
            if (STAGE == 1) { idx = it * 256 + tid; headl = 0; }
            else            { idx = tid & 127;      headl = tid >> 7; }
            const int k = idx >> 1, dh = idx & 1;
            const int h = hx * HPB + headl;
            const size_t grow = ((size_t)(sl * L + k)) * 768 + h * 32 + dh * 16;
            const s16x8 kr0 = *(const s16x8*)&qkv[grow + 256];
            const s16x8 kr1 = *(const s16x8*)&qkv[grow + 264];
            const s16x8 vr0 = *(const s16x8*)&qkv[grow + 512];
            const s16x8 vr1 = *(const s16x8*)&qkv[grow + 520];
            float kvv[16];
#pragma unroll
            for (int e = 0; e < 8; ++e) {
                kvv[e]     = bf2f((unsigned short)kr0[e]);
                kvv[8 + e] = bf2f((unsigned short)kr1[e]);
            }
#pragma unroll
            for (int j = 0; j < 8; ++j) {
                float2 r = rope_pair(kvv[2 * j], kvv[2 * j + 1], dh * 8 + j, (float)k);
                kvv[2 * j] = r.x; kvv[2 * j + 1] = r.y;
            }
            char* kf = kvLds + headl * 2 * KVB;
            s16x8 wlo, whi;
#pragma unroll
            for (int e = 0; e < 8; ++e) {
                wlo[e] = (short)f2bf(kvv[e]);
                whi[e] = (short)f2bf(kvv[8 + e]);
            }
            *(s16x8*)(kf + (((k >> 5) * 2 + dh) * 64 + (k & 31)) * 16) = wlo;
            *(s16x8*)(kf + (((k >> 5) * 2 + dh) * 64 + 32 + (k & 31)) * 16) = whi;
            char* vf = kf + KVB;
            const int kb = k >> 4, hi8 = (k >> 3) & 1, eo = (k & 7) * 2;
#pragma unroll
            for (int dp = 0; dp < 16; ++dp) {
                const unsigned short vv = (unsigned short)((dp < 8) ? vr0[dp] : vr1[dp - 8]);
                *(unsigned short*)(vf + (kb * 64 + dh * 16 + dp + 32 * hi8) * 16 + eo) = vv;
            }
        }
    }
    __syncthreads();

    // ---- compute ----
    const int headl = (STAGE == 1) ? 0 : (wave >> 1);
    const int h = hx * HPB + headl;
    const char* Kf = kvLds + headl * 2 * KVB;
    const char* Vf = Kf + KVB;
    const int nPass = (STAGE == 1) ? 2 : 1;

    for (int pass = 0; pass < nPass; ++pass) {
        const int qt = (STAGE == 1) ? (wave + pass * 4) : (wave & 1);
        const int q = qt * 32 + qloc;
        // Q fragments (rope + scale folded)
        s16x8 qf0, qf1;
        {
            const size_t qrow = ((size_t)(sl * L + q)) * 768 + h * 32;
            const s16x8 qr0 = *(const s16x8*)&qkv[qrow + hiSel * 8];
            const s16x8 qr1 = *(const s16x8*)&qkv[qrow + 16 + hiSel * 8];
#pragma unroll
            for (int j = 0; j < 4; ++j) {
                float2 r0 = rope_pair(bf2f((unsigned short)qr0[2 * j]),
                                      bf2f((unsigned short)qr0[2 * j + 1]),
                                      hiSel * 4 + j, (float)q);
                qf0[2 * j]     = (short)f2bf(r0.x * SM_SCALE);
                qf0[2 * j + 1] = (short)f2bf(r0.y * SM_SCALE);
                float2 r1 = rope_pair(bf2f((unsigned short)qr1[2 * j]),
                                      bf2f((unsigned short)qr1[2 * j + 1]),
                                      8 + hiSel * 4 + j, (float)q);
                qf1[2 * j]     = (short)f2bf(r1.x * SM_SCALE);
                qf1[2 * j + 1] = (short)f2bf(r1.y * SM_SCALE);
            }
        }
        f32x16 o = (f32x16)0.0f;
        float m = -INFINITY, lsum = 0.f;
#pragma unroll
        for (int c = 0; c < NCH; ++c) {
            const s16x8 ka = *(const s16x8*)(Kf + (c * 2 + 0) * 1024 + lane * 16);
            const s16x8 kb = *(const s16x8*)(Kf + (c * 2 + 1) * 1024 + lane * 16);
            f32x16 S = (f32x16)0.0f;
            S = __builtin_amdgcn_mfma_f32_32x32x16_bf16(ka, qf0, S, 0, 0, 0);
            S = __builtin_amdgcn_mfma_f32_32x32x16_bf16(kb, qf1, S, 0, 0, 0);
            float cmax = S[0];
#pragma unroll
            for (int r = 1; r < 16; ++r) cmax = fmaxf(cmax, S[r]);
            cmax = fmaxf(cmax, __shfl_xor(cmax, 32, 64));
            if (__any(cmax > m + 8.0f)) {        // defer-max (THR=8)
                const float mnew = fmaxf(m, cmax);
                const float corr = __expf(m - mnew);
                m = mnew;
                lsum *= corr;
#pragma unroll
                for (int r = 0; r < 16; ++r) o[r] *= corr;
            }
            float p[16], ssum = 0.f;
#pragma unroll
            for (int r = 0; r < 16; ++r) { p[r] = __expf(S[r] - m); ssum += p[r]; }
            lsum += ssum;
            // P -> PLds (explicit pairrow addressing), read back PV B-frags
#pragma unroll
            for (int j = 0; j < 8; ++j)
                PLds[wave][(j & 1) + 4 * (j >> 1) + 2 * hiSel][qloc] =
                    cvt_pk_bf16(p[2 * j], p[2 * j + 1]);
            union { int u[4]; s16x8 v; } P0, P1;
#pragma unroll
            for (int i = 0; i < 4; ++i) {
                P0.u[i] = PLds[wave][hiSel * 4 + i][qloc];
                P1.u[i] = PLds[wave][8 + hiSel * 4 + i][qloc];
            }
            const s16x8 va = *(const s16x8*)(Vf + (c * 2 + 0) * 1024 + lane * 16);
            const s16x8 vb = *(const s16x8*)(Vf + (c * 2 + 1) * 1024 + lane * 16);
            o = __builtin_amdgcn_mfma_f32_32x32x16_bf16(va, P0.v, o, 0, 0, 0);
            o = __builtin_amdgcn_mfma_f32_32x32x16_bf16(vb, P1.v, o, 0, 0, 0);
        }
        // ---- epilogue via Osc ----
        lsum += __shfl_xor(lsum, 32, 64);
        const float inv = 1.0f / lsum;
#pragma unroll
        for (int r = 0; r < 16; ++r)
            Osc[wave][qloc][(r & 3) + 8 * (r >> 2) + 4 * hiSel] = o[r] * inv;
        int tok;
        if constexpr (STAGE == 1) {
            const int s = s0 + sl, b = s >> 6, f = s & 63;
            tok = (b * 256 + q) * 64 + f;
        } else if constexpr (STAGE == 2) {
            const int s2 = s0 + sl, b = s2 >> 8, t = s2 & 255;
            tok = ((b * 32 + (t >> 3)) * 8 + (q >> 3)) * 64 + (t & 7) * 8 + (q & 7);
        } else {
            const int w = s0 + sl, b = w >> 8, tb = (w >> 3) & 31, fb = w & 7;
            tok = (b * 256 + tb * 8 + (q >> 3)) * 64 + fb * 8 + (q & 7);
        }
        const int rloc = tok & 127;
        char* base = Ximg + ((size_t)((tok >> 7) * 4 + (h >> 1))) * 32768;
        const int sw = (rloc & 7) << 4;
        const int hb64 = (h & 1) * 64;
#pragma unroll
        for (int gg = 0; gg < 2; ++gg) {
            const int g = hiSel * 2 + gg;
            float v8[8];
            *(float4*)&v8[0] = *(const float4*)&Osc[wave][qloc][g * 8];
            *(float4*)&v8[4] = *(const float4*)&Osc[wave][qloc][g * 8 + 4];
            s16x8 hi, lo;
#pragma unroll
            for (int e = 0; e < 8; ++e) {
                unsigned short hb = f2bf(v8[e]);
                hi[e] = (short)hb;
                lo[e] = (short)f2bf(v8[e] - bf2f(hb));
            }
            const int off = rloc * 128 + ((hb64 + g * 16) ^ sw);
            *(s16x8*)(base + off) = hi;
            *(s16x8*)(base + 16384 + off) = lo;
        }
    }
}

// ---------------------------------------------------------------- launch
extern "C" void kernel_launch(void* const* d_in, const int* in_sizes, int n_in,
                              void* d_out, int out_size, void* d_ws, size_t ws_size,
                              hipStream_t stream) {
    const float* x  = (const float*)d_in[0];
    const float* W1 = (const float*)d_in[1];
    const float* W2 = (const float*)d_in[2];
    const float* W3 = (const float*)d_in[3];
    const float* Wp = (const float*)d_in[4];
    float* out = (float*)d_out;

    const size_t M = (size_t)B_ * T_ * F_;        // 65536 tokens
    char* Xa = (char*)d_out;                      // image buffer A (X1, X3)
    char* Xb = (char*)d_ws;                       // image buffer B (X2, X4)
    char* W1i = (char*)d_ws + M * 1024;           // weight images
    char* W2i = W1i + 786432;
    char* W3i = W2i + 786432;
    char* Wpi = W3i + 786432;
    unsigned short* qkvB = (unsigned short*)(Wpi + 262144);  // bf16 qkv

    const size_t fixedBytes = M * 1024 + 3 * 786432 + 262144;
    int CH = 2048;
    const int cands[5] = {65536, 32768, 16384, 8192, 4096};
    for (int i = 0; i < 5; ++i) {
        if (fixedBytes + (size_t)cands[i] * 1536 <= ws_size) { CH = cands[i]; break; }
    }
    const int NC = (int)(M / CH);

    split_w<<<dim3(6, 4), 256, 0, stream>>>(W1, W1i, 768);
    split_w<<<dim3(6, 4), 256, 0, stream>>>(W2, W2i, 768);
    split_w<<<dim3(6, 4), 256, 0, stream>>>(W3, W3i, 768);
    split_w<<<dim3(2, 4), 256, 0, stream>>>(Wp, Wpi, 256);

    transpose_in<<<dim3(8, 2, 1024), dim3(32, 8), 0, stream>>>(x, Xa);

    // stage 1: time attention (L=256)
    for (int c = 0; c < NC; ++c) {
        gemm_bf16x3<<<(CH / 128) * 6, 256, 0, stream>>>(
            Xa + (size_t)c * CH * 1024, W1i, qkvB, 768);
        attn_mfma<1><<<8 * (CH / 256), 256, 0, stream>>>(qkvB, Xb, c * (CH / 256));
    }
    // stage 2: freq attention (L=64)
    for (int c = 0; c < NC; ++c) {
        gemm_bf16x3<<<(CH / 128) * 6, 256, 0, stream>>>(
            Xb + (size_t)c * CH * 1024, W2i, qkvB, 768);
        attn_mfma<2><<<4 * (CH / 64), 256, 0, stream>>>(qkvB, Xa, c * (CH / 64));
    }
    // stage 3: windowed attention (L=64)
    for (int c = 0; c < NC; ++c) {
        gemm_bf16x3<<<(CH / 128) * 6, 256, 0, stream>>>(
            Xa + (size_t)c * CH * 1024, W3i, qkvB, 768);
        attn_mfma<3><<<4 * (CH / 64), 256, 0, stream>>>(qkvB, Xb, c * (CH / 64));
    }
    // fused c_proj + output scatter
    for (int c = 0; c < NC; ++c) {
        gemm_cproj<<<(CH / 128) * 2, 256, 0, stream>>>(
            Xb + (size_t)c * CH * 1024, Wpi, out, c * CH);
    }
}

// Round 11
// 362.770 us; speedup vs baseline: 6.2591x; 1.2136x over previous
//
#include <hip/hip_runtime.h>
#include <math.h>

#define B_  4
#define D_  256
#define T_  256
#define F_  64
#define H_  8

#define LN10000 9.210340371976184f
#define SM_SCALE 0.17677669529663687f   // 1/sqrt(32)

typedef float f32x4  __attribute__((ext_vector_type(4)));
typedef float f32x16 __attribute__((ext_vector_type(16)));
typedef short s16x8  __attribute__((ext_vector_type(8)));

// ---------------------------------------------------------------- bf16 helpers
__device__ __forceinline__ unsigned short f2bf(float x) {
    unsigned u = __float_as_uint(x);
    return (unsigned short)((u + 0x7fffu + ((u >> 16) & 1u)) >> 16);
}
__device__ __forceinline__ float bf2f(unsigned short h) {
    return __uint_as_float(((unsigned)h) << 16);
}
__device__ __forceinline__ int cvt_pk_bf16(float a, float b) {
    int r;
    asm("v_cvt_pk_bf16_f32 %0, %1, %2" : "=v"(r) : "v"(a), "v"(b));
    return r;   // lo16 = bf16(a), hi16 = bf16(b)
}

// XCD-aware bijective remap of a 1D block id (nwg % 8 == 0)
__device__ __forceinline__ int xcd_swz(int lin, int nwg) {
    return (lin & 7) * (nwg >> 3) + (lin >> 3);
}

#define GLOAD_LDS(g, l)                                                         \
    __builtin_amdgcn_global_load_lds(                                           \
        (const __attribute__((address_space(1))) void*)(g),                     \
        (__attribute__((address_space(3))) void*)(l), 16, 0, 0)

// ---------------------------------------------------------------- RoPE helper
__device__ __forceinline__ float2 rope_pair(float x0, float x1, int pairIdx, float pos) {
    float freq = __expf(-(float)(2 * pairIdx) * (LN10000 / 32.0f));
    float ang = pos * freq;
    float s, c;
    __sincosf(ang, &s, &c);
    return make_float2(x0 * c - x1 * s, x1 * c + x0 * s);
}

// ---------------------------------------------------------------- weight split (128-col blocks)
__global__ __launch_bounds__(256) void split_w(const float* __restrict__ W,
                                               char* __restrict__ img, int N) {
    __shared__ float Wt[64][132];
    const int nb = blockIdx.x, ks = blockIdx.y;
    const int tid = threadIdx.x;
#pragma unroll
    for (int j = 0; j < 8; ++j) {
        int idx = j * 1024 + tid * 4;
        int r = idx >> 7, cidx = idx & 127;
        const float4 v = *reinterpret_cast<const float4*>(
            &W[(size_t)(ks * 64 + r) * N + nb * 128 + cidx]);
        Wt[r][cidx] = v.x; Wt[r][cidx + 1] = v.y;
        Wt[r][cidx + 2] = v.z; Wt[r][cidx + 3] = v.w;
    }
    __syncthreads();
    char* base = img + ((size_t)(nb * 4 + ks)) * 32768;
#pragma unroll
    for (int i = 0; i < 4; ++i) {
        int p = i * 256 + tid;
        int n = p >> 3, seg = p & 7;
        s16x8 hi, lo;
#pragma unroll
        for (int e = 0; e < 8; ++e) {
            float v = Wt[seg * 8 + e][n];
            unsigned short hb = f2bf(v);
            hi[e] = (short)hb;
            lo[e] = (short)f2bf(v - bf2f(hb));
        }
        int off = n * 128 + ((seg * 16) ^ ((n & 7) << 4));
        *(s16x8*)(base + off) = hi;
        *(s16x8*)(base + 16384 + off) = lo;
    }
}

// ---------------------------------------------------------------- input transpose (hi image only)
__global__ __launch_bounds__(256) void transpose_in(const float* __restrict__ x,
                                                    char* __restrict__ Ximg) {
    __shared__ float tile[32][33];
    const int bt = blockIdx.z, b = bt >> 8, t = bt & 255;
    const int d0 = blockIdx.x * 32, f0 = blockIdx.y * 32;
    const int tx = threadIdx.x, ty = threadIdx.y;   // (32, 8)
    const size_t xbase = (size_t)b * D_ * T_ * F_ + (size_t)t * F_;
#pragma unroll
    for (int j = 0; j < 4; ++j) {
        int d = d0 + ty + j * 8;
        tile[ty + j * 8][tx] = x[xbase + (size_t)d * T_ * F_ + f0 + tx];
    }
    __syncthreads();
    const int tok = (b * 64 + f0 + tx) * 256 + t;
    const int rloc = tok & 127;
    const int hl = ty >> 2, seg = ty & 3;
    if (hl) return;   // lo image unread by x2 GEMM — skip
    char* base = Ximg + ((size_t)((tok >> 7) * 4 + (d0 >> 6))) * 32768;
    const int off = rloc * 128 + ((((d0 & 32) << 1) + seg * 16) ^ ((rloc & 7) << 4));
    s16x8 v;
#pragma unroll
    for (int e = 0; e < 8; ++e) v[e] = (short)f2bf(tile[seg * 8 + e][tx]);
    *(s16x8*)(base + off) = v;
}

// ---------------------------------------------------------------- x2 GEMM (qkv): bf16(A) @ (Wh+Wl)
// LDS 48KB: A-hi 16KB | Bh 16KB | Bl 16KB -> 3 blocks/CU.
__global__ __launch_bounds__(256) void gemm_x2(const char* __restrict__ Aimg,
                                               const char* __restrict__ Bimg,
                                               unsigned short* __restrict__ C, int N) {
    __shared__ alignas(16) char lds[49152];
    const int tid = threadIdx.x, lane = tid & 63, wave = tid >> 6;
    const int wm = wave >> 1, wn = wave & 1;
    const int rlo = lane & 15, rg = lane >> 4;
    const int wg = xcd_swz(blockIdx.x, gridDim.x);
    const int ncol = N >> 7;
    const int brow = wg / ncol, bcol = wg % ncol;
    f32x4 acc[4][4] = {};
    for (int ks = 0; ks < 4; ++ks) {
        const char* ga = Aimg + ((size_t)(brow * 4 + ks)) * 32768 + wave * 4096 + lane * 16;
        const char* gb = Bimg + ((size_t)(bcol * 4 + ks)) * 32768 + wave * 8192 + lane * 16;
#pragma unroll
        for (int i = 0; i < 4; ++i)
            GLOAD_LDS(ga + i * 1024, lds + wave * 4096 + lane * 16 + i * 1024);
#pragma unroll
        for (int i = 0; i < 8; ++i)
            GLOAD_LDS(gb + i * 1024, lds + 16384 + wave * 8192 + lane * 16 + i * 1024);
        __syncthreads();
#pragma unroll
        for (int kk = 0; kk < 2; ++kk) {
            s16x8 ah[4], bh[4], bl[4];
#pragma unroll
            for (int i = 0; i < 4; ++i) {
                const int ra = wm * 64 + i * 16 + rlo;
                const int ka = (kk * 64 + rg * 16) ^ ((ra & 7) << 4);
                ah[i] = *(const s16x8*)(lds + ra * 128 + ka);
                const int rb = wn * 64 + i * 16 + rlo;
                const int kb = (kk * 64 + rg * 16) ^ ((rb & 7) << 4);
                bh[i] = *(const s16x8*)(lds + 16384 + rb * 128 + kb);
                bl[i] = *(const s16x8*)(lds + 32768 + rb * 128 + kb);
            }
#pragma unroll
            for (int mt = 0; mt < 4; ++mt)
#pragma unroll
                for (int nt = 0; nt < 4; ++nt) {
                    acc[mt][nt] = __builtin_amdgcn_mfma_f32_16x16x32_bf16(ah[mt], bh[nt], acc[mt][nt], 0, 0, 0);
                    acc[mt][nt] = __builtin_amdgcn_mfma_f32_16x16x32_bf16(ah[mt], bl[nt], acc[mt][nt], 0, 0, 0);
                }
        }
        __syncthreads();
    }
    const int row0 = brow * 128 + wm * 64, col0 = bcol * 128 + wn * 64;
#pragma unroll
    for (int mt = 0; mt < 4; ++mt)
#pragma unroll
        for (int nt = 0; nt < 4; ++nt)
#pragma unroll
            for (int r = 0; r < 4; ++r)
                C[(size_t)(row0 + mt * 16 + rg * 4 + r) * N + col0 + nt * 16 + rlo] =
                    f2bf(acc[mt][nt][r]);
}

// ---------------------------------------------------------------- fused c_proj GEMM (x3) + (b,d,t,f) scatter
__global__ __launch_bounds__(256) void gemm_cproj(const char* __restrict__ Aimg,
                                                  const char* __restrict__ Bimg,
                                                  float* __restrict__ out, int tok0) {
    __shared__ alignas(16) char lds[65536];
    const int tid = threadIdx.x, lane = tid & 63, wave = tid >> 6;
    const int wm = wave >> 1, wn = wave & 1;
    const int rlo = lane & 15, rg = lane >> 4;
    const int wg = xcd_swz(blockIdx.x, gridDim.x);
    const int brow = wg >> 1, bcol = wg & 1;
    f32x4 acc[4][4] = {};
    for (int ks = 0; ks < 4; ++ks) {
        const char* ga = Aimg + ((size_t)(brow * 4 + ks)) * 32768 + wave * 8192 + lane * 16;
        const char* gb = Bimg + ((size_t)(bcol * 4 + ks)) * 32768 + wave * 8192 + lane * 16;
        char* la = lds + wave * 8192;
        char* lb = lds + 32768 + wave * 8192;
#pragma unroll
        for (int i = 0; i < 8; ++i) {
            GLOAD_LDS(ga + i * 1024, la + lane * 16 + i * 1024);
            GLOAD_LDS(gb + i * 1024, lb + lane * 16 + i * 1024);
        }
        __syncthreads();
#pragma unroll
        for (int kk = 0; kk < 2; ++kk) {
            s16x8 ah[4], al[4], bh[4], bl[4];
#pragma unroll
            for (int i = 0; i < 4; ++i) {
                const int ra = wm * 64 + i * 16 + rlo;
                const int ka = (kk * 64 + rg * 16) ^ ((ra & 7) << 4);
                ah[i] = *(const s16x8*)(lds + ra * 128 + ka);
                al[i] = *(const s16x8*)(lds + 16384 + ra * 128 + ka);
                const int rb = wn * 64 + i * 16 + rlo;
                const int kb = (kk * 64 + rg * 16) ^ ((rb & 7) << 4);
                bh[i] = *(const s16x8*)(lds + 32768 + rb * 128 + kb);
                bl[i] = *(const s16x8*)(lds + 49152 + rb * 128 + kb);
            }
#pragma unroll
            for (int mt = 0; mt < 4; ++mt)
#pragma unroll
                for (int nt = 0; nt < 4; ++nt) {
                    acc[mt][nt] = __builtin_amdgcn_mfma_f32_16x16x32_bf16(ah[mt], bh[nt], acc[mt][nt], 0, 0, 0);
                    acc[mt][nt] = __builtin_amdgcn_mfma_f32_16x16x32_bf16(ah[mt], bl[nt], acc[mt][nt], 0, 0, 0);
                    acc[mt][nt] = __builtin_amdgcn_mfma_f32_16x16x32_bf16(al[mt], bh[nt], acc[mt][nt], 0, 0, 0);
                }
        }
        __syncthreads();
    }
    float* ct = (float*)lds;
#pragma unroll
    for (int mt = 0; mt < 4; ++mt)
#pragma unroll
        for (int nt = 0; nt < 4; ++nt)
#pragma unroll
            for (int r = 0; r < 4; ++r) {
                const int tok = wm * 64 + mt * 16 + rg * 4 + r;
                const int d   = wn * 64 + nt * 16 + rlo;
                ct[d * 128 + (tok ^ ((d & 7) << 2))] = acc[mt][nt][r];
            }
    __syncthreads();
    const int tokb = tok0 + brow * 128;
    const int bidx = tokb >> 14;
    const int t0 = (tokb >> 6) & 255;
    const int dcol0 = bcol * 128;
#pragma unroll
    for (int it = 0; it < 16; ++it) {
        const int seg = it * 16 + (tid >> 4);
        const int dd = seg >> 1, tt = seg & 1;
        const int f0 = (tid & 15) * 4;
        const float4 v = *(const float4*)&ct[dd * 128 + ((tt * 64 + f0) ^ ((dd & 7) << 2))];
        *(float4*)&out[((size_t)((bidx * 256 + dcol0 + dd) * 256 + t0 + tt)) * 64 + f0] = v;
    }
}

// ---------------------------------------------------------------- MFMA attention (32x32, swapped ops) — round-9 validated
// WLO: write the lo residual image (needed only when consumer is x3 = cproj).
template <int STAGE, bool WLO>
__global__ __launch_bounds__(256) void attn_mfma(const unsigned short* __restrict__ qkv,
                                                 char* __restrict__ Ximg, int s0) {
    constexpr int L   = (STAGE == 1) ? 256 : 64;
    constexpr int HPB = (STAGE == 1) ? 1 : 2;
    constexpr int GX  = (STAGE == 1) ? 8 : 4;
    constexpr int NCH = L / 32;
    constexpr int KVB = L * 64;
    __shared__ alignas(16) char kvLds[HPB * 2 * KVB];
    __shared__ int   PLds[4][16][32];
    __shared__ alignas(16) float Osc[4][32][36];
    const int tid = threadIdx.x, lane = tid & 63, wave = tid >> 6;
    const int hiSel = lane >> 5;
    const int qloc = lane & 31;
    const int wg = xcd_swz(blockIdx.x, gridDim.x);
    const int hx = wg & (GX - 1);
    const int sl = wg / GX;

    // ---- stage K (roped, A-frag order) and V (V^T A-frag order) ----
    {
        const int nIter = (STAGE == 1) ? 2 : 1;
#pragma unroll
        for (int it = 0; it < nIter; ++it) {
            int idx, headl;
            if (STAGE == 1) { idx = it * 256 + tid; headl = 0; }
            else            { idx = tid & 127;      headl = tid >> 7; }
            const int k = idx >> 1, dh = idx & 1;
            const int h = hx * HPB + headl;
            const size_t grow = ((size_t)(sl * L + k)) * 768 + h * 32 + dh * 16;
            const s16x8 kr0 = *(const s16x8*)&qkv[grow + 256];
            const s16x8 kr1 = *(const s16x8*)&qkv[grow + 264];
            const s16x8 vr0 = *(const s16x8*)&qkv[grow + 512];
            const s16x8 vr1 = *(const s16x8*)&qkv[grow + 520];
            float kvv[16];
#pragma unroll
            for (int e = 0; e < 8; ++e) {
                kvv[e]     = bf2f((unsigned short)kr0[e]);
                kvv[8 + e] = bf2f((unsigned short)kr1[e]);
            }
#pragma unroll
            for (int j = 0; j < 8; ++j) {
                float2 r = rope_pair(kvv[2 * j], kvv[2 * j + 1], dh * 8 + j, (float)k);
                kvv[2 * j] = r.x; kvv[2 * j + 1] = r.y;
            }
            char* kf = kvLds + headl * 2 * KVB;
            s16x8 wlo, whi;
#pragma unroll
            for (int e = 0; e < 8; ++e) {
                wlo[e] = (short)f2bf(kvv[e]);
                whi[e] = (short)f2bf(kvv[8 + e]);
            }
            *(s16x8*)(kf + (((k >> 5) * 2 + dh) * 64 + (k & 31)) * 16) = wlo;
            *(s16x8*)(kf + (((k >> 5) * 2 + dh) * 64 + 32 + (k & 31)) * 16) = whi;
            char* vf = kf + KVB;
            const int kb = k >> 4, hi8 = (k >> 3) & 1, eo = (k & 7) * 2;
#pragma unroll
            for (int dp = 0; dp < 16; ++dp) {
                const unsigned short vv = (unsigned short)((dp < 8) ? vr0[dp] : vr1[dp - 8]);
                *(unsigned short*)(vf + (kb * 64 + dh * 16 + dp + 32 * hi8) * 16 + eo) = vv;
            }
        }
    }
    __syncthreads();

    // ---- compute ----
    const int headl = (STAGE == 1) ? 0 : (wave >> 1);
    const int h = hx * HPB + headl;
    const char* Kf = kvLds + headl * 2 * KVB;
    const char* Vf = Kf + KVB;
    const int nPass = (STAGE == 1) ? 2 : 1;

    for (int pass = 0; pass < nPass; ++pass) {
        const int qt = (STAGE == 1) ? (wave + pass * 4) : (wave & 1);
        const int q = qt * 32 + qloc;
        s16x8 qf0, qf1;
        {
            const size_t qrow = ((size_t)(sl * L + q)) * 768 + h * 32;
            const s16x8 qr0 = *(const s16x8*)&qkv[qrow + hiSel * 8];
            const s16x8 qr1 = *(const s16x8*)&qkv[qrow + 16 + hiSel * 8];
#pragma unroll
            for (int j = 0; j < 4; ++j) {
                float2 r0 = rope_pair(bf2f((unsigned short)qr0[2 * j]),
                                      bf2f((unsigned short)qr0[2 * j + 1]),
                                      hiSel * 4 + j, (float)q);
                qf0[2 * j]     = (short)f2bf(r0.x * SM_SCALE);
                qf0[2 * j + 1] = (short)f2bf(r0.y * SM_SCALE);
                float2 r1 = rope_pair(bf2f((unsigned short)qr1[2 * j]),
                                      bf2f((unsigned short)qr1[2 * j + 1]),
                                      8 + hiSel * 4 + j, (float)q);
                qf1[2 * j]     = (short)f2bf(r1.x * SM_SCALE);
                qf1[2 * j + 1] = (short)f2bf(r1.y * SM_SCALE);
            }
        }
        f32x16 o = (f32x16)0.0f;
        float m = -INFINITY, lsum = 0.f;
#pragma unroll
        for (int c = 0; c < NCH; ++c) {
            const s16x8 ka = *(const s16x8*)(Kf + (c * 2 + 0) * 1024 + lane * 16);
            const s16x8 kb = *(const s16x8*)(Kf + (c * 2 + 1) * 1024 + lane * 16);
            f32x16 S = (f32x16)0.0f;
            S = __builtin_amdgcn_mfma_f32_32x32x16_bf16(ka, qf0, S, 0, 0, 0);
            S = __builtin_amdgcn_mfma_f32_32x32x16_bf16(kb, qf1, S, 0, 0, 0);
            float cmax = S[0];
#pragma unroll
            for (int r = 1; r < 16; ++r) cmax = fmaxf(cmax, S[r]);
            cmax = fmaxf(cmax, __shfl_xor(cmax, 32, 64));
            if (__any(cmax > m + 8.0f)) {        // defer-max (THR=8)
                const float mnew = fmaxf(m, cmax);
                const float corr = __expf(m - mnew);
                m = mnew;
                lsum *= corr;
#pragma unroll
                for (int r = 0; r < 16; ++r) o[r] *= corr;
            }
            float p[16], ssum = 0.f;
#pragma unroll
            for (int r = 0; r < 16; ++r) { p[r] = __expf(S[r] - m); ssum += p[r]; }
            lsum += ssum;
#pragma unroll
            for (int j = 0; j < 8; ++j)
                PLds[wave][(j & 1) + 4 * (j >> 1) + 2 * hiSel][qloc] =
                    cvt_pk_bf16(p[2 * j], p[2 * j + 1]);
            union { int u[4]; s16x8 v; } P0, P1;
#pragma unroll
            for (int i = 0; i < 4; ++i) {
                P0.u[i] = PLds[wave][hiSel * 4 + i][qloc];
                P1.u[i] = PLds[wave][8 + hiSel * 4 + i][qloc];
            }
            const s16x8 va = *(const s16x8*)(Vf + (c * 2 + 0) * 1024 + lane * 16);
            const s16x8 vb = *(const s16x8*)(Vf + (c * 2 + 1) * 1024 + lane * 16);
            o = __builtin_amdgcn_mfma_f32_32x32x16_bf16(va, P0.v, o, 0, 0, 0);
            o = __builtin_amdgcn_mfma_f32_32x32x16_bf16(vb, P1.v, o, 0, 0, 0);
        }
        lsum += __shfl_xor(lsum, 32, 64);
        const float inv = 1.0f / lsum;
#pragma unroll
        for (int r = 0; r < 16; ++r)
            Osc[wave][qloc][(r & 3) + 8 * (r >> 2) + 4 * hiSel] = o[r] * inv;
        int tok;
        if constexpr (STAGE == 1) {
            const int s = s0 + sl, b = s >> 6, f = s & 63;
            tok = (b * 256 + q) * 64 + f;
        } else if constexpr (STAGE == 2) {
            const int s2 = s0 + sl, b = s2 >> 8, t = s2 & 255;
            tok = ((b * 32 + (t >> 3)) * 8 + (q >> 3)) * 64 + (t & 7) * 8 + (q & 7);
        } else {
            const int w = s0 + sl, b = w >> 8, tb = (w >> 3) & 31, fb = w & 7;
            tok = (b * 256 + tb * 8 + (q >> 3)) * 64 + fb * 8 + (q & 7);
        }
        const int rloc = tok & 127;
        char* base = Ximg + ((size_t)((tok >> 7) * 4 + (h >> 1))) * 32768;
        const int sw = (rloc & 7) << 4;
        const int hb64 = (h & 1) * 64;
#pragma unroll
        for (int gg = 0; gg < 2; ++gg) {
            const int g = hiSel * 2 + gg;
            float v8[8];
            *(float4*)&v8[0] = *(const float4*)&Osc[wave][qloc][g * 8];
            *(float4*)&v8[4] = *(const float4*)&Osc[wave][qloc][g * 8 + 4];
            const int off = rloc * 128 + ((hb64 + g * 16) ^ sw);
            s16x8 hi;
#pragma unroll
            for (int e = 0; e < 8; ++e) hi[e] = (short)f2bf(v8[e]);
            *(s16x8*)(base + off) = hi;
            if constexpr (WLO) {
                s16x8 lo;
#pragma unroll
                for (int e = 0; e < 8; ++e)
                    lo[e] = (short)f2bf(v8[e] - bf2f((unsigned short)hi[e]));
                *(s16x8*)(base + 16384 + off) = lo;
            }
        }
    }
}

// ---------------------------------------------------------------- launch
extern "C" void kernel_launch(void* const* d_in, const int* in_sizes, int n_in,
                              void* d_out, int out_size, void* d_ws, size_t ws_size,
                              hipStream_t stream) {
    const float* x  = (const float*)d_in[0];
    const float* W1 = (const float*)d_in[1];
    const float* W2 = (const float*)d_in[2];
    const float* W3 = (const float*)d_in[3];
    const float* Wp = (const float*)d_in[4];
    float* out = (float*)d_out;

    const size_t M = (size_t)B_ * T_ * F_;        // 65536 tokens
    char* Xa = (char*)d_out;                      // image buffer A (X1, X3)
    char* Xb = (char*)d_ws;                       // image buffer B (X2, X4)
    char* W1i = (char*)d_ws + M * 1024;           // weight images
    char* W2i = W1i + 786432;
    char* W3i = W2i + 786432;
    char* Wpi = W3i + 786432;
    unsigned short* qkvB = (unsigned short*)(Wpi + 262144);  // bf16 qkv

    const size_t fixedBytes = M * 1024 + 3 * 786432 + 262144;
    int CH = 2048;
    const int cands[5] = {65536, 32768, 16384, 8192, 4096};
    for (int i = 0; i < 5; ++i) {
        if (fixedBytes + (size_t)cands[i] * 1536 <= ws_size) { CH = cands[i]; break; }
    }
    const int NC = (int)(M / CH);

    split_w<<<dim3(6, 4), 256, 0, stream>>>(W1, W1i, 768);
    split_w<<<dim3(6, 4), 256, 0, stream>>>(W2, W2i, 768);
    split_w<<<dim3(6, 4), 256, 0, stream>>>(W3, W3i, 768);
    split_w<<<dim3(2, 4), 256, 0, stream>>>(Wp, Wpi, 256);

    transpose_in<<<dim3(8, 2, 1024), dim3(32, 8), 0, stream>>>(x, Xa);

    // stage 1: time attention (L=256)
    for (int c = 0; c < NC; ++c) {
        gemm_x2<<<(CH / 128) * 6, 256, 0, stream>>>(
            Xa + (size_t)c * CH * 1024, W1i, qkvB, 768);
        attn_mfma<1, false><<<8 * (CH / 256), 256, 0, stream>>>(qkvB, Xb, c * (CH / 256));
    }
    // stage 2: freq attention (L=64)
    for (int c = 0; c < NC; ++c) {
        gemm_x2<<<(CH / 128) * 6, 256, 0, stream>>>(
            Xb + (size_t)c * CH * 1024, W2i, qkvB, 768);
        attn_mfma<2, false><<<4 * (CH / 64), 256, 0, stream>>>(qkvB, Xa, c * (CH / 64));
    }
    // stage 3: windowed attention (L=64) — output feeds x3 cproj, keep lo
    for (int c = 0; c < NC; ++c) {
        gemm_x2<<<(CH / 128) * 6, 256, 0, stream>>>(
            Xa + (size_t)c * CH * 1024, W3i, qkvB, 768);
        attn_mfma<3, true><<<4 * (CH / 64), 256, 0, stream>>>(qkvB, Xb, c * (CH / 64));
    }
    // fused c_proj (x3) + output scatter
    for (int c = 0; c < NC; ++c) {
        gemm_cproj<<<(CH / 128) * 2, 256, 0, stream>>>(
            Xb + (size_t)c * CH * 1024, Wpi, out, c * CH);
    }
}

// Round 12
// 359.470 us; speedup vs baseline: 6.3166x; 1.0092x over previous
//
#include <hip/hip_runtime.h>
#include <math.h>

#define B_  4
#define D_  256
#define T_  256
#define F_  64
#define H_  8

#define LN10000 9.210340371976184f
#define SM_SCALE 0.17677669529663687f   // 1/sqrt(32)
#define LOG2E    1.4426950408889634f

typedef float f32x4  __attribute__((ext_vector_type(4)));
typedef float f32x16 __attribute__((ext_vector_type(16)));
typedef short s16x8  __attribute__((ext_vector_type(8)));

// ---------------------------------------------------------------- bf16 helpers
__device__ __forceinline__ unsigned short f2bf(float x) {
    unsigned u = __float_as_uint(x);
    return (unsigned short)((u + 0x7fffu + ((u >> 16) & 1u)) >> 16);
}
__device__ __forceinline__ float bf2f(unsigned short h) {
    return __uint_as_float(((unsigned)h) << 16);
}
__device__ __forceinline__ int cvt_pk_bf16(float a, float b) {
    int r;
    asm("v_cvt_pk_bf16_f32 %0, %1, %2" : "=v"(r) : "v"(a), "v"(b));
    return r;   // lo16 = bf16(a), hi16 = bf16(b)
}
__device__ __forceinline__ float exp2fast(float x) {   // D = 2^x (v_exp_f32)
    float r;
    asm("v_exp_f32 %0, %1" : "=v"(r) : "v"(x));
    return r;
}

// XCD-aware bijective remap of a 1D block id (nwg % 8 == 0)
__device__ __forceinline__ int xcd_swz(int lin, int nwg) {
    return (lin & 7) * (nwg >> 3) + (lin >> 3);
}

#define GLOAD_LDS(g, l)                                                         \
    __builtin_amdgcn_global_load_lds(                                           \
        (const __attribute__((address_space(1))) void*)(g),                     \
        (__attribute__((address_space(3))) void*)(l), 16, 0, 0)

// ---------------------------------------------------------------- RoPE table
// tab[pos*16 + i] = (cos(pos*freq_i), sin(pos*freq_i)), pos 0..255, i 0..15
__global__ __launch_bounds__(256) void rope_table(float2* __restrict__ tab) {
    const int idx = blockIdx.x * 256 + threadIdx.x;   // 4096 entries
    const int pos = idx >> 4, pr = idx & 15;
    const float freq = __expf(-(float)(2 * pr) * (LN10000 / 32.0f));
    float s, c;
    __sincosf((float)pos * freq, &s, &c);
    tab[idx] = make_float2(c, s);
}

// ---------------------------------------------------------------- weight split (128-col blocks)
__global__ __launch_bounds__(256) void split_w(const float* __restrict__ W,
                                               char* __restrict__ img, int N) {
    __shared__ float Wt[64][132];
    const int nb = blockIdx.x, ks = blockIdx.y;
    const int tid = threadIdx.x;
#pragma unroll
    for (int j = 0; j < 8; ++j) {
        int idx = j * 1024 + tid * 4;
        int r = idx >> 7, cidx = idx & 127;
        const float4 v = *reinterpret_cast<const float4*>(
            &W[(size_t)(ks * 64 + r) * N + nb * 128 + cidx]);
        Wt[r][cidx] = v.x; Wt[r][cidx + 1] = v.y;
        Wt[r][cidx + 2] = v.z; Wt[r][cidx + 3] = v.w;
    }
    __syncthreads();
    char* base = img + ((size_t)(nb * 4 + ks)) * 32768;
#pragma unroll
    for (int i = 0; i < 4; ++i) {
        int p = i * 256 + tid;
        int n = p >> 3, seg = p & 7;
        s16x8 hi, lo;
#pragma unroll
        for (int e = 0; e < 8; ++e) {
            float v = Wt[seg * 8 + e][n];
            unsigned short hb = f2bf(v);
            hi[e] = (short)hb;
            lo[e] = (short)f2bf(v - bf2f(hb));
        }
        int off = n * 128 + ((seg * 16) ^ ((n & 7) << 4));
        *(s16x8*)(base + off) = hi;
        *(s16x8*)(base + 16384 + off) = lo;
    }
}

// ---------------------------------------------------------------- input transpose (hi image only)
__global__ __launch_bounds__(256) void transpose_in(const float* __restrict__ x,
                                                    char* __restrict__ Ximg) {
    __shared__ float tile[32][33];
    const int bt = blockIdx.z, b = bt >> 8, t = bt & 255;
    const int d0 = blockIdx.x * 32, f0 = blockIdx.y * 32;
    const int tx = threadIdx.x, ty = threadIdx.y;   // (32, 8)
    const size_t xbase = (size_t)b * D_ * T_ * F_ + (size_t)t * F_;
#pragma unroll
    for (int j = 0; j < 4; ++j) {
        int d = d0 + ty + j * 8;
        tile[ty + j * 8][tx] = x[xbase + (size_t)d * T_ * F_ + f0 + tx];
    }
    __syncthreads();
    const int tok = (b * 64 + f0 + tx) * 256 + t;
    const int rloc = tok & 127;
    const int hl = ty >> 2, seg = ty & 3;
    if (hl) return;   // lo image unread by x2 GEMM — skip
    char* base = Ximg + ((size_t)((tok >> 7) * 4 + (d0 >> 6))) * 32768;
    const int off = rloc * 128 + ((((d0 & 32) << 1) + seg * 16) ^ ((rloc & 7) << 4));
    s16x8 v;
#pragma unroll
    for (int e = 0; e < 8; ++e) v[e] = (short)f2bf(tile[seg * 8 + e][tx]);
    *(s16x8*)(base + off) = v;
}

// ---------------------------------------------------------------- x2 GEMM (qkv): bf16(A) @ (Wh+Wl)
__global__ __launch_bounds__(256) void gemm_x2(const char* __restrict__ Aimg,
                                               const char* __restrict__ Bimg,
                                               unsigned short* __restrict__ C, int N) {
    __shared__ alignas(16) char lds[49152];
    const int tid = threadIdx.x, lane = tid & 63, wave = tid >> 6;
    const int wm = wave >> 1, wn = wave & 1;
    const int rlo = lane & 15, rg = lane >> 4;
    const int wg = xcd_swz(blockIdx.x, gridDim.x);
    const int ncol = N >> 7;
    const int brow = wg / ncol, bcol = wg % ncol;
    f32x4 acc[4][4] = {};
    for (int ks = 0; ks < 4; ++ks) {
        const char* ga = Aimg + ((size_t)(brow * 4 + ks)) * 32768 + wave * 4096 + lane * 16;
        const char* gb = Bimg + ((size_t)(bcol * 4 + ks)) * 32768 + wave * 8192 + lane * 16;
#pragma unroll
        for (int i = 0; i < 4; ++i)
            GLOAD_LDS(ga + i * 1024, lds + wave * 4096 + lane * 16 + i * 1024);
#pragma unroll
        for (int i = 0; i < 8; ++i)
            GLOAD_LDS(gb + i * 1024, lds + 16384 + wave * 8192 + lane * 16 + i * 1024);
        __syncthreads();
#pragma unroll
        for (int kk = 0; kk < 2; ++kk) {
            s16x8 ah[4], bh[4], bl[4];
#pragma unroll
            for (int i = 0; i < 4; ++i) {
                const int ra = wm * 64 + i * 16 + rlo;
                const int ka = (kk * 64 + rg * 16) ^ ((ra & 7) << 4);
                ah[i] = *(const s16x8*)(lds + ra * 128 + ka);
                const int rb = wn * 64 + i * 16 + rlo;
                const int kb = (kk * 64 + rg * 16) ^ ((rb & 7) << 4);
                bh[i] = *(const s16x8*)(lds + 16384 + rb * 128 + kb);
                bl[i] = *(const s16x8*)(lds + 32768 + rb * 128 + kb);
            }
#pragma unroll
            for (int mt = 0; mt < 4; ++mt)
#pragma unroll
                for (int nt = 0; nt < 4; ++nt) {
                    acc[mt][nt] = __builtin_amdgcn_mfma_f32_16x16x32_bf16(ah[mt], bh[nt], acc[mt][nt], 0, 0, 0);
                    acc[mt][nt] = __builtin_amdgcn_mfma_f32_16x16x32_bf16(ah[mt], bl[nt], acc[mt][nt], 0, 0, 0);
                }
        }
        __syncthreads();
    }
    const int row0 = brow * 128 + wm * 64, col0 = bcol * 128 + wn * 64;
#pragma unroll
    for (int mt = 0; mt < 4; ++mt)
#pragma unroll
        for (int nt = 0; nt < 4; ++nt)
#pragma unroll
            for (int r = 0; r < 4; ++r)
                C[(size_t)(row0 + mt * 16 + rg * 4 + r) * N + col0 + nt * 16 + rlo] =
                    f2bf(acc[mt][nt][r]);
}

// ---------------------------------------------------------------- fused c_proj GEMM (x3) + (b,d,t,f) scatter
__global__ __launch_bounds__(256) void gemm_cproj(const char* __restrict__ Aimg,
                                                  const char* __restrict__ Bimg,
                                                  float* __restrict__ out, int tok0) {
    __shared__ alignas(16) char lds[65536];
    const int tid = threadIdx.x, lane = tid & 63, wave = tid >> 6;
    const int wm = wave >> 1, wn = wave & 1;
    const int rlo = lane & 15, rg = lane >> 4;
    const int wg = xcd_swz(blockIdx.x, gridDim.x);
    const int brow = wg >> 1, bcol = wg & 1;
    f32x4 acc[4][4] = {};
    for (int ks = 0; ks < 4; ++ks) {
        const char* ga = Aimg + ((size_t)(brow * 4 + ks)) * 32768 + wave * 8192 + lane * 16;
        const char* gb = Bimg + ((size_t)(bcol * 4 + ks)) * 32768 + wave * 8192 + lane * 16;
        char* la = lds + wave * 8192;
        char* lb = lds + 32768 + wave * 8192;
#pragma unroll
        for (int i = 0; i < 8; ++i) {
            GLOAD_LDS(ga + i * 1024, la + lane * 16 + i * 1024);
            GLOAD_LDS(gb + i * 1024, lb + lane * 16 + i * 1024);
        }
        __syncthreads();
#pragma unroll
        for (int kk = 0; kk < 2; ++kk) {
            s16x8 ah[4], al[4], bh[4], bl[4];
#pragma unroll
            for (int i = 0; i < 4; ++i) {
                const int ra = wm * 64 + i * 16 + rlo;
                const int ka = (kk * 64 + rg * 16) ^ ((ra & 7) << 4);
                ah[i] = *(const s16x8*)(lds + ra * 128 + ka);
                al[i] = *(const s16x8*)(lds + 16384 + ra * 128 + ka);
                const int rb = wn * 64 + i * 16 + rlo;
                const int kb = (kk * 64 + rg * 16) ^ ((rb & 7) << 4);
                bh[i] = *(const s16x8*)(lds + 32768 + rb * 128 + kb);
                bl[i] = *(const s16x8*)(lds + 49152 + rb * 128 + kb);
            }
#pragma unroll
            for (int mt = 0; mt < 4; ++mt)
#pragma unroll
                for (int nt = 0; nt < 4; ++nt) {
                    acc[mt][nt] = __builtin_amdgcn_mfma_f32_16x16x32_bf16(ah[mt], bh[nt], acc[mt][nt], 0, 0, 0);
                    acc[mt][nt] = __builtin_amdgcn_mfma_f32_16x16x32_bf16(ah[mt], bl[nt], acc[mt][nt], 0, 0, 0);
                    acc[mt][nt] = __builtin_amdgcn_mfma_f32_16x16x32_bf16(al[mt], bh[nt], acc[mt][nt], 0, 0, 0);
                }
        }
        __syncthreads();
    }
    float* ct = (float*)lds;
#pragma unroll
    for (int mt = 0; mt < 4; ++mt)
#pragma unroll
        for (int nt = 0; nt < 4; ++nt)
#pragma unroll
            for (int r = 0; r < 4; ++r) {
                const int tok = wm * 64 + mt * 16 + rg * 4 + r;
                const int d   = wn * 64 + nt * 16 + rlo;
                ct[d * 128 + (tok ^ ((d & 7) << 2))] = acc[mt][nt][r];
            }
    __syncthreads();
    const int tokb = tok0 + brow * 128;
    const int bidx = tokb >> 14;
    const int t0 = (tokb >> 6) & 255;
    const int dcol0 = bcol * 128;
#pragma unroll
    for (int it = 0; it < 16; ++it) {
        const int seg = it * 16 + (tid >> 4);
        const int dd = seg >> 1, tt = seg & 1;
        const int f0 = (tid & 15) * 4;
        const float4 v = *(const float4*)&ct[dd * 128 + ((tt * 64 + f0) ^ ((dd & 7) << 2))];
        *(float4*)&out[((size_t)((bidx * 256 + dcol0 + dd) * 256 + t0 + tt)) * 64 + f0] = v;
    }
}

// ---------------------------------------------------------------- MFMA attention (32x32, swapped ops)
// Round-9/11 validated structure + rope table + exp2 softmax + PL/Osc aliasing.
template <int STAGE, bool WLO>
__global__ __launch_bounds__(256) void attn_mfma(const unsigned short* __restrict__ qkv,
                                                 char* __restrict__ Ximg,
                                                 const float2* __restrict__ ropeT, int s0) {
    constexpr int L   = (STAGE == 1) ? 256 : 64;
    constexpr int HPB = (STAGE == 1) ? 1 : 2;
    constexpr int GX  = (STAGE == 1) ? 8 : 4;
    constexpr int NCH = L / 32;
    constexpr int KVB = L * 64;
    __shared__ alignas(16) char kvLds[HPB * 2 * KVB];
    __shared__ alignas(16) float Osc[4][32][36];   // PL scratch aliases first 2KB/wave
    const int tid = threadIdx.x, lane = tid & 63, wave = tid >> 6;
    const int hiSel = lane >> 5;
    const int qloc = lane & 31;
    const int wg = xcd_swz(blockIdx.x, gridDim.x);
    const int hx = wg & (GX - 1);
    const int sl = wg / GX;
    float* PL = &Osc[wave][0][0];   // [row*32 + qloc], rows 0..15 (2KB < 4.6KB slice)

    // ---- stage K (roped via table, A-frag order) and V (V^T A-frag order) ----
    {
        const int nIter = (STAGE == 1) ? 2 : 1;
#pragma unroll
        for (int it = 0; it < nIter; ++it) {
            int idx, headl;
            if (STAGE == 1) { idx = it * 256 + tid; headl = 0; }
            else            { idx = tid & 127;      headl = tid >> 7; }
            const int k = idx >> 1, dh = idx & 1;
            const int h = hx * HPB + headl;
            const size_t grow = ((size_t)(sl * L + k)) * 768 + h * 32 + dh * 16;
            const s16x8 kr0 = *(const s16x8*)&qkv[grow + 256];
            const s16x8 kr1 = *(const s16x8*)&qkv[grow + 264];
            const s16x8 vr0 = *(const s16x8*)&qkv[grow + 512];
            const s16x8 vr1 = *(const s16x8*)&qkv[grow + 520];
            float kvv[16];
#pragma unroll
            for (int e = 0; e < 8; ++e) {
                kvv[e]     = bf2f((unsigned short)kr0[e]);
                kvv[8 + e] = bf2f((unsigned short)kr1[e]);
            }
#pragma unroll
            for (int j = 0; j < 8; ++j) {
                const float2 cs = ropeT[k * 16 + dh * 8 + j];
                const float x0 = kvv[2 * j], x1 = kvv[2 * j + 1];
                kvv[2 * j]     = x0 * cs.x - x1 * cs.y;
                kvv[2 * j + 1] = x1 * cs.x + x0 * cs.y;
            }
            char* kf = kvLds + headl * 2 * KVB;
            s16x8 wlo, whi;
#pragma unroll
            for (int e = 0; e < 8; ++e) {
                wlo[e] = (short)f2bf(kvv[e]);
                whi[e] = (short)f2bf(kvv[8 + e]);
            }
            *(s16x8*)(kf + (((k >> 5) * 2 + dh) * 64 + (k & 31)) * 16) = wlo;
            *(s16x8*)(kf + (((k >> 5) * 2 + dh) * 64 + 32 + (k & 31)) * 16) = whi;
            char* vf = kf + KVB;
            const int kb = k >> 4, hi8 = (k >> 3) & 1, eo = (k & 7) * 2;
#pragma unroll
            for (int dp = 0; dp < 16; ++dp) {
                const unsigned short vv = (unsigned short)((dp < 8) ? vr0[dp] : vr1[dp - 8]);
                *(unsigned short*)(vf + (kb * 64 + dh * 16 + dp + 32 * hi8) * 16 + eo) = vv;
            }
        }
    }
    __syncthreads();

    // ---- compute (exp2 domain) ----
    const int headl = (STAGE == 1) ? 0 : (wave >> 1);
    const int h = hx * HPB + headl;
    const char* Kf = kvLds + headl * 2 * KVB;
    const char* Vf = Kf + KVB;
    const int nPass = (STAGE == 1) ? 2 : 1;
    const float QS = SM_SCALE * LOG2E;
    const float THR = 8.0f * LOG2E;

    for (int pass = 0; pass < nPass; ++pass) {
        const int qt = (STAGE == 1) ? (wave + pass * 4) : (wave & 1);
        const int q = qt * 32 + qloc;
        s16x8 qf0, qf1;
        {
            const size_t qrow = ((size_t)(sl * L + q)) * 768 + h * 32;
            const s16x8 qr0 = *(const s16x8*)&qkv[qrow + hiSel * 8];
            const s16x8 qr1 = *(const s16x8*)&qkv[qrow + 16 + hiSel * 8];
#pragma unroll
            for (int j = 0; j < 4; ++j) {
                const float2 c0 = ropeT[q * 16 + hiSel * 4 + j];
                const float a0 = bf2f((unsigned short)qr0[2 * j]);
                const float a1 = bf2f((unsigned short)qr0[2 * j + 1]);
                qf0[2 * j]     = (short)f2bf((a0 * c0.x - a1 * c0.y) * QS);
                qf0[2 * j + 1] = (short)f2bf((a1 * c0.x + a0 * c0.y) * QS);
                const float2 c1 = ropeT[q * 16 + 8 + hiSel * 4 + j];
                const float b0 = bf2f((unsigned short)qr1[2 * j]);
                const float b1 = bf2f((unsigned short)qr1[2 * j + 1]);
                qf1[2 * j]     = (short)f2bf((b0 * c1.x - b1 * c1.y) * QS);
                qf1[2 * j + 1] = (short)f2bf((b1 * c1.x + b0 * c1.y) * QS);
            }
        }
        f32x16 o = (f32x16)0.0f;
        float m = -INFINITY, lsum = 0.f;
#pragma unroll
        for (int c = 0; c < NCH; ++c) {
            const s16x8 ka = *(const s16x8*)(Kf + (c * 2 + 0) * 1024 + lane * 16);
            const s16x8 kb = *(const s16x8*)(Kf + (c * 2 + 1) * 1024 + lane * 16);
            f32x16 S = (f32x16)0.0f;
            S = __builtin_amdgcn_mfma_f32_32x32x16_bf16(ka, qf0, S, 0, 0, 0);
            S = __builtin_amdgcn_mfma_f32_32x32x16_bf16(kb, qf1, S, 0, 0, 0);
            float cmax = S[0];
#pragma unroll
            for (int r = 1; r < 16; ++r) cmax = fmaxf(cmax, S[r]);
            cmax = fmaxf(cmax, __shfl_xor(cmax, 32, 64));
            if (__any(cmax > m + THR)) {         // defer-max (e^8 bound)
                const float mnew = fmaxf(m, cmax);
                const float corr = exp2fast(m - mnew);
                m = mnew;
                lsum *= corr;
#pragma unroll
                for (int r = 0; r < 16; ++r) o[r] *= corr;
            }
            float p[16], ssum = 0.f;
#pragma unroll
            for (int r = 0; r < 16; ++r) { p[r] = exp2fast(S[r] - m); ssum += p[r]; }
            lsum += ssum;
#pragma unroll
            for (int j = 0; j < 8; ++j)
                PL[((j & 1) + 4 * (j >> 1) + 2 * hiSel) * 32 + qloc] =
                    __int_as_float(cvt_pk_bf16(p[2 * j], p[2 * j + 1]));
            union { int u[4]; s16x8 v; } P0, P1;
#pragma unroll
            for (int i = 0; i < 4; ++i) {
                P0.u[i] = __float_as_int(PL[(hiSel * 4 + i) * 32 + qloc]);
                P1.u[i] = __float_as_int(PL[(8 + hiSel * 4 + i) * 32 + qloc]);
            }
            const s16x8 va = *(const s16x8*)(Vf + (c * 2 + 0) * 1024 + lane * 16);
            const s16x8 vb = *(const s16x8*)(Vf + (c * 2 + 1) * 1024 + lane * 16);
            o = __builtin_amdgcn_mfma_f32_32x32x16_bf16(va, P0.v, o, 0, 0, 0);
            o = __builtin_amdgcn_mfma_f32_32x32x16_bf16(vb, P1.v, o, 0, 0, 0);
        }
        lsum += __shfl_xor(lsum, 32, 64);
        const float inv = 1.0f / lsum;
#pragma unroll
        for (int r = 0; r < 16; ++r)
            Osc[wave][qloc][(r & 3) + 8 * (r >> 2) + 4 * hiSel] = o[r] * inv;
        int tok;
        if constexpr (STAGE == 1) {
            const int s = s0 + sl, b = s >> 6, f = s & 63;
            tok = (b * 256 + q) * 64 + f;
        } else if constexpr (STAGE == 2) {
            const int s2 = s0 + sl, b = s2 >> 8, t = s2 & 255;
            tok = ((b * 32 + (t >> 3)) * 8 + (q >> 3)) * 64 + (t & 7) * 8 + (q & 7);
        } else {
            const int w = s0 + sl, b = w >> 8, tb = (w >> 3) & 31, fb = w & 7;
            tok = (b * 256 + tb * 8 + (q >> 3)) * 64 + fb * 8 + (q & 7);
        }
        const int rloc = tok & 127;
        char* base = Ximg + ((size_t)((tok >> 7) * 4 + (h >> 1))) * 32768;
        const int sw = (rloc & 7) << 4;
        const int hb64 = (h & 1) * 64;
#pragma unroll
        for (int gg = 0; gg < 2; ++gg) {
            const int g = hiSel * 2 + gg;
            float v8[8];
            *(float4*)&v8[0] = *(const float4*)&Osc[wave][qloc][g * 8];
            *(float4*)&v8[4] = *(const float4*)&Osc[wave][qloc][g * 8 + 4];
            const int off = rloc * 128 + ((hb64 + g * 16) ^ sw);
            s16x8 hi;
#pragma unroll
            for (int e = 0; e < 8; ++e) hi[e] = (short)f2bf(v8[e]);
            *(s16x8*)(base + off) = hi;
            if constexpr (WLO) {
                s16x8 lo;
#pragma unroll
                for (int e = 0; e < 8; ++e)
                    lo[e] = (short)f2bf(v8[e] - bf2f((unsigned short)hi[e]));
                *(s16x8*)(base + 16384 + off) = lo;
            }
        }
    }
}

// ---------------------------------------------------------------- launch
extern "C" void kernel_launch(void* const* d_in, const int* in_sizes, int n_in,
                              void* d_out, int out_size, void* d_ws, size_t ws_size,
                              hipStream_t stream) {
    const float* x  = (const float*)d_in[0];
    const float* W1 = (const float*)d_in[1];
    const float* W2 = (const float*)d_in[2];
    const float* W3 = (const float*)d_in[3];
    const float* Wp = (const float*)d_in[4];
    float* out = (float*)d_out;

    const size_t M = (size_t)B_ * T_ * F_;        // 65536 tokens
    char* Xa = (char*)d_out;                      // image buffer A (X1, X3)
    char* Xb = (char*)d_ws;                       // image buffer B (X2, X4)
    char* W1i = (char*)d_ws + M * 1024;           // weight images
    char* W2i = W1i + 786432;
    char* W3i = W2i + 786432;
    char* Wpi = W3i + 786432;
    float2* ropeT = (float2*)(Wpi + 262144);                 // 32 KB
    unsigned short* qkvB = (unsigned short*)((char*)ropeT + 32768);

    const size_t fixedBytes = M * 1024 + 3 * 786432 + 262144 + 32768;
    int CH = 2048;
    const int cands[5] = {65536, 32768, 16384, 8192, 4096};
    for (int i = 0; i < 5; ++i) {
        if (fixedBytes + (size_t)cands[i] * 1536 <= ws_size) { CH = cands[i]; break; }
    }
    const int NC = (int)(M / CH);

    rope_table<<<16, 256, 0, stream>>>(ropeT);
    split_w<<<dim3(6, 4), 256, 0, stream>>>(W1, W1i, 768);
    split_w<<<dim3(6, 4), 256, 0, stream>>>(W2, W2i, 768);
    split_w<<<dim3(6, 4), 256, 0, stream>>>(W3, W3i, 768);
    split_w<<<dim3(2, 4), 256, 0, stream>>>(Wp, Wpi, 256);

    transpose_in<<<dim3(8, 2, 1024), dim3(32, 8), 0, stream>>>(x, Xa);

    // stage 1: time attention (L=256)
    for (int c = 0; c < NC; ++c) {
        gemm_x2<<<(CH / 128) * 6, 256, 0, stream>>>(
            Xa + (size_t)c * CH * 1024, W1i, qkvB, 768);
        attn_mfma<1, false><<<8 * (CH / 256), 256, 0, stream>>>(
            qkvB, Xb, ropeT, c * (CH / 256));
    }
    // stage 2: freq attention (L=64)
    for (int c = 0; c < NC; ++c) {
        gemm_x2<<<(CH / 128) * 6, 256, 0, stream>>>(
            Xb + (size_t)c * CH * 1024, W2i, qkvB, 768);
        attn_mfma<2, false><<<4 * (CH / 64), 256, 0, stream>>>(
            qkvB, Xa, ropeT, c * (CH / 64));
    }
    // stage 3: windowed attention (L=64) — output feeds x3 cproj, keep lo
    for (int c = 0; c < NC; ++c) {
        gemm_x2<<<(CH / 128) * 6, 256, 0, stream>>>(
            Xa + (size_t)c * CH * 1024, W3i, qkvB, 768);
        attn_mfma<3, true><<<4 * (CH / 64), 256, 0, stream>>>(
            qkvB, Xb, ropeT, c * (CH / 64));
    }
    // fused c_proj (x3) + output scatter
    for (int c = 0; c < NC; ++c) {
        gemm_cproj<<<(CH / 128) * 2, 256, 0, stream>>>(
            Xb + (size_t)c * CH * 1024, Wpi, out, c * CH);
    }
}

// Round 13
// 355.961 us; speedup vs baseline: 6.3788x; 1.0099x over previous
//
#include <hip/hip_runtime.h>
#include <math.h>

#define B_  4
#define D_  256
#define T_  256
#define F_  64
#define H_  8

#define LN10000 9.210340371976184f
#define SM_SCALE 0.17677669529663687f   // 1/sqrt(32)
#define LOG2E    1.4426950408889634f

typedef float f32x4  __attribute__((ext_vector_type(4)));
typedef float f32x16 __attribute__((ext_vector_type(16)));
typedef short s16x8  __attribute__((ext_vector_type(8)));

// ---------------------------------------------------------------- bf16 helpers
__device__ __forceinline__ unsigned short f2bf(float x) {
    unsigned u = __float_as_uint(x);
    return (unsigned short)((u + 0x7fffu + ((u >> 16) & 1u)) >> 16);
}
__device__ __forceinline__ float bf2f(unsigned short h) {
    return __uint_as_float(((unsigned)h) << 16);
}
__device__ __forceinline__ int cvt_pk_bf16(float a, float b) {
    int r;
    asm("v_cvt_pk_bf16_f32 %0, %1, %2" : "=v"(r) : "v"(a), "v"(b));
    return r;   // lo16 = bf16(a), hi16 = bf16(b)
}
__device__ __forceinline__ float exp2fast(float x) {   // D = 2^x (v_exp_f32)
    float r;
    asm("v_exp_f32 %0, %1" : "=v"(r) : "v"(x));
    return r;
}
// pairwise-tree reductions over a 16-vector (depth 4, not a 15-deep chain)
__device__ __forceinline__ float max16(const f32x16& S) {
    float a0 = fmaxf(S[0], S[1]),  a1 = fmaxf(S[2], S[3]);
    float a2 = fmaxf(S[4], S[5]),  a3 = fmaxf(S[6], S[7]);
    float a4 = fmaxf(S[8], S[9]),  a5 = fmaxf(S[10], S[11]);
    float a6 = fmaxf(S[12], S[13]), a7 = fmaxf(S[14], S[15]);
    float b0 = fmaxf(a0, a1), b1 = fmaxf(a2, a3);
    float b2 = fmaxf(a4, a5), b3 = fmaxf(a6, a7);
    return fmaxf(fmaxf(b0, b1), fmaxf(b2, b3));
}
__device__ __forceinline__ float sum16(const float* p) {
    float a0 = p[0] + p[1],  a1 = p[2] + p[3];
    float a2 = p[4] + p[5],  a3 = p[6] + p[7];
    float a4 = p[8] + p[9],  a5 = p[10] + p[11];
    float a6 = p[12] + p[13], a7 = p[14] + p[15];
    float b0 = a0 + a1, b1 = a2 + a3, b2 = a4 + a5, b3 = a6 + a7;
    return (b0 + b1) + (b2 + b3);
}

// XCD-aware bijective remap of a 1D block id (nwg % 8 == 0)
__device__ __forceinline__ int xcd_swz(int lin, int nwg) {
    return (lin & 7) * (nwg >> 3) + (lin >> 3);
}

#define GLOAD_LDS(g, l)                                                         \
    __builtin_amdgcn_global_load_lds(                                           \
        (const __attribute__((address_space(1))) void*)(g),                     \
        (__attribute__((address_space(3))) void*)(l), 16, 0, 0)

// ---------------------------------------------------------------- RoPE table
__global__ __launch_bounds__(256) void rope_table(float2* __restrict__ tab) {
    const int idx = blockIdx.x * 256 + threadIdx.x;   // 4096 entries
    const int pos = idx >> 4, pr = idx & 15;
    const float freq = __expf(-(float)(2 * pr) * (LN10000 / 32.0f));
    float s, c;
    __sincosf((float)pos * freq, &s, &c);
    tab[idx] = make_float2(c, s);
}

// ---------------------------------------------------------------- weight split (128-col blocks)
__global__ __launch_bounds__(256) void split_w(const float* __restrict__ W,
                                               char* __restrict__ img, int N) {
    __shared__ float Wt[64][132];
    const int nb = blockIdx.x, ks = blockIdx.y;
    const int tid = threadIdx.x;
#pragma unroll
    for (int j = 0; j < 8; ++j) {
        int idx = j * 1024 + tid * 4;
        int r = idx >> 7, cidx = idx & 127;
        const float4 v = *reinterpret_cast<const float4*>(
            &W[(size_t)(ks * 64 + r) * N + nb * 128 + cidx]);
        Wt[r][cidx] = v.x; Wt[r][cidx + 1] = v.y;
        Wt[r][cidx + 2] = v.z; Wt[r][cidx + 3] = v.w;
    }
    __syncthreads();
    char* base = img + ((size_t)(nb * 4 + ks)) * 32768;
#pragma unroll
    for (int i = 0; i < 4; ++i) {
        int p = i * 256 + tid;
        int n = p >> 3, seg = p & 7;
        s16x8 hi, lo;
#pragma unroll
        for (int e = 0; e < 8; ++e) {
            float v = Wt[seg * 8 + e][n];
            unsigned short hb = f2bf(v);
            hi[e] = (short)hb;
            lo[e] = (short)f2bf(v - bf2f(hb));
        }
        int off = n * 128 + ((seg * 16) ^ ((n & 7) << 4));
        *(s16x8*)(base + off) = hi;
        *(s16x8*)(base + 16384 + off) = lo;
    }
}

// ---------------------------------------------------------------- input transpose (hi image only)
__global__ __launch_bounds__(256) void transpose_in(const float* __restrict__ x,
                                                    char* __restrict__ Ximg) {
    __shared__ float tile[32][33];
    const int bt = blockIdx.z, b = bt >> 8, t = bt & 255;
    const int d0 = blockIdx.x * 32, f0 = blockIdx.y * 32;
    const int tx = threadIdx.x, ty = threadIdx.y;   // (32, 8)
    const size_t xbase = (size_t)b * D_ * T_ * F_ + (size_t)t * F_;
#pragma unroll
    for (int j = 0; j < 4; ++j) {
        int d = d0 + ty + j * 8;
        tile[ty + j * 8][tx] = x[xbase + (size_t)d * T_ * F_ + f0 + tx];
    }
    __syncthreads();
    const int tok = (b * 64 + f0 + tx) * 256 + t;
    const int rloc = tok & 127;
    const int hl = ty >> 2, seg = ty & 3;
    if (hl) return;   // lo image unread by x2 GEMM — skip
    char* base = Ximg + ((size_t)((tok >> 7) * 4 + (d0 >> 6))) * 32768;
    const int off = rloc * 128 + ((((d0 & 32) << 1) + seg * 16) ^ ((rloc & 7) << 4));
    s16x8 v;
#pragma unroll
    for (int e = 0; e < 8; ++e) v[e] = (short)f2bf(tile[seg * 8 + e][tx]);
    *(s16x8*)(base + off) = v;
}

// ---------------------------------------------------------------- x2 GEMM (qkv): bf16(A) @ (Wh+Wl)
// C written head-blocked: qkv[seq][head][{q,k,v}][L][32] bf16, L = 1<<LSH.
template <int LSH>
__global__ __launch_bounds__(256) void gemm_x2(const char* __restrict__ Aimg,
                                               const char* __restrict__ Bimg,
                                               unsigned short* __restrict__ C) {
    __shared__ alignas(16) char lds[49152];
    const int tid = threadIdx.x, lane = tid & 63, wave = tid >> 6;
    const int wm = wave >> 1, wn = wave & 1;
    const int rlo = lane & 15, rg = lane >> 4;
    const int wg = xcd_swz(blockIdx.x, gridDim.x);
    const int brow = wg / 6, bcol = wg % 6;
    f32x4 acc[4][4] = {};
    for (int ks = 0; ks < 4; ++ks) {
        const char* ga = Aimg + ((size_t)(brow * 4 + ks)) * 32768 + wave * 4096 + lane * 16;
        const char* gb = Bimg + ((size_t)(bcol * 4 + ks)) * 32768 + wave * 8192 + lane * 16;
#pragma unroll
        for (int i = 0; i < 4; ++i)
            GLOAD_LDS(ga + i * 1024, lds + wave * 4096 + lane * 16 + i * 1024);
#pragma unroll
        for (int i = 0; i < 8; ++i)
            GLOAD_LDS(gb + i * 1024, lds + 16384 + wave * 8192 + lane * 16 + i * 1024);
        __syncthreads();
#pragma unroll
        for (int kk = 0; kk < 2; ++kk) {
            s16x8 ah[4], bh[4], bl[4];
#pragma unroll
            for (int i = 0; i < 4; ++i) {
                const int ra = wm * 64 + i * 16 + rlo;
                const int ka = (kk * 64 + rg * 16) ^ ((ra & 7) << 4);
                ah[i] = *(const s16x8*)(lds + ra * 128 + ka);
                const int rb = wn * 64 + i * 16 + rlo;
                const int kb = (kk * 64 + rg * 16) ^ ((rb & 7) << 4);
                bh[i] = *(const s16x8*)(lds + 16384 + rb * 128 + kb);
                bl[i] = *(const s16x8*)(lds + 32768 + rb * 128 + kb);
            }
#pragma unroll
            for (int mt = 0; mt < 4; ++mt)
#pragma unroll
                for (int nt = 0; nt < 4; ++nt) {
                    acc[mt][nt] = __builtin_amdgcn_mfma_f32_16x16x32_bf16(ah[mt], bh[nt], acc[mt][nt], 0, 0, 0);
                    acc[mt][nt] = __builtin_amdgcn_mfma_f32_16x16x32_bf16(ah[mt], bl[nt], acc[mt][nt], 0, 0, 0);
                }
        }
        __syncthreads();
    }
    const int row0 = brow * 128 + wm * 64, col0 = bcol * 128 + wn * 64;
#pragma unroll
    for (int nt = 0; nt < 4; ++nt) {
        const int col = col0 + nt * 16 + rlo;
        const int third = col >> 8, head = (col >> 5) & 7, d = col & 31;
        const int sec = head * 3 + third;
#pragma unroll
        for (int mt = 0; mt < 4; ++mt)
#pragma unroll
            for (int r = 0; r < 4; ++r) {
                const int R = row0 + mt * 16 + rg * 4 + r;
                const int seq = R >> LSH, k = R & ((1 << LSH) - 1);
                const size_t off =
                    ((((size_t)(seq * 24 + sec)) << LSH) + k) * 32 + d;
                C[off] = f2bf(acc[mt][nt][r]);
            }
    }
}

// ---------------------------------------------------------------- fused c_proj GEMM (x3) + (b,d,t,f) scatter
__global__ __launch_bounds__(256) void gemm_cproj(const char* __restrict__ Aimg,
                                                  const char* __restrict__ Bimg,
                                                  float* __restrict__ out, int tok0) {
    __shared__ alignas(16) char lds[65536];
    const int tid = threadIdx.x, lane = tid & 63, wave = tid >> 6;
    const int wm = wave >> 1, wn = wave & 1;
    const int rlo = lane & 15, rg = lane >> 4;
    const int wg = xcd_swz(blockIdx.x, gridDim.x);
    const int brow = wg >> 1, bcol = wg & 1;
    f32x4 acc[4][4] = {};
    for (int ks = 0; ks < 4; ++ks) {
        const char* ga = Aimg + ((size_t)(brow * 4 + ks)) * 32768 + wave * 8192 + lane * 16;
        const char* gb = Bimg + ((size_t)(bcol * 4 + ks)) * 32768 + wave * 8192 + lane * 16;
        char* la = lds + wave * 8192;
        char* lb = lds + 32768 + wave * 8192;
#pragma unroll
        for (int i = 0; i < 8; ++i) {
            GLOAD_LDS(ga + i * 1024, la + lane * 16 + i * 1024);
            GLOAD_LDS(gb + i * 1024, lb + lane * 16 + i * 1024);
        }
        __syncthreads();
#pragma unroll
        for (int kk = 0; kk < 2; ++kk) {
            s16x8 ah[4], al[4], bh[4], bl[4];
#pragma unroll
            for (int i = 0; i < 4; ++i) {
                const int ra = wm * 64 + i * 16 + rlo;
                const int ka = (kk * 64 + rg * 16) ^ ((ra & 7) << 4);
                ah[i] = *(const s16x8*)(lds + ra * 128 + ka);
                al[i] = *(const s16x8*)(lds + 16384 + ra * 128 + ka);
                const int rb = wn * 64 + i * 16 + rlo;
                const int kb = (kk * 64 + rg * 16) ^ ((rb & 7) << 4);
                bh[i] = *(const s16x8*)(lds + 32768 + rb * 128 + kb);
                bl[i] = *(const s16x8*)(lds + 49152 + rb * 128 + kb);
            }
#pragma unroll
            for (int mt = 0; mt < 4; ++mt)
#pragma unroll
                for (int nt = 0; nt < 4; ++nt) {
                    acc[mt][nt] = __builtin_amdgcn_mfma_f32_16x16x32_bf16(ah[mt], bh[nt], acc[mt][nt], 0, 0, 0);
                    acc[mt][nt] = __builtin_amdgcn_mfma_f32_16x16x32_bf16(ah[mt], bl[nt], acc[mt][nt], 0, 0, 0);
                    acc[mt][nt] = __builtin_amdgcn_mfma_f32_16x16x32_bf16(al[mt], bh[nt], acc[mt][nt], 0, 0, 0);
                }
        }
        __syncthreads();
    }
    float* ct = (float*)lds;
#pragma unroll
    for (int mt = 0; mt < 4; ++mt)
#pragma unroll
        for (int nt = 0; nt < 4; ++nt)
#pragma unroll
            for (int r = 0; r < 4; ++r) {
                const int tok = wm * 64 + mt * 16 + rg * 4 + r;
                const int d   = wn * 64 + nt * 16 + rlo;
                ct[d * 128 + (tok ^ ((d & 7) << 2))] = acc[mt][nt][r];
            }
    __syncthreads();
    const int tokb = tok0 + brow * 128;
    const int bidx = tokb >> 14;
    const int t0 = (tokb >> 6) & 255;
    const int dcol0 = bcol * 128;
#pragma unroll
    for (int it = 0; it < 16; ++it) {
        const int seg = it * 16 + (tid >> 4);
        const int dd = seg >> 1, tt = seg & 1;
        const int f0 = (tid & 15) * 4;
        const float4 v = *(const float4*)&ct[dd * 128 + ((tt * 64 + f0) ^ ((dd & 7) << 2))];
        *(float4*)&out[((size_t)((bidx * 256 + dcol0 + dd) * 256 + t0 + tt)) * 64 + f0] = v;
    }
}

// ---------------------------------------------------------------- MFMA attention (32x32, swapped ops)
// qkv head-blocked: [seq][head][{q,k,v}][L][32] bf16 — contiguous K/V/Q streams.
template <int STAGE, bool WLO>
__global__ __launch_bounds__(256) void attn_mfma(const unsigned short* __restrict__ qkv,
                                                 char* __restrict__ Ximg,
                                                 const float2* __restrict__ ropeT, int s0) {
    constexpr int L   = (STAGE == 1) ? 256 : 64;
    constexpr int HPB = (STAGE == 1) ? 1 : 2;
    constexpr int GX  = (STAGE == 1) ? 8 : 4;
    constexpr int NCH = L / 32;
    constexpr int KVB = L * 64;
    __shared__ alignas(16) char kvLds[HPB * 2 * KVB];
    __shared__ alignas(16) float Osc[4][32][36];   // PL scratch aliases first 2KB/wave
    const int tid = threadIdx.x, lane = tid & 63, wave = tid >> 6;
    const int hiSel = lane >> 5;
    const int qloc = lane & 31;
    const int wg = xcd_swz(blockIdx.x, gridDim.x);
    const int hx = wg & (GX - 1);
    const int sl = wg / GX;
    float* PL = &Osc[wave][0][0];   // [row*32 + qloc], rows 0..15

    // ---- stage K (roped via table, A-frag order) and V (V^T A-frag order) ----
    {
        const int nIter = (STAGE == 1) ? 2 : 1;
#pragma unroll
        for (int it = 0; it < nIter; ++it) {
            int idx, headl;
            if (STAGE == 1) { idx = it * 256 + tid; headl = 0; }
            else            { idx = tid & 127;      headl = tid >> 7; }
            const int k = idx >> 1, dh = idx & 1;
            const int h = hx * HPB + headl;
            const size_t secBase = (((size_t)(sl * 8 + h) * 3) << ((STAGE == 1) ? 8 : 6)) * 32;
            const s16x8 kr0 = *(const s16x8*)&qkv[secBase + (size_t)(L + k) * 32 + dh * 16];
            const s16x8 kr1 = *(const s16x8*)&qkv[secBase + (size_t)(L + k) * 32 + dh * 16 + 8];
            const s16x8 vr0 = *(const s16x8*)&qkv[secBase + (size_t)(2 * L + k) * 32 + dh * 16];
            const s16x8 vr1 = *(const s16x8*)&qkv[secBase + (size_t)(2 * L + k) * 32 + dh * 16 + 8];
            float kvv[16];
#pragma unroll
            for (int e = 0; e < 8; ++e) {
                kvv[e]     = bf2f((unsigned short)kr0[e]);
                kvv[8 + e] = bf2f((unsigned short)kr1[e]);
            }
#pragma unroll
            for (int j = 0; j < 8; ++j) {
                const float2 cs = ropeT[k * 16 + dh * 8 + j];
                const float x0 = kvv[2 * j], x1 = kvv[2 * j + 1];
                kvv[2 * j]     = x0 * cs.x - x1 * cs.y;
                kvv[2 * j + 1] = x1 * cs.x + x0 * cs.y;
            }
            char* kf = kvLds + headl * 2 * KVB;
            s16x8 wlo, whi;
#pragma unroll
            for (int e = 0; e < 8; ++e) {
                wlo[e] = (short)f2bf(kvv[e]);
                whi[e] = (short)f2bf(kvv[8 + e]);
            }
            *(s16x8*)(kf + (((k >> 5) * 2 + dh) * 64 + (k & 31)) * 16) = wlo;
            *(s16x8*)(kf + (((k >> 5) * 2 + dh) * 64 + 32 + (k & 31)) * 16) = whi;
            char* vf = kf + KVB;
            const int kb = k >> 4, hi8 = (k >> 3) & 1, eo = (k & 7) * 2;
#pragma unroll
            for (int dp = 0; dp < 16; ++dp) {
                const unsigned short vv = (unsigned short)((dp < 8) ? vr0[dp] : vr1[dp - 8]);
                *(unsigned short*)(vf + (kb * 64 + dh * 16 + dp + 32 * hi8) * 16 + eo) = vv;
            }
        }
    }
    __syncthreads();

    // ---- compute (exp2 domain) ----
    const int headl = (STAGE == 1) ? 0 : (wave >> 1);
    const int h = hx * HPB + headl;
    const char* Kf = kvLds + headl * 2 * KVB;
    const char* Vf = Kf + KVB;
    const int nPass = (STAGE == 1) ? 2 : 1;
    const float QS = SM_SCALE * LOG2E;
    const float THR = 8.0f * LOG2E;
    const size_t qSec = (((size_t)(sl * 8 + h) * 3) << ((STAGE == 1) ? 8 : 6)) * 32;

    for (int pass = 0; pass < nPass; ++pass) {
        const int qt = (STAGE == 1) ? (wave + pass * 4) : (wave & 1);
        const int q = qt * 32 + qloc;
        s16x8 qf0, qf1;
        {
            const size_t qrow = qSec + (size_t)q * 32;
            const s16x8 qr0 = *(const s16x8*)&qkv[qrow + hiSel * 8];
            const s16x8 qr1 = *(const s16x8*)&qkv[qrow + 16 + hiSel * 8];
#pragma unroll
            for (int j = 0; j < 4; ++j) {
                const float2 c0 = ropeT[q * 16 + hiSel * 4 + j];
                const float a0 = bf2f((unsigned short)qr0[2 * j]);
                const float a1 = bf2f((unsigned short)qr0[2 * j + 1]);
                qf0[2 * j]     = (short)f2bf((a0 * c0.x - a1 * c0.y) * QS);
                qf0[2 * j + 1] = (short)f2bf((a1 * c0.x + a0 * c0.y) * QS);
                const float2 c1 = ropeT[q * 16 + 8 + hiSel * 4 + j];
                const float b0 = bf2f((unsigned short)qr1[2 * j]);
                const float b1 = bf2f((unsigned short)qr1[2 * j + 1]);
                qf1[2 * j]     = (short)f2bf((b0 * c1.x - b1 * c1.y) * QS);
                qf1[2 * j + 1] = (short)f2bf((b1 * c1.x + b0 * c1.y) * QS);
            }
        }
        f32x16 o = (f32x16)0.0f;
        float m = -INFINITY, lsum = 0.f;
#pragma unroll
        for (int c = 0; c < NCH; ++c) {
            const s16x8 ka = *(const s16x8*)(Kf + (c * 2 + 0) * 1024 + lane * 16);
            const s16x8 kb = *(const s16x8*)(Kf + (c * 2 + 1) * 1024 + lane * 16);
            f32x16 S = (f32x16)0.0f;
            S = __builtin_amdgcn_mfma_f32_32x32x16_bf16(ka, qf0, S, 0, 0, 0);
            S = __builtin_amdgcn_mfma_f32_32x32x16_bf16(kb, qf1, S, 0, 0, 0);
            float cmax = max16(S);
            cmax = fmaxf(cmax, __shfl_xor(cmax, 32, 64));
            if (__any(cmax > m + THR)) {         // defer-max (e^8 bound)
                const float mnew = fmaxf(m, cmax);
                const float corr = exp2fast(m - mnew);
                m = mnew;
                lsum *= corr;
#pragma unroll
                for (int r = 0; r < 16; ++r) o[r] *= corr;
            }
            float p[16];
#pragma unroll
            for (int r = 0; r < 16; ++r) p[r] = exp2fast(S[r] - m);
            lsum += sum16(p);
#pragma unroll
            for (int j = 0; j < 8; ++j)
                PL[((j & 1) + 4 * (j >> 1) + 2 * hiSel) * 32 + qloc] =
                    __int_as_float(cvt_pk_bf16(p[2 * j], p[2 * j + 1]));
            union { int u[4]; s16x8 v; } P0, P1;
#pragma unroll
            for (int i = 0; i < 4; ++i) {
                P0.u[i] = __float_as_int(PL[(hiSel * 4 + i) * 32 + qloc]);
                P1.u[i] = __float_as_int(PL[(8 + hiSel * 4 + i) * 32 + qloc]);
            }
            const s16x8 va = *(const s16x8*)(Vf + (c * 2 + 0) * 1024 + lane * 16);
            const s16x8 vb = *(const s16x8*)(Vf + (c * 2 + 1) * 1024 + lane * 16);
            o = __builtin_amdgcn_mfma_f32_32x32x16_bf16(va, P0.v, o, 0, 0, 0);
            o = __builtin_amdgcn_mfma_f32_32x32x16_bf16(vb, P1.v, o, 0, 0, 0);
        }
        lsum += __shfl_xor(lsum, 32, 64);
        const float inv = 1.0f / lsum;
#pragma unroll
        for (int r = 0; r < 16; ++r)
            Osc[wave][qloc][(r & 3) + 8 * (r >> 2) + 4 * hiSel] = o[r] * inv;
        int tok;
        if constexpr (STAGE == 1) {
            const int s = s0 + sl, b = s >> 6, f = s & 63;
            tok = (b * 256 + q) * 64 + f;
        } else if constexpr (STAGE == 2) {
            const int s2 = s0 + sl, b = s2 >> 8, t = s2 & 255;
            tok = ((b * 32 + (t >> 3)) * 8 + (q >> 3)) * 64 + (t & 7) * 8 + (q & 7);
        } else {
            const int w = s0 + sl, b = w >> 8, tb = (w >> 3) & 31, fb = w & 7;
            tok = (b * 256 + tb * 8 + (q >> 3)) * 64 + fb * 8 + (q & 7);
        }
        const int rloc = tok & 127;
        char* base = Ximg + ((size_t)((tok >> 7) * 4 + (h >> 1))) * 32768;
        const int sw = (rloc & 7) << 4;
        const int hb64 = (h & 1) * 64;
#pragma unroll
        for (int gg = 0; gg < 2; ++gg) {
            const int g = hiSel * 2 + gg;
            float v8[8];
            *(float4*)&v8[0] = *(const float4*)&Osc[wave][qloc][g * 8];
            *(float4*)&v8[4] = *(const float4*)&Osc[wave][qloc][g * 8 + 4];
            const int off = rloc * 128 + ((hb64 + g * 16) ^ sw);
            s16x8 hi;
#pragma unroll
            for (int e = 0; e < 8; ++e) hi[e] = (short)f2bf(v8[e]);
            *(s16x8*)(base + off) = hi;
            if constexpr (WLO) {
                s16x8 lo;
#pragma unroll
                for (int e = 0; e < 8; ++e)
                    lo[e] = (short)f2bf(v8[e] - bf2f((unsigned short)hi[e]));
                *(s16x8*)(base + 16384 + off) = lo;
            }
        }
    }
}

// ---------------------------------------------------------------- launch
extern "C" void kernel_launch(void* const* d_in, const int* in_sizes, int n_in,
                              void* d_out, int out_size, void* d_ws, size_t ws_size,
                              hipStream_t stream) {
    const float* x  = (const float*)d_in[0];
    const float* W1 = (const float*)d_in[1];
    const float* W2 = (const float*)d_in[2];
    const float* W3 = (const float*)d_in[3];
    const float* Wp = (const float*)d_in[4];
    float* out = (float*)d_out;

    const size_t M = (size_t)B_ * T_ * F_;        // 65536 tokens
    char* Xa = (char*)d_out;                      // image buffer A (X1, X3)
    char* Xb = (char*)d_ws;                       // image buffer B (X2, X4)
    char* W1i = (char*)d_ws + M * 1024;           // weight images
    char* W2i = W1i + 786432;
    char* W3i = W2i + 786432;
    char* Wpi = W3i + 786432;
    float2* ropeT = (float2*)(Wpi + 262144);                 // 32 KB
    unsigned short* qkvB = (unsigned short*)((char*)ropeT + 32768);

    const size_t fixedBytes = M * 1024 + 3 * 786432 + 262144 + 32768;
    int CH = 2048;
    const int cands[5] = {65536, 32768, 16384, 8192, 4096};
    for (int i = 0; i < 5; ++i) {
        if (fixedBytes + (size_t)cands[i] * 1536 <= ws_size) { CH = cands[i]; break; }
    }
    const int NC = (int)(M / CH);

    rope_table<<<16, 256, 0, stream>>>(ropeT);
    split_w<<<dim3(6, 4), 256, 0, stream>>>(W1, W1i, 768);
    split_w<<<dim3(6, 4), 256, 0, stream>>>(W2, W2i, 768);
    split_w<<<dim3(6, 4), 256, 0, stream>>>(W3, W3i, 768);
    split_w<<<dim3(2, 4), 256, 0, stream>>>(Wp, Wpi, 256);

    transpose_in<<<dim3(8, 2, 1024), dim3(32, 8), 0, stream>>>(x, Xa);

    // stage 1: time attention (L=256)
    for (int c = 0; c < NC; ++c) {
        gemm_x2<8><<<(CH / 128) * 6, 256, 0, stream>>>(
            Xa + (size_t)c * CH * 1024, W1i, qkvB);
        attn_mfma<1, false><<<8 * (CH / 256), 256, 0, stream>>>(
            qkvB, Xb, ropeT, c * (CH / 256));
    }
    // stage 2: freq attention (L=64)
    for (int c = 0; c < NC; ++c) {
        gemm_x2<6><<<(CH / 128) * 6, 256, 0, stream>>>(
            Xb + (size_t)c * CH * 1024, W2i, qkvB);
        attn_mfma<2, false><<<4 * (CH / 64), 256, 0, stream>>>(
            qkvB, Xa, ropeT, c * (CH / 64));
    }
    // stage 3: windowed attention (L=64) — output feeds x3 cproj, keep lo
    for (int c = 0; c < NC; ++c) {
        gemm_x2<6><<<(CH / 128) * 6, 256, 0, stream>>>(
            Xa + (size_t)c * CH * 1024, W3i, qkvB);
        attn_mfma<3, true><<<4 * (CH / 64), 256, 0, stream>>>(
            qkvB, Xb, ropeT, c * (CH / 64));
    }
    // fused c_proj (x3) + output scatter
    for (int c = 0; c < NC; ++c) {
        gemm_cproj<<<(CH / 128) * 2, 256, 0, stream>>>(
            Xb + (size_t)c * CH * 1024, Wpi, out, c * CH);
    }
}